// Round 1
// baseline (1000.960 us; speedup 1.0000x reference)
//
#include <hip/hip_runtime.h>
#include <hip/hip_bf16.h>
#include <math.h>

#define NNODES 20000
#define NEDGES 640000
#define BSZ 256
#define GDIM 256
#define HID 512
#define INNER 2048
#define RANK 512
#define NCLS 3
#define NGENES 6640

typedef __attribute__((ext_vector_type(8))) short bf16x8;
typedef __attribute__((ext_vector_type(4))) float f32x4;

__device__ inline float bf2f(unsigned short u) {
    return __uint_as_float(((unsigned)u) << 16);
}
__device__ inline unsigned short f2bf(float f) {
    unsigned u = __float_as_uint(f);
    u = u + 0x7fff + ((u >> 16) & 1);   // RNE
    return (unsigned short)(u >> 16);
}

// ---------------- CSR build ----------------
__global__ void hist_k(const int* __restrict__ dst, int* __restrict__ counts, int E) {
    int e = blockIdx.x * 256 + threadIdx.x;
    if (e < E) atomicAdd(&counts[dst[e]], 1);
}

__global__ void scan1_k(const int* __restrict__ counts, int* __restrict__ incl,
                        int* __restrict__ bsums, int n) {
    __shared__ int s[256];
    int i = blockIdx.x * 256 + threadIdx.x;
    int v = (i < n) ? counts[i] : 0;
    s[threadIdx.x] = v;
    __syncthreads();
    for (int off = 1; off < 256; off <<= 1) {
        int t = (threadIdx.x >= off) ? s[threadIdx.x - off] : 0;
        __syncthreads();
        s[threadIdx.x] += t;
        __syncthreads();
    }
    if (i < n) incl[i] = s[threadIdx.x];
    if (threadIdx.x == 255) bsums[blockIdx.x] = s[255];
}

__global__ void scan2_k(const int* __restrict__ bsums, int* __restrict__ boffs, int nb) {
    __shared__ int s[128];
    int tid = threadIdx.x;
    int v = (tid < nb) ? bsums[tid] : 0;
    s[tid] = v;
    __syncthreads();
    for (int off = 1; off < 128; off <<= 1) {
        int t = (tid >= off) ? s[tid - off] : 0;
        __syncthreads();
        s[tid] += t;
        __syncthreads();
    }
    if (tid < nb) boffs[tid] = s[tid] - v;
}

__global__ void scan3_k(const int* __restrict__ incl, const int* __restrict__ counts,
                        const int* __restrict__ boffs, int* __restrict__ row_start,
                        int* __restrict__ cursor, int n) {
    int i = blockIdx.x * 256 + threadIdx.x;
    if (i < n) {
        int st = incl[i] - counts[i] + boffs[blockIdx.x];
        row_start[i] = st;
        cursor[i] = st;
    }
}

__global__ void scatter_k(const int* __restrict__ src, const int* __restrict__ dst,
                          const float* __restrict__ w, int* __restrict__ cursor,
                          int2* __restrict__ ep, int E) {
    int e = blockIdx.x * 256 + threadIdx.x;
    if (e < E) {
        int d = dst[e];
        int p = atomicAdd(&cursor[d], 1);
        ep[p] = make_int2(src[e], __float_as_int(w[e]));
    }
}

// ---------------- combined weight conversion (replaces 7 kernels) ----------------
// block ranges: gnn 0-191, post 192-255, pin 256-383, w1 384-6527,
//               w2 6528-12671, pout 12672-13439, gene 13440-15099
__global__ void convall_k(const float* __restrict__ gnn_w, const float* __restrict__ post_w,
                          const float* __restrict__ pin_w, const float* __restrict__ blk_w1,
                          const float* __restrict__ blk_w2, const float* __restrict__ pout_w,
                          const float* __restrict__ gene, unsigned short* __restrict__ gnnT,
                          unsigned short* __restrict__ postT, unsigned short* __restrict__ pinT,
                          unsigned short* __restrict__ w1T, unsigned short* __restrict__ w2T,
                          unsigned short* __restrict__ poutT,
                          unsigned short* __restrict__ geneb) {
    int b = blockIdx.x;
    if (b >= 13440) {   // gene: plain fp32 -> bf16 convert, 2048 elems/block
        int t = b - 13440;
        const float4* xp = (const float4*)gene;
        int i = t * 512 + threadIdx.x * 2;    // float4 index
        float4 a = xp[i], c = xp[i + 1];
        *(ushort4*)(geneb + (size_t)i * 4) =
            make_ushort4(f2bf(a.x), f2bf(a.y), f2bf(a.z), f2bf(a.w));
        *(ushort4*)(geneb + (size_t)i * 4 + 4) =
            make_ushort4(f2bf(c.x), f2bf(c.y), f2bf(c.z), f2bf(c.w));
        return;
    }
    const float* W;
    unsigned short* WT;
    int K, N, tile;
    if (b < 192) {
        int l = b >> 6;
        tile = b & 63;
        W = gnn_w + (size_t)l * GDIM * GDIM;
        WT = gnnT + (size_t)l * GDIM * GDIM;
        K = GDIM; N = GDIM;
    } else if (b < 256) {
        tile = b - 192; W = post_w; WT = postT; K = GDIM; N = GDIM;
    } else if (b < 384) {
        tile = b - 256; W = pin_w; WT = pinT; K = GDIM; N = HID;
    } else if (b < 6528) {
        int t = b - 384;
        int l = t >> 10;
        tile = t & 1023;
        W = blk_w1 + (size_t)l * HID * INNER;
        WT = w1T + (size_t)l * INNER * HID;
        K = HID; N = INNER;
    } else if (b < 12672) {
        int t = b - 6528;
        int l = t >> 10;
        tile = t & 1023;
        W = blk_w2 + (size_t)l * INNER * HID;
        WT = w2T + (size_t)l * HID * INNER;
        K = INNER; N = HID;
    } else {
        tile = b - 12672; W = pout_w; WT = poutT; K = HID; N = NCLS * RANK;
    }
    __shared__ float s[32][33];
    int ntx = N >> 5;
    int k0 = (tile / ntx) << 5;
    int n0 = (tile % ntx) << 5;
    int tx = threadIdx.x & 31, ty = threadIdx.x >> 5;
#pragma unroll
    for (int i = 0; i < 4; i++)
        s[ty + 8 * i][tx] = W[(size_t)(k0 + ty + 8 * i) * N + n0 + tx];
    __syncthreads();
#pragma unroll
    for (int i = 0; i < 4; i++)
        WT[(size_t)(n0 + ty + 8 * i) * K + k0 + tx] = f2bf(s[tx][ty + 8 * i]);
}

// ---------------- GNN LayerNorm (D=256), bf16 out ----------------
__global__ void lnb_k(const float* __restrict__ X, const float* __restrict__ sc,
                      const float* __restrict__ bi, unsigned short* __restrict__ Y, int M) {
    int row = blockIdx.x * 4 + (threadIdx.x >> 6);
    int lane = threadIdx.x & 63;
    if (row >= M) return;
    float4 v = ((const float4*)(X + (size_t)row * GDIM))[lane];
    float sum = v.x + v.y + v.z + v.w;
#pragma unroll
    for (int off = 32; off >= 1; off >>= 1) sum += __shfl_xor(sum, off);
    float mu = sum / GDIM;
    float a = v.x - mu, b = v.y - mu, c = v.z - mu, d = v.w - mu;
    float sq = a * a + b * b + c * c + d * d;
#pragma unroll
    for (int off = 32; off >= 1; off >>= 1) sq += __shfl_xor(sq, off);
    float rstd = rsqrtf(sq / GDIM + 1e-5f);
    float4 s4 = ((const float4*)sc)[lane];
    float4 b4 = ((const float4*)bi)[lane];
    *(ushort4*)(Y + (size_t)row * GDIM + lane * 4) =
        make_ushort4(f2bf(a * rstd * s4.x + b4.x), f2bf(b * rstd * s4.y + b4.y),
                     f2bf(c * rstd * s4.z + b4.z), f2bf(d * rstd * s4.w + b4.w));
}

// ---------------- CSR aggregation, 16-deep MLP unroll ----------------
__device__ inline void agg_row(int beg, int cnt, int lane, const int2* __restrict__ ep,
                               const unsigned short* __restrict__ H, float& a0, float& a1,
                               float& a2, float& a3) {
    int t = 0;
    for (; t + 16 <= cnt; t += 16) {
        int2 e[16];
#pragma unroll
        for (int u = 0; u < 16; u++) e[u] = ep[beg + t + u];
        ushort4 v[16];
#pragma unroll
        for (int u = 0; u < 16; u++)
            v[u] = *(const ushort4*)(H + (size_t)e[u].x * GDIM + lane * 4);
#pragma unroll
        for (int u = 0; u < 16; u++) {
            float w = __int_as_float(e[u].y);
            a0 = fmaf(bf2f(v[u].x), w, a0);
            a1 = fmaf(bf2f(v[u].y), w, a1);
            a2 = fmaf(bf2f(v[u].z), w, a2);
            a3 = fmaf(bf2f(v[u].w), w, a3);
        }
    }
    for (; t + 4 <= cnt; t += 4) {
        int2 e[4];
#pragma unroll
        for (int u = 0; u < 4; u++) e[u] = ep[beg + t + u];
        ushort4 v[4];
#pragma unroll
        for (int u = 0; u < 4; u++)
            v[u] = *(const ushort4*)(H + (size_t)e[u].x * GDIM + lane * 4);
#pragma unroll
        for (int u = 0; u < 4; u++) {
            float w = __int_as_float(e[u].y);
            a0 = fmaf(bf2f(v[u].x), w, a0);
            a1 = fmaf(bf2f(v[u].y), w, a1);
            a2 = fmaf(bf2f(v[u].z), w, a2);
            a3 = fmaf(bf2f(v[u].w), w, a3);
        }
    }
    for (; t < cnt; t++) {
        int2 e = ep[beg + t];
        float w = __int_as_float(e.y);
        ushort4 v = *(const ushort4*)(H + (size_t)e.x * GDIM + lane * 4);
        a0 = fmaf(bf2f(v.x), w, a0);
        a1 = fmaf(bf2f(v.y), w, a1);
        a2 = fmaf(bf2f(v.z), w, a2);
        a3 = fmaf(bf2f(v.w), w, a3);
    }
}

__global__ void aggb_k(const int* __restrict__ row_start, const int* __restrict__ counts,
                       const int2* __restrict__ ep, const unsigned short* __restrict__ H,
                       unsigned short* __restrict__ AGG, int n) {
    int row = blockIdx.x * 4 + (threadIdx.x >> 6);
    int lane = threadIdx.x & 63;
    if (row >= n) return;
    float a0 = 0.f, a1 = 0.f, a2 = 0.f, a3 = 0.f;
    agg_row(row_start[row], counts[row], lane, ep, H, a0, a1, a2, a3);
    *(ushort4*)(AGG + (size_t)row * GDIM + lane * 4) =
        make_ushort4(f2bf(a0), f2bf(a1), f2bf(a2), f2bf(a3));
}

__global__ void aggsel_k(const int* __restrict__ idx, const int* __restrict__ row_start,
                         const int* __restrict__ counts, const int2* __restrict__ ep,
                         const unsigned short* __restrict__ H, unsigned short* __restrict__ AGG) {
    int b = blockIdx.x * 4 + (threadIdx.x >> 6);
    int lane = threadIdx.x & 63;
    int id = idx[b];
    int row = id < 0 ? 0 : id;
    float a0 = 0.f, a1 = 0.f, a2 = 0.f, a3 = 0.f;
    agg_row(row_start[row], counts[row], lane, ep, H, a0, a1, a2, a3);
    *(ushort4*)(AGG + (size_t)b * GDIM + lane * 4) =
        make_ushort4(f2bf(a0), f2bf(a1), f2bf(a2), f2bf(a3));
}

// ---------------- bf16 MFMA GEMM (full-K, fp32 out, fused epilogue) — GNN L1/L2 & logits ----------------
template <int ACT, bool RES, bool BIAS>
__global__ __launch_bounds__(256) void mgemm_k(const unsigned short* __restrict__ A,
                                               const unsigned short* __restrict__ BT,
                                               const float* __restrict__ bias,
                                               const float* __restrict__ R,
                                               float* __restrict__ C, int M, int N, int K) {
    __shared__ unsigned short As[128 * 32];
    __shared__ unsigned short Bs[128 * 32];
    int m0 = blockIdx.y * 128, n0 = blockIdx.x * 128;
    int tid = threadIdx.x;
    int wave = tid >> 6, lane = tid & 63;
    int wm = (wave >> 1) * 64, wn = (wave & 1) * 64;
    int lrow = lane & 15, lq = lane >> 4;

    f32x4 acc[4][4];
    const f32x4 zz = {0.f, 0.f, 0.f, 0.f};
#pragma unroll
    for (int i = 0; i < 4; i++)
#pragma unroll
        for (int j = 0; j < 4; j++) acc[i][j] = zz;

    int r0 = tid >> 2;
    int q = tid & 3;

    for (int k0 = 0; k0 < K; k0 += 32) {
#pragma unroll
        for (int p = 0; p < 2; p++) {
            int row = r0 + p * 64;
            int gm = m0 + row;
            uint4 va = make_uint4(0, 0, 0, 0);
            if (gm < M) va = *(const uint4*)(A + (size_t)gm * K + k0 + q * 8);
            *(uint4*)&As[row * 32 + q * 8] = va;
            int gn = n0 + row;
            uint4 vb = make_uint4(0, 0, 0, 0);
            if (gn < N) vb = *(const uint4*)(BT + (size_t)gn * K + k0 + q * 8);
            *(uint4*)&Bs[row * 32 + q * 8] = vb;
        }
        __syncthreads();
        bf16x8 af[4], bf[4];
#pragma unroll
        for (int i = 0; i < 4; i++)
            af[i] = *(const bf16x8*)&As[(wm + i * 16 + lrow) * 32 + lq * 8];
#pragma unroll
        for (int j = 0; j < 4; j++)
            bf[j] = *(const bf16x8*)&Bs[(wn + j * 16 + lrow) * 32 + lq * 8];
#pragma unroll
        for (int i = 0; i < 4; i++)
#pragma unroll
            for (int j = 0; j < 4; j++)
                acc[i][j] =
                    __builtin_amdgcn_mfma_f32_16x16x32_bf16(af[i], bf[j], acc[i][j], 0, 0, 0);
        __syncthreads();
    }

#pragma unroll
    for (int i = 0; i < 4; i++) {
#pragma unroll
        for (int j = 0; j < 4; j++) {
            int gn = n0 + wn + j * 16 + lrow;
            if (gn >= N) continue;
            float bv = BIAS ? bias[gn] : 0.f;
#pragma unroll
            for (int r = 0; r < 4; r++) {
                int gm = m0 + wm + i * 16 + lq * 4 + r;
                if (gm >= M) continue;
                float v = acc[i][j][r] + bv;
                if (ACT == 1) v = fmaxf(v, 0.f);
                if (RES) v += R[(size_t)gm * N + gn];
                C[(size_t)gm * N + gn] = v;
            }
        }
    }
}

// ---------------- bf16 MFMA full-K, bf16 out, fused epilogue (GNN L3 / post) ----------------
template <int ACT, int EPI>
__global__ __launch_bounds__(256) void mfull_k(const unsigned short* __restrict__ A,
                                               const unsigned short* __restrict__ BT,
                                               const float* __restrict__ bias,
                                               const int* __restrict__ idx,
                                               const float* __restrict__ aux,
                                               unsigned short* __restrict__ O, int M, int N,
                                               int K) {
    __shared__ unsigned short As[64 * 32];
    __shared__ unsigned short Bs[64 * 32];
    int m0 = blockIdx.y * 64, n0 = blockIdx.x * 64;
    int tid = threadIdx.x;
    int wave = tid >> 6, lane = tid & 63;
    int wm = wave * 16;
    int lrow = lane & 15, lq = lane >> 4;
    f32x4 acc[4];
    const f32x4 zz = {0.f, 0.f, 0.f, 0.f};
#pragma unroll
    for (int j = 0; j < 4; j++) acc[j] = zz;
    int r0 = tid >> 2;
    int q = tid & 3;
    for (int k0 = 0; k0 < K; k0 += 32) {
        *(uint4*)&As[r0 * 32 + q * 8] = *(const uint4*)(A + (size_t)(m0 + r0) * K + k0 + q * 8);
        *(uint4*)&Bs[r0 * 32 + q * 8] = *(const uint4*)(BT + (size_t)(n0 + r0) * K + k0 + q * 8);
        __syncthreads();
        bf16x8 af = *(const bf16x8*)&As[(wm + lrow) * 32 + lq * 8];
#pragma unroll
        for (int j = 0; j < 4; j++) {
            bf16x8 bfr = *(const bf16x8*)&Bs[(j * 16 + lrow) * 32 + lq * 8];
            acc[j] = __builtin_amdgcn_mfma_f32_16x16x32_bf16(af, bfr, acc[j], 0, 0, 0);
        }
        __syncthreads();
    }
#pragma unroll
    for (int j = 0; j < 4; j++) {
        int gn = n0 + j * 16 + lrow;
        float bv = bias[gn];
#pragma unroll
        for (int r = 0; r < 4; r++) {
            int gm = m0 + wm + lq * 4 + r;
            float v = acc[j][r] + bv;
            if (ACT == 1) v = fmaxf(v, 0.f);
            if (ACT == 2) v = 0.5f * v * (1.f + erff(v * 0.70710678118654752f));
            if (EPI == 2) {
                int id = idx[gm];
                int safe = id < 0 ? 0 : id;
                v += aux[(size_t)safe * N + gn];
            }
            if (EPI == 1) {
                if (idx[gm] < 0) v = aux[gn];
            }
            O[(size_t)gm * N + gn] = f2bf(v);
        }
    }
}

// ================= fused persistent head =================
// grid = 256 blocks x 256 threads, guaranteed co-resident (256 CUs, 1 block/CU floor),
// homebrew device-scope barrier (graph-capture-safe, no cooperative launch).

#define HGRID 256
#define LDP 72   // padded LDS row stride (ushort): keeps ds_read_b128 conflict-free at BK=64

__device__ inline void gsync(int* bar, int target) {
    __syncthreads();
    if (threadIdx.x == 0) {
        __threadfence();   // device-scope release of this block's prior writes
        __hip_atomic_fetch_add(bar, 1, __ATOMIC_RELEASE, __HIP_MEMORY_SCOPE_AGENT);
        while (__hip_atomic_load(bar, __ATOMIC_ACQUIRE, __HIP_MEMORY_SCOPE_AGENT) < target)
            __builtin_amdgcn_s_sleep(2);
    }
    __syncthreads();
}

// 32x64 tile GEMM, BK=64, reg-double-buffered staging (issue-early / write-late).
// waves 2x2: each wave 16 rows x 32 cols (2 j-frags).
__device__ inline void gemm32x64(const unsigned short* __restrict__ A, int lda,
                                 const unsigned short* __restrict__ BT, int ldb, int m0, int n0,
                                 int kbeg, int kcnt, unsigned short* As, unsigned short* Bs,
                                 f32x4 acc[2]) {
    int tid = threadIdx.x;
    int wave = tid >> 6, lane = tid & 63;
    int wm = (wave >> 1) * 16, wn = (wave & 1) * 32;
    int lrow = lane & 15, lq = lane >> 4;
    int rb = tid >> 2, qb = tid & 3;   // B rows 0..63
    int ra = rb & 31;                  // A rows 0..31 (tid<128)
    const unsigned short* bp = BT + (size_t)(n0 + rb) * ldb + kbeg + qb * 16;
    const unsigned short* ap = A + (size_t)(m0 + ra) * lda + kbeg + qb * 16;
    uint4 vb0 = *(const uint4*)bp, vb1 = *(const uint4*)(bp + 8);
    uint4 va0 = {0, 0, 0, 0}, va1 = {0, 0, 0, 0};
    if (tid < 128) {
        va0 = *(const uint4*)ap;
        va1 = *(const uint4*)(ap + 8);
    }
    for (int k0 = 0; k0 < kcnt; k0 += 64) {
        *(uint4*)&Bs[rb * LDP + qb * 16] = vb0;
        *(uint4*)&Bs[rb * LDP + qb * 16 + 8] = vb1;
        if (tid < 128) {
            *(uint4*)&As[ra * LDP + qb * 16] = va0;
            *(uint4*)&As[ra * LDP + qb * 16 + 8] = va1;
        }
        __syncthreads();
        if (k0 + 64 < kcnt) {   // prefetch next K-slab; overlaps the MFMA section below
            vb0 = *(const uint4*)(bp + k0 + 64);
            vb1 = *(const uint4*)(bp + k0 + 72);
            if (tid < 128) {
                va0 = *(const uint4*)(ap + k0 + 64);
                va1 = *(const uint4*)(ap + k0 + 72);
            }
        }
#pragma unroll
        for (int kk = 0; kk < 2; kk++) {
            bf16x8 af = *(const bf16x8*)&As[(wm + lrow) * LDP + kk * 32 + lq * 8];
#pragma unroll
            for (int j = 0; j < 2; j++) {
                bf16x8 bfr = *(const bf16x8*)&Bs[(wn + j * 16 + lrow) * LDP + kk * 32 + lq * 8];
                acc[j] = __builtin_amdgcn_mfma_f32_16x16x32_bf16(af, bfr, acc[j], 0, 0, 0);
            }
        }
        __syncthreads();
    }
}

template <int ACT>
__device__ inline void epi32x64_bf(const f32x4 acc[2], const float* __restrict__ bias,
                                   unsigned short* __restrict__ O, int ldo, int m0, int n0) {
    int tid = threadIdx.x, wave = tid >> 6, lane = tid & 63;
    int wm = (wave >> 1) * 16, wn = (wave & 1) * 32;
    int lrow = lane & 15, lq = lane >> 4;
#pragma unroll
    for (int j = 0; j < 2; j++) {
        int gn = n0 + wn + j * 16 + lrow;
        float bv = bias[gn];
#pragma unroll
        for (int r = 0; r < 4; r++) {
            int gm = m0 + wm + lq * 4 + r;
            float v = acc[j][r] + bv;
            if (ACT == 2) v = 0.5f * v * (1.f + erff(v * 0.70710678118654752f));
            O[(size_t)gm * ldo + gn] = f2bf(v);
        }
    }
}

__device__ inline void epi32x64_f32(const f32x4 acc[2], float* __restrict__ C, int ldo, int m0,
                                    int n0) {
    int tid = threadIdx.x, wave = tid >> 6, lane = tid & 63;
    int wm = (wave >> 1) * 16, wn = (wave & 1) * 32;
    int lrow = lane & 15, lq = lane >> 4;
#pragma unroll
    for (int j = 0; j < 2; j++) {
        int gn = n0 + wn + j * 16 + lrow;
#pragma unroll
        for (int r = 0; r < 4; r++) {
            int gm = m0 + wm + lq * 4 + r;
            C[(size_t)gm * ldo + gn] = acc[j][r];
        }
    }
}

// reduce 4 split-K partials + bias (+residual) -> hbuf, optional LN -> bf16 out.
// called by blocks 0..63 (4 rows each).
template <bool RESID, bool DO_LN>
__device__ inline void redln_dev(const float* __restrict__ Cp, const float* __restrict__ bias,
                                 const float* __restrict__ ln_s, const float* __restrict__ ln_b,
                                 float* __restrict__ hbuf, unsigned short* __restrict__ outbf) {
    int row = blockIdx.x * 4 + (threadIdx.x >> 6);
    int lane = threadIdx.x & 63;
    float4 a0 = {0.f, 0.f, 0.f, 0.f}, a1 = a0;
#pragma unroll
    for (int s = 0; s < 4; s++) {
        const float4* pp = (const float4*)(Cp + ((size_t)s * BSZ + row) * HID);
        float4 b0 = pp[lane * 2], b1 = pp[lane * 2 + 1];
        a0.x += b0.x; a0.y += b0.y; a0.z += b0.z; a0.w += b0.w;
        a1.x += b1.x; a1.y += b1.y; a1.z += b1.z; a1.w += b1.w;
    }
    const float4* bb = (const float4*)bias;
    float4 c0 = bb[lane * 2], c1 = bb[lane * 2 + 1];
    a0.x += c0.x; a0.y += c0.y; a0.z += c0.z; a0.w += c0.w;
    a1.x += c1.x; a1.y += c1.y; a1.z += c1.z; a1.w += c1.w;
    float4* hp = (float4*)(hbuf + (size_t)row * HID);
    if (RESID) {
        float4 r0 = hp[lane * 2], r1 = hp[lane * 2 + 1];
        a0.x += r0.x; a0.y += r0.y; a0.z += r0.z; a0.w += r0.w;
        a1.x += r1.x; a1.y += r1.y; a1.z += r1.z; a1.w += r1.w;
    }
    hp[lane * 2] = a0;
    hp[lane * 2 + 1] = a1;
    unsigned short* op = outbf + (size_t)row * HID;
    if (DO_LN) {
        float sum = a0.x + a0.y + a0.z + a0.w + a1.x + a1.y + a1.z + a1.w;
#pragma unroll
        for (int off = 32; off >= 1; off >>= 1) sum += __shfl_xor(sum, off);
        float mu = sum / HID;
        float d0 = a0.x - mu, d1 = a0.y - mu, d2 = a0.z - mu, d3 = a0.w - mu;
        float d4 = a1.x - mu, d5 = a1.y - mu, d6 = a1.z - mu, d7 = a1.w - mu;
        float sq = d0 * d0 + d1 * d1 + d2 * d2 + d3 * d3 + d4 * d4 + d5 * d5 + d6 * d6 + d7 * d7;
#pragma unroll
        for (int off = 32; off >= 1; off >>= 1) sq += __shfl_xor(sq, off);
        float rstd = rsqrtf(sq / HID + 1e-5f);
        const float4* sp = (const float4*)ln_s;
        const float4* bp2 = (const float4*)ln_b;
        float4 s0 = sp[lane * 2], s1 = sp[lane * 2 + 1];
        float4 t0 = bp2[lane * 2], t1 = bp2[lane * 2 + 1];
        *(ushort4*)(op + lane * 8) =
            make_ushort4(f2bf(d0 * rstd * s0.x + t0.x), f2bf(d1 * rstd * s0.y + t0.y),
                         f2bf(d2 * rstd * s0.z + t0.z), f2bf(d3 * rstd * s0.w + t0.w));
        *(ushort4*)(op + lane * 8 + 4) =
            make_ushort4(f2bf(d4 * rstd * s1.x + t1.x), f2bf(d5 * rstd * s1.y + t1.y),
                         f2bf(d6 * rstd * s1.z + t1.z), f2bf(d7 * rstd * s1.w + t1.w));
    } else {
        *(ushort4*)(op + lane * 8) = make_ushort4(f2bf(a0.x), f2bf(a0.y), f2bf(a0.z), f2bf(a0.w));
        *(ushort4*)(op + lane * 8 + 4) =
            make_ushort4(f2bf(a1.x), f2bf(a1.y), f2bf(a1.z), f2bf(a1.w));
    }
}

// fused: pin(split-K)+LN0 -> 6x{w1-GELU, w2 split-K, reduce+res+LN} -> pout. 20 grid syncs.
__global__ __launch_bounds__(256) void head_k(
    const unsigned short* __restrict__ pertbf, const unsigned short* __restrict__ pinT,
    const float* __restrict__ pin_b, const float* __restrict__ blk_ln_s,
    const float* __restrict__ blk_ln_b, const unsigned short* __restrict__ w1T,
    const float* __restrict__ blk_b1, const unsigned short* __restrict__ w2T,
    const float* __restrict__ blk_b2, const unsigned short* __restrict__ poutT,
    const float* __restrict__ pout_b, float* __restrict__ hbuf,
    unsigned short* __restrict__ zlnbf, unsigned short* __restrict__ z1bf,
    float* __restrict__ part, unsigned short* __restrict__ hbufbf,
    unsigned short* __restrict__ projb, int* __restrict__ bar) {
    __shared__ unsigned short As[32 * LDP];
    __shared__ unsigned short Bs[64 * LDP];
    int b = blockIdx.x;
    int ph = 0;
    f32x4 acc[2];
    const f32x4 zz = {0.f, 0.f, 0.f, 0.f};

    // P0: pin split-K partials (M=256, N=512, K=256; 64 tiles x S=4)
    {
        int s = b >> 6, t = b & 63;
        int m0 = (t >> 3) * 32, n0 = (t & 7) * 64;
        acc[0] = zz; acc[1] = zz;
        gemm32x64(pertbf, GDIM, pinT, GDIM, m0, n0, s * 64, 64, As, Bs, acc);
        epi32x64_f32(acc, part + (size_t)s * BSZ * HID, HID, m0, n0);
    }
    gsync(bar, ++ph * HGRID);
    // P1: reduce + pin_b + LN(block0)
    if (b < 64) redln_dev<false, true>(part, pin_b, blk_ln_s, blk_ln_b, hbuf, zlnbf);
    gsync(bar, ++ph * HGRID);

    for (int i = 0; i < 6; i++) {
        {   // A: z1 = gelu(zln @ w1 + b1)   (M=256, N=2048, K=512; 8x32 tiles)
            int m0 = (b >> 5) * 32, n0 = (b & 31) * 64;
            acc[0] = zz; acc[1] = zz;
            gemm32x64(zlnbf, HID, w1T + (size_t)i * INNER * HID, HID, m0, n0, 0, HID, As, Bs,
                      acc);
            epi32x64_bf<2>(acc, blk_b1 + (size_t)i * INNER, z1bf, INNER, m0, n0);
        }
        gsync(bar, ++ph * HGRID);
        {   // B: part[s] = z1 @ w2 K-chunk  (M=256, N=512, K=2048; 64 tiles x S=4)
            int s = b >> 6, t = b & 63;
            int m0 = (t >> 3) * 32, n0 = (t & 7) * 64;
            acc[0] = zz; acc[1] = zz;
            gemm32x64(z1bf, INNER, w2T + (size_t)i * HID * INNER, INNER, m0, n0, s * 512, 512,
                      As, Bs, acc);
            epi32x64_f32(acc, part + (size_t)s * BSZ * HID, HID, m0, n0);
        }
        gsync(bar, ++ph * HGRID);
        // C: h += sum(part) + b2  (+LN for next layer / bf16 out for last)
        if (b < 64) {
            if (i < 5)
                redln_dev<true, true>(part, blk_b2 + (size_t)i * HID,
                                      blk_ln_s + (size_t)(i + 1) * HID,
                                      blk_ln_b + (size_t)(i + 1) * HID, hbuf, zlnbf);
            else
                redln_dev<true, false>(part, blk_b2 + (size_t)i * HID, nullptr, nullptr, hbuf,
                                       hbufbf);
        }
        gsync(bar, ++ph * HGRID);
    }

    // P2: proj = h @ pout + b (M=256, N=1536, K=512; 8x24=192 tiles)
    if (b < 192) {
        int m0 = (b / 24) * 32, n0 = (b % 24) * 64;
        acc[0] = zz; acc[1] = zz;
        gemm32x64(hbufbf, HID, poutT, HID, m0, n0, 0, HID, As, Bs, acc);
        epi32x64_bf<0>(acc, pout_b, projb, NCLS * RANK, m0, n0);
    }
}

// ---------------- launch ----------------
extern "C" void kernel_launch(void* const* d_in, const int* in_sizes, int n_in,
                              void* d_out, int out_size, void* d_ws, size_t ws_size,
                              hipStream_t stream) {
    const int* node_indices = (const int*)d_in[0];
    const int* edge_src = (const int*)d_in[1];
    const int* edge_dst = edge_src + NEDGES;
    const float* edge_w = (const float*)d_in[2];
    const float* partial_emb = (const float*)d_in[3];
    const float* oov_emb = (const float*)d_in[4];
    const float* gnn_ln_s = (const float*)d_in[5];
    const float* gnn_ln_b = (const float*)d_in[6];
    const float* gnn_w = (const float*)d_in[7];
    const float* gnn_b = (const float*)d_in[8];
    const float* post_w = (const float*)d_in[9];
    const float* post_b = (const float*)d_in[10];
    const float* pin_w = (const float*)d_in[11];
    const float* pin_b = (const float*)d_in[12];
    const float* blk_ln_s = (const float*)d_in[13];
    const float* blk_ln_b = (const float*)d_in[14];
    const float* blk_w1 = (const float*)d_in[15];
    const float* blk_b1 = (const float*)d_in[16];
    const float* blk_w2 = (const float*)d_in[17];
    const float* blk_b2 = (const float*)d_in[18];
    const float* pout_w = (const float*)d_in[19];
    const float* pout_b = (const float*)d_in[20];
    const float* gene = (const float*)d_in[21];
    float* out = (float*)d_out;

    char* p = (char*)d_ws;
    auto alloc = [&](size_t bytes) {
        char* r = p;
        p += (bytes + 255) & ~(size_t)255;
        return r;
    };
    int* counts = (int*)alloc(NNODES * 4);
    int* incl = (int*)alloc(NNODES * 4);
    int* bsums = (int*)alloc(128 * 4);
    int* boffs = (int*)alloc(128 * 4);
    int* row_start = (int*)alloc(NNODES * 4);
    int* cursor = (int*)alloc(NNODES * 4);
    int2* epack = (int2*)alloc((size_t)NEDGES * 8);
    // 'part': GNN phase = ln_bf + aggbf (bf16); head phase = split-K fp32 partials (4x256x512)
    float* part = (float*)alloc((size_t)NNODES * GDIM * 4);
    unsigned short* ln_bf = (unsigned short*)part;
    unsigned short* aggbf = (unsigned short*)((char*)part + (size_t)NNODES * GDIM * 2);
    float* xa = (float*)alloc((size_t)NNODES * GDIM * 4);
    float* xb = (float*)alloc((size_t)NNODES * GDIM * 4);
    float* hbuf = (float*)alloc((size_t)BSZ * HID * 4);
    unsigned short* aggselb = (unsigned short*)alloc((size_t)BSZ * GDIM * 2);
    unsigned short* pertinbf = (unsigned short*)alloc((size_t)BSZ * GDIM * 2);
    unsigned short* pertbf = (unsigned short*)alloc((size_t)BSZ * GDIM * 2);
    unsigned short* zlnbf = (unsigned short*)alloc((size_t)BSZ * HID * 2);
    unsigned short* z1bf = (unsigned short*)alloc((size_t)BSZ * INNER * 2);
    unsigned short* hbufbf = (unsigned short*)alloc((size_t)BSZ * HID * 2);
    unsigned short* projb = (unsigned short*)alloc((size_t)BSZ * NCLS * RANK * 2);
    unsigned short* gnnT = (unsigned short*)alloc((size_t)3 * GDIM * GDIM * 2);
    unsigned short* postT = (unsigned short*)alloc((size_t)GDIM * GDIM * 2);
    unsigned short* pinT = (unsigned short*)alloc((size_t)HID * GDIM * 2);
    unsigned short* w1T = (unsigned short*)alloc((size_t)6 * INNER * HID * 2);
    unsigned short* w2T = (unsigned short*)alloc((size_t)6 * HID * INNER * 2);
    unsigned short* poutT = (unsigned short*)alloc((size_t)NCLS * RANK * HID * 2);
    unsigned short* geneb = (unsigned short*)alloc((size_t)NGENES * RANK * 2);
    int* bar = (int*)alloc(256);

    const int EB = (NEDGES + 255) / 256;
    const int NB = (NNODES + 255) / 256;

    // all weight conversions in one dispatch
    convall_k<<<15100, 256, 0, stream>>>(gnn_w, post_w, pin_w, blk_w1, blk_w2, pout_w, gene,
                                         gnnT, postT, pinT, w1T, w2T, poutT, geneb);

    // CSR build
    hipMemsetAsync(counts, 0, NNODES * 4, stream);
    hipMemsetAsync(bar, 0, 4, stream);
    hist_k<<<EB, 256, 0, stream>>>(edge_dst, counts, NEDGES);
    scan1_k<<<NB, 256, 0, stream>>>(counts, incl, bsums, NNODES);
    scan2_k<<<1, 128, 0, stream>>>(bsums, boffs, NB);
    scan3_k<<<NB, 256, 0, stream>>>(incl, counts, boffs, row_start, cursor, NNODES);
    scatter_k<<<EB, 256, 0, stream>>>(edge_src, edge_dst, edge_w, cursor, epack, NEDGES);

    // GNN layers 1 & 2 (full), layer 3 (selective)
    const float* x_in = partial_emb;
    float* bufs[2] = {xa, xb};
    for (int i = 0; i < 2; i++) {
        lnb_k<<<(NNODES + 3) / 4, 256, 0, stream>>>(x_in, gnn_ln_s + i * GDIM,
                                                    gnn_ln_b + i * GDIM, ln_bf, NNODES);
        aggb_k<<<(NNODES + 3) / 4, 256, 0, stream>>>(row_start, counts, epack, ln_bf, aggbf,
                                                     NNODES);
        float* x_out = bufs[i];
        mgemm_k<1, true, true><<<dim3(GDIM / 128, (NNODES + 127) / 128), 256, 0, stream>>>(
            aggbf, gnnT + (size_t)i * GDIM * GDIM, gnn_b + i * GDIM, x_in, x_out, NNODES, GDIM,
            GDIM);
        x_in = x_out;
    }
    lnb_k<<<(NNODES + 3) / 4, 256, 0, stream>>>(xb, gnn_ln_s + 2 * GDIM, gnn_ln_b + 2 * GDIM,
                                                ln_bf, NNODES);
    aggsel_k<<<BSZ / 4, 256, 0, stream>>>(node_indices, row_start, counts, epack, ln_bf, aggselb);
    mfull_k<1, 2><<<dim3(GDIM / 64, BSZ / 64), 256, 0, stream>>>(
        aggselb, gnnT + (size_t)2 * GDIM * GDIM, gnn_b + 2 * GDIM, node_indices, xb, pertinbf,
        BSZ, GDIM, GDIM);

    // post_mp + OOV replace (fused)
    mfull_k<0, 1><<<dim3(GDIM / 64, BSZ / 64), 256, 0, stream>>>(
        pertinbf, postT, post_b, node_indices, oov_emb, pertbf, BSZ, GDIM, GDIM);

    // fused head: pin + 6 blocks + pout in ONE persistent kernel
    head_k<<<HGRID, 256, 0, stream>>>(pertbf, pinT, pin_b, blk_ln_s, blk_ln_b, w1T, blk_b1, w2T,
                                      blk_b2, poutT, pout_b, hbuf, zlnbf, z1bf, part, hbufbf,
                                      projb, bar);

    // logits
    mgemm_k<0, false, false><<<dim3((NGENES + 127) / 128, (BSZ * NCLS) / 128), 256, 0, stream>>>(
        projb, geneb, nullptr, nullptr, out, BSZ * NCLS, NGENES, RANK);
}

// Round 2
// 805.849 us; speedup vs baseline: 1.2421x; 1.2421x over previous
//
#include <hip/hip_runtime.h>
#include <hip/hip_bf16.h>
#include <math.h>

#define NNODES 20000
#define NEDGES 640000
#define BSZ 256
#define GDIM 256
#define HID 512
#define INNER 2048
#define RANK 512
#define NCLS 3
#define NGENES 6640

typedef __attribute__((ext_vector_type(8))) short bf16x8;
typedef __attribute__((ext_vector_type(4))) float f32x4;

__device__ inline float bf2f(unsigned short u) {
    return __uint_as_float(((unsigned)u) << 16);
}
__device__ inline unsigned short f2bf(float f) {
    unsigned u = __float_as_uint(f);
    u = u + 0x7fff + ((u >> 16) & 1);   // RNE
    return (unsigned short)(u >> 16);
}

// ---------------- CSR build ----------------
__global__ void hist_k(const int* __restrict__ dst, int* __restrict__ counts, int E) {
    int e = blockIdx.x * 256 + threadIdx.x;
    if (e < E) atomicAdd(&counts[dst[e]], 1);
}

__global__ void scan1_k(const int* __restrict__ counts, int* __restrict__ incl,
                        int* __restrict__ bsums, int n) {
    __shared__ int s[256];
    int i = blockIdx.x * 256 + threadIdx.x;
    int v = (i < n) ? counts[i] : 0;
    s[threadIdx.x] = v;
    __syncthreads();
    for (int off = 1; off < 256; off <<= 1) {
        int t = (threadIdx.x >= off) ? s[threadIdx.x - off] : 0;
        __syncthreads();
        s[threadIdx.x] += t;
        __syncthreads();
    }
    if (i < n) incl[i] = s[threadIdx.x];
    if (threadIdx.x == 255) bsums[blockIdx.x] = s[255];
}

__global__ void scan2_k(const int* __restrict__ bsums, int* __restrict__ boffs, int nb) {
    __shared__ int s[128];
    int tid = threadIdx.x;
    int v = (tid < nb) ? bsums[tid] : 0;
    s[tid] = v;
    __syncthreads();
    for (int off = 1; off < 128; off <<= 1) {
        int t = (tid >= off) ? s[tid - off] : 0;
        __syncthreads();
        s[tid] += t;
        __syncthreads();
    }
    if (tid < nb) boffs[tid] = s[tid] - v;
}

__global__ void scan3_k(const int* __restrict__ incl, const int* __restrict__ counts,
                        const int* __restrict__ boffs, int* __restrict__ row_start,
                        int* __restrict__ cursor, int n) {
    int i = blockIdx.x * 256 + threadIdx.x;
    if (i < n) {
        int st = incl[i] - counts[i] + boffs[blockIdx.x];
        row_start[i] = st;
        cursor[i] = st;
    }
}

__global__ void scatter_k(const int* __restrict__ src, const int* __restrict__ dst,
                          const float* __restrict__ w, int* __restrict__ cursor,
                          int2* __restrict__ ep, int E) {
    int e = blockIdx.x * 256 + threadIdx.x;
    if (e < E) {
        int d = dst[e];
        int p = atomicAdd(&cursor[d], 1);
        ep[p] = make_int2(src[e], __float_as_int(w[e]));
    }
}

// ---------------- combined weight conversion (replaces 7 kernels) ----------------
// block ranges: gnn 0-191, post 192-255, pin 256-383, w1 384-6527,
//               w2 6528-12671, pout 12672-13439, gene 13440-15099
__global__ void convall_k(const float* __restrict__ gnn_w, const float* __restrict__ post_w,
                          const float* __restrict__ pin_w, const float* __restrict__ blk_w1,
                          const float* __restrict__ blk_w2, const float* __restrict__ pout_w,
                          const float* __restrict__ gene, unsigned short* __restrict__ gnnT,
                          unsigned short* __restrict__ postT, unsigned short* __restrict__ pinT,
                          unsigned short* __restrict__ w1T, unsigned short* __restrict__ w2T,
                          unsigned short* __restrict__ poutT,
                          unsigned short* __restrict__ geneb) {
    int b = blockIdx.x;
    if (b >= 13440) {   // gene: plain fp32 -> bf16 convert, 2048 elems/block
        int t = b - 13440;
        const float4* xp = (const float4*)gene;
        int i = t * 512 + threadIdx.x * 2;    // float4 index
        float4 a = xp[i], c = xp[i + 1];
        *(ushort4*)(geneb + (size_t)i * 4) =
            make_ushort4(f2bf(a.x), f2bf(a.y), f2bf(a.z), f2bf(a.w));
        *(ushort4*)(geneb + (size_t)i * 4 + 4) =
            make_ushort4(f2bf(c.x), f2bf(c.y), f2bf(c.z), f2bf(c.w));
        return;
    }
    const float* W;
    unsigned short* WT;
    int K, N, tile;
    if (b < 192) {
        int l = b >> 6;
        tile = b & 63;
        W = gnn_w + (size_t)l * GDIM * GDIM;
        WT = gnnT + (size_t)l * GDIM * GDIM;
        K = GDIM; N = GDIM;
    } else if (b < 256) {
        tile = b - 192; W = post_w; WT = postT; K = GDIM; N = GDIM;
    } else if (b < 384) {
        tile = b - 256; W = pin_w; WT = pinT; K = GDIM; N = HID;
    } else if (b < 6528) {
        int t = b - 384;
        int l = t >> 10;
        tile = t & 1023;
        W = blk_w1 + (size_t)l * HID * INNER;
        WT = w1T + (size_t)l * INNER * HID;
        K = HID; N = INNER;
    } else if (b < 12672) {
        int t = b - 6528;
        int l = t >> 10;
        tile = t & 1023;
        W = blk_w2 + (size_t)l * INNER * HID;
        WT = w2T + (size_t)l * HID * INNER;
        K = INNER; N = HID;
    } else {
        tile = b - 12672; W = pout_w; WT = poutT; K = HID; N = NCLS * RANK;
    }
    __shared__ float s[32][33];
    int ntx = N >> 5;
    int k0 = (tile / ntx) << 5;
    int n0 = (tile % ntx) << 5;
    int tx = threadIdx.x & 31, ty = threadIdx.x >> 5;
#pragma unroll
    for (int i = 0; i < 4; i++)
        s[ty + 8 * i][tx] = W[(size_t)(k0 + ty + 8 * i) * N + n0 + tx];
    __syncthreads();
#pragma unroll
    for (int i = 0; i < 4; i++)
        WT[(size_t)(n0 + ty + 8 * i) * K + k0 + tx] = f2bf(s[tx][ty + 8 * i]);
}

// ---------------- GNN LayerNorm (D=256), bf16 out ----------------
__global__ void lnb_k(const float* __restrict__ X, const float* __restrict__ sc,
                      const float* __restrict__ bi, unsigned short* __restrict__ Y, int M) {
    int row = blockIdx.x * 4 + (threadIdx.x >> 6);
    int lane = threadIdx.x & 63;
    if (row >= M) return;
    float4 v = ((const float4*)(X + (size_t)row * GDIM))[lane];
    float sum = v.x + v.y + v.z + v.w;
#pragma unroll
    for (int off = 32; off >= 1; off >>= 1) sum += __shfl_xor(sum, off);
    float mu = sum / GDIM;
    float a = v.x - mu, b = v.y - mu, c = v.z - mu, d = v.w - mu;
    float sq = a * a + b * b + c * c + d * d;
#pragma unroll
    for (int off = 32; off >= 1; off >>= 1) sq += __shfl_xor(sq, off);
    float rstd = rsqrtf(sq / GDIM + 1e-5f);
    float4 s4 = ((const float4*)sc)[lane];
    float4 b4 = ((const float4*)bi)[lane];
    *(ushort4*)(Y + (size_t)row * GDIM + lane * 4) =
        make_ushort4(f2bf(a * rstd * s4.x + b4.x), f2bf(b * rstd * s4.y + b4.y),
                     f2bf(c * rstd * s4.z + b4.z), f2bf(d * rstd * s4.w + b4.w));
}

// ---------------- CSR aggregation, 16-deep MLP unroll ----------------
__device__ inline void agg_row(int beg, int cnt, int lane, const int2* __restrict__ ep,
                               const unsigned short* __restrict__ H, float& a0, float& a1,
                               float& a2, float& a3) {
    int t = 0;
    for (; t + 16 <= cnt; t += 16) {
        int2 e[16];
#pragma unroll
        for (int u = 0; u < 16; u++) e[u] = ep[beg + t + u];
        ushort4 v[16];
#pragma unroll
        for (int u = 0; u < 16; u++)
            v[u] = *(const ushort4*)(H + (size_t)e[u].x * GDIM + lane * 4);
#pragma unroll
        for (int u = 0; u < 16; u++) {
            float w = __int_as_float(e[u].y);
            a0 = fmaf(bf2f(v[u].x), w, a0);
            a1 = fmaf(bf2f(v[u].y), w, a1);
            a2 = fmaf(bf2f(v[u].z), w, a2);
            a3 = fmaf(bf2f(v[u].w), w, a3);
        }
    }
    for (; t + 4 <= cnt; t += 4) {
        int2 e[4];
#pragma unroll
        for (int u = 0; u < 4; u++) e[u] = ep[beg + t + u];
        ushort4 v[4];
#pragma unroll
        for (int u = 0; u < 4; u++)
            v[u] = *(const ushort4*)(H + (size_t)e[u].x * GDIM + lane * 4);
#pragma unroll
        for (int u = 0; u < 4; u++) {
            float w = __int_as_float(e[u].y);
            a0 = fmaf(bf2f(v[u].x), w, a0);
            a1 = fmaf(bf2f(v[u].y), w, a1);
            a2 = fmaf(bf2f(v[u].z), w, a2);
            a3 = fmaf(bf2f(v[u].w), w, a3);
        }
    }
    for (; t < cnt; t++) {
        int2 e = ep[beg + t];
        float w = __int_as_float(e.y);
        ushort4 v = *(const ushort4*)(H + (size_t)e.x * GDIM + lane * 4);
        a0 = fmaf(bf2f(v.x), w, a0);
        a1 = fmaf(bf2f(v.y), w, a1);
        a2 = fmaf(bf2f(v.z), w, a2);
        a3 = fmaf(bf2f(v.w), w, a3);
    }
}

__global__ void aggb_k(const int* __restrict__ row_start, const int* __restrict__ counts,
                       const int2* __restrict__ ep, const unsigned short* __restrict__ H,
                       unsigned short* __restrict__ AGG, int n) {
    int row = blockIdx.x * 4 + (threadIdx.x >> 6);
    int lane = threadIdx.x & 63;
    if (row >= n) return;
    float a0 = 0.f, a1 = 0.f, a2 = 0.f, a3 = 0.f;
    agg_row(row_start[row], counts[row], lane, ep, H, a0, a1, a2, a3);
    *(ushort4*)(AGG + (size_t)row * GDIM + lane * 4) =
        make_ushort4(f2bf(a0), f2bf(a1), f2bf(a2), f2bf(a3));
}

__global__ void aggsel_k(const int* __restrict__ idx, const int* __restrict__ row_start,
                         const int* __restrict__ counts, const int2* __restrict__ ep,
                         const unsigned short* __restrict__ H, unsigned short* __restrict__ AGG) {
    int b = blockIdx.x * 4 + (threadIdx.x >> 6);
    int lane = threadIdx.x & 63;
    int id = idx[b];
    int row = id < 0 ? 0 : id;
    float a0 = 0.f, a1 = 0.f, a2 = 0.f, a3 = 0.f;
    agg_row(row_start[row], counts[row], lane, ep, H, a0, a1, a2, a3);
    *(ushort4*)(AGG + (size_t)b * GDIM + lane * 4) =
        make_ushort4(f2bf(a0), f2bf(a1), f2bf(a2), f2bf(a3));
}

// ---------------- bf16 MFMA GEMM (full-K, fp32 out, fused epilogue) — GNN L1/L2 & logits ----------------
template <int ACT, bool RES, bool BIAS>
__global__ __launch_bounds__(256) void mgemm_k(const unsigned short* __restrict__ A,
                                               const unsigned short* __restrict__ BT,
                                               const float* __restrict__ bias,
                                               const float* __restrict__ R,
                                               float* __restrict__ C, int M, int N, int K) {
    __shared__ unsigned short As[128 * 32];
    __shared__ unsigned short Bs[128 * 32];
    int m0 = blockIdx.y * 128, n0 = blockIdx.x * 128;
    int tid = threadIdx.x;
    int wave = tid >> 6, lane = tid & 63;
    int wm = (wave >> 1) * 64, wn = (wave & 1) * 64;
    int lrow = lane & 15, lq = lane >> 4;

    f32x4 acc[4][4];
    const f32x4 zz = {0.f, 0.f, 0.f, 0.f};
#pragma unroll
    for (int i = 0; i < 4; i++)
#pragma unroll
        for (int j = 0; j < 4; j++) acc[i][j] = zz;

    int r0 = tid >> 2;
    int q = tid & 3;

    for (int k0 = 0; k0 < K; k0 += 32) {
#pragma unroll
        for (int p = 0; p < 2; p++) {
            int row = r0 + p * 64;
            int gm = m0 + row;
            uint4 va = make_uint4(0, 0, 0, 0);
            if (gm < M) va = *(const uint4*)(A + (size_t)gm * K + k0 + q * 8);
            *(uint4*)&As[row * 32 + q * 8] = va;
            int gn = n0 + row;
            uint4 vb = make_uint4(0, 0, 0, 0);
            if (gn < N) vb = *(const uint4*)(BT + (size_t)gn * K + k0 + q * 8);
            *(uint4*)&Bs[row * 32 + q * 8] = vb;
        }
        __syncthreads();
        bf16x8 af[4], bf[4];
#pragma unroll
        for (int i = 0; i < 4; i++)
            af[i] = *(const bf16x8*)&As[(wm + i * 16 + lrow) * 32 + lq * 8];
#pragma unroll
        for (int j = 0; j < 4; j++)
            bf[j] = *(const bf16x8*)&Bs[(wn + j * 16 + lrow) * 32 + lq * 8];
#pragma unroll
        for (int i = 0; i < 4; i++)
#pragma unroll
            for (int j = 0; j < 4; j++)
                acc[i][j] =
                    __builtin_amdgcn_mfma_f32_16x16x32_bf16(af[i], bf[j], acc[i][j], 0, 0, 0);
        __syncthreads();
    }

#pragma unroll
    for (int i = 0; i < 4; i++) {
#pragma unroll
        for (int j = 0; j < 4; j++) {
            int gn = n0 + wn + j * 16 + lrow;
            if (gn >= N) continue;
            float bv = BIAS ? bias[gn] : 0.f;
#pragma unroll
            for (int r = 0; r < 4; r++) {
                int gm = m0 + wm + i * 16 + lq * 4 + r;
                if (gm >= M) continue;
                float v = acc[i][j][r] + bv;
                if (ACT == 1) v = fmaxf(v, 0.f);
                if (RES) v += R[(size_t)gm * N + gn];
                C[(size_t)gm * N + gn] = v;
            }
        }
    }
}

// ---------------- bf16 MFMA full-K, bf16 out, fused epilogue (GNN L3 / post) ----------------
template <int ACT, int EPI>
__global__ __launch_bounds__(256) void mfull_k(const unsigned short* __restrict__ A,
                                               const unsigned short* __restrict__ BT,
                                               const float* __restrict__ bias,
                                               const int* __restrict__ idx,
                                               const float* __restrict__ aux,
                                               unsigned short* __restrict__ O, int M, int N,
                                               int K) {
    __shared__ unsigned short As[64 * 32];
    __shared__ unsigned short Bs[64 * 32];
    int m0 = blockIdx.y * 64, n0 = blockIdx.x * 64;
    int tid = threadIdx.x;
    int wave = tid >> 6, lane = tid & 63;
    int wm = wave * 16;
    int lrow = lane & 15, lq = lane >> 4;
    f32x4 acc[4];
    const f32x4 zz = {0.f, 0.f, 0.f, 0.f};
#pragma unroll
    for (int j = 0; j < 4; j++) acc[j] = zz;
    int r0 = tid >> 2;
    int q = tid & 3;
    for (int k0 = 0; k0 < K; k0 += 32) {
        *(uint4*)&As[r0 * 32 + q * 8] = *(const uint4*)(A + (size_t)(m0 + r0) * K + k0 + q * 8);
        *(uint4*)&Bs[r0 * 32 + q * 8] = *(const uint4*)(BT + (size_t)(n0 + r0) * K + k0 + q * 8);
        __syncthreads();
        bf16x8 af = *(const bf16x8*)&As[(wm + lrow) * 32 + lq * 8];
#pragma unroll
        for (int j = 0; j < 4; j++) {
            bf16x8 bfr = *(const bf16x8*)&Bs[(j * 16 + lrow) * 32 + lq * 8];
            acc[j] = __builtin_amdgcn_mfma_f32_16x16x32_bf16(af, bfr, acc[j], 0, 0, 0);
        }
        __syncthreads();
    }
#pragma unroll
    for (int j = 0; j < 4; j++) {
        int gn = n0 + j * 16 + lrow;
        float bv = bias[gn];
#pragma unroll
        for (int r = 0; r < 4; r++) {
            int gm = m0 + wm + lq * 4 + r;
            float v = acc[j][r] + bv;
            if (ACT == 1) v = fmaxf(v, 0.f);
            if (ACT == 2) v = 0.5f * v * (1.f + erff(v * 0.70710678118654752f));
            if (EPI == 2) {
                int id = idx[gm];
                int safe = id < 0 ? 0 : id;
                v += aux[(size_t)safe * N + gn];
            }
            if (EPI == 1) {
                if (idx[gm] < 0) v = aux[gn];
            }
            O[(size_t)gm * N + gn] = f2bf(v);
        }
    }
}

// ================= fused persistent head =================
// grid = 256 blocks x 256 threads, guaranteed co-resident (256 CUs, 1 block/CU floor),
// homebrew device-scope barrier (graph-capture-safe, no cooperative launch).

#define HGRID 256
#define LDP 72   // padded LDS row stride (ushort): keeps ds_read_b128 conflict-free at BK=64

// Grid barrier. CRITICAL on multi-XCD gfx950: poll with RELAXED agent loads
// (cache-bypassing, NO L2 invalidate). An ACQUIRE poll invalidates the XCD's
// L2 every iteration (256 blocks spinning -> all 8 L2s perpetually empty ->
// every phase load becomes an HBM miss; measured 28us/barrier in round 1).
// One acquire AFTER the spin exits provides the needed ordering.
__device__ inline void gsync(int* bar, int target) {
    __syncthreads();
    if (threadIdx.x == 0) {
        // RELEASE add: waitcnt + L2 writeback of this block's prior stores.
        __hip_atomic_fetch_add(bar, 1, __ATOMIC_RELEASE, __HIP_MEMORY_SCOPE_AGENT);
        while (__hip_atomic_load(bar, __ATOMIC_RELAXED, __HIP_MEMORY_SCOPE_AGENT) < target)
            __builtin_amdgcn_s_sleep(8);
        // single acquire: invalidate L1/L2 once so phase N+1 sees phase N's data
        (void)__hip_atomic_load(bar, __ATOMIC_ACQUIRE, __HIP_MEMORY_SCOPE_AGENT);
    }
    __syncthreads();
}

// 32x64 tile GEMM, BK=64, reg-double-buffered staging (issue-early / write-late).
// waves 2x2: each wave 16 rows x 32 cols (2 j-frags).
__device__ inline void gemm32x64(const unsigned short* __restrict__ A, int lda,
                                 const unsigned short* __restrict__ BT, int ldb, int m0, int n0,
                                 int kbeg, int kcnt, unsigned short* As, unsigned short* Bs,
                                 f32x4 acc[2]) {
    int tid = threadIdx.x;
    int wave = tid >> 6, lane = tid & 63;
    int wm = (wave >> 1) * 16, wn = (wave & 1) * 32;
    int lrow = lane & 15, lq = lane >> 4;
    int rb = tid >> 2, qb = tid & 3;   // B rows 0..63
    int ra = rb & 31;                  // A rows 0..31 (tid<128)
    const unsigned short* bp = BT + (size_t)(n0 + rb) * ldb + kbeg + qb * 16;
    const unsigned short* ap = A + (size_t)(m0 + ra) * lda + kbeg + qb * 16;
    uint4 vb0 = *(const uint4*)bp, vb1 = *(const uint4*)(bp + 8);
    uint4 va0 = {0, 0, 0, 0}, va1 = {0, 0, 0, 0};
    if (tid < 128) {
        va0 = *(const uint4*)ap;
        va1 = *(const uint4*)(ap + 8);
    }
    for (int k0 = 0; k0 < kcnt; k0 += 64) {
        *(uint4*)&Bs[rb * LDP + qb * 16] = vb0;
        *(uint4*)&Bs[rb * LDP + qb * 16 + 8] = vb1;
        if (tid < 128) {
            *(uint4*)&As[ra * LDP + qb * 16] = va0;
            *(uint4*)&As[ra * LDP + qb * 16 + 8] = va1;
        }
        __syncthreads();
        if (k0 + 64 < kcnt) {   // prefetch next K-slab; overlaps the MFMA section below
            vb0 = *(const uint4*)(bp + k0 + 64);
            vb1 = *(const uint4*)(bp + k0 + 72);
            if (tid < 128) {
                va0 = *(const uint4*)(ap + k0 + 64);
                va1 = *(const uint4*)(ap + k0 + 72);
            }
        }
#pragma unroll
        for (int kk = 0; kk < 2; kk++) {
            bf16x8 af = *(const bf16x8*)&As[(wm + lrow) * LDP + kk * 32 + lq * 8];
#pragma unroll
            for (int j = 0; j < 2; j++) {
                bf16x8 bfr = *(const bf16x8*)&Bs[(wn + j * 16 + lrow) * LDP + kk * 32 + lq * 8];
                acc[j] = __builtin_amdgcn_mfma_f32_16x16x32_bf16(af, bfr, acc[j], 0, 0, 0);
            }
        }
        __syncthreads();
    }
}

template <int ACT>
__device__ inline void epi32x64_bf(const f32x4 acc[2], const float* __restrict__ bias,
                                   unsigned short* __restrict__ O, int ldo, int m0, int n0) {
    int tid = threadIdx.x, wave = tid >> 6, lane = tid & 63;
    int wm = (wave >> 1) * 16, wn = (wave & 1) * 32;
    int lrow = lane & 15, lq = lane >> 4;
#pragma unroll
    for (int j = 0; j < 2; j++) {
        int gn = n0 + wn + j * 16 + lrow;
        float bv = bias[gn];
#pragma unroll
        for (int r = 0; r < 4; r++) {
            int gm = m0 + wm + lq * 4 + r;
            float v = acc[j][r] + bv;
            if (ACT == 2) v = 0.5f * v * (1.f + erff(v * 0.70710678118654752f));
            O[(size_t)gm * ldo + gn] = f2bf(v);
        }
    }
}

__device__ inline void epi32x64_f32(const f32x4 acc[2], float* __restrict__ C, int ldo, int m0,
                                    int n0) {
    int tid = threadIdx.x, wave = tid >> 6, lane = tid & 63;
    int wm = (wave >> 1) * 16, wn = (wave & 1) * 32;
    int lrow = lane & 15, lq = lane >> 4;
#pragma unroll
    for (int j = 0; j < 2; j++) {
        int gn = n0 + wn + j * 16 + lrow;
#pragma unroll
        for (int r = 0; r < 4; r++) {
            int gm = m0 + wm + lq * 4 + r;
            C[(size_t)gm * ldo + gn] = acc[j][r];
        }
    }
}

// reduce 4 split-K partials + bias (+residual) -> hbuf, optional LN -> bf16 out.
// called by blocks 0..63 (4 rows each).
template <bool RESID, bool DO_LN>
__device__ inline void redln_dev(const float* __restrict__ Cp, const float* __restrict__ bias,
                                 const float* __restrict__ ln_s, const float* __restrict__ ln_b,
                                 float* __restrict__ hbuf, unsigned short* __restrict__ outbf) {
    int row = blockIdx.x * 4 + (threadIdx.x >> 6);
    int lane = threadIdx.x & 63;
    float4 a0 = {0.f, 0.f, 0.f, 0.f}, a1 = a0;
#pragma unroll
    for (int s = 0; s < 4; s++) {
        const float4* pp = (const float4*)(Cp + ((size_t)s * BSZ + row) * HID);
        float4 b0 = pp[lane * 2], b1 = pp[lane * 2 + 1];
        a0.x += b0.x; a0.y += b0.y; a0.z += b0.z; a0.w += b0.w;
        a1.x += b1.x; a1.y += b1.y; a1.z += b1.z; a1.w += b1.w;
    }
    const float4* bb = (const float4*)bias;
    float4 c0 = bb[lane * 2], c1 = bb[lane * 2 + 1];
    a0.x += c0.x; a0.y += c0.y; a0.z += c0.z; a0.w += c0.w;
    a1.x += c1.x; a1.y += c1.y; a1.z += c1.z; a1.w += c1.w;
    float4* hp = (float4*)(hbuf + (size_t)row * HID);
    if (RESID) {
        float4 r0 = hp[lane * 2], r1 = hp[lane * 2 + 1];
        a0.x += r0.x; a0.y += r0.y; a0.z += r0.z; a0.w += r0.w;
        a1.x += r1.x; a1.y += r1.y; a1.z += r1.z; a1.w += r1.w;
    }
    hp[lane * 2] = a0;
    hp[lane * 2 + 1] = a1;
    unsigned short* op = outbf + (size_t)row * HID;
    if (DO_LN) {
        float sum = a0.x + a0.y + a0.z + a0.w + a1.x + a1.y + a1.z + a1.w;
#pragma unroll
        for (int off = 32; off >= 1; off >>= 1) sum += __shfl_xor(sum, off);
        float mu = sum / HID;
        float d0 = a0.x - mu, d1 = a0.y - mu, d2 = a0.z - mu, d3 = a0.w - mu;
        float d4 = a1.x - mu, d5 = a1.y - mu, d6 = a1.z - mu, d7 = a1.w - mu;
        float sq = d0 * d0 + d1 * d1 + d2 * d2 + d3 * d3 + d4 * d4 + d5 * d5 + d6 * d6 + d7 * d7;
#pragma unroll
        for (int off = 32; off >= 1; off >>= 1) sq += __shfl_xor(sq, off);
        float rstd = rsqrtf(sq / HID + 1e-5f);
        const float4* sp = (const float4*)ln_s;
        const float4* bp2 = (const float4*)ln_b;
        float4 s0 = sp[lane * 2], s1 = sp[lane * 2 + 1];
        float4 t0 = bp2[lane * 2], t1 = bp2[lane * 2 + 1];
        *(ushort4*)(op + lane * 8) =
            make_ushort4(f2bf(d0 * rstd * s0.x + t0.x), f2bf(d1 * rstd * s0.y + t0.y),
                         f2bf(d2 * rstd * s0.z + t0.z), f2bf(d3 * rstd * s0.w + t0.w));
        *(ushort4*)(op + lane * 8 + 4) =
            make_ushort4(f2bf(d4 * rstd * s1.x + t1.x), f2bf(d5 * rstd * s1.y + t1.y),
                         f2bf(d6 * rstd * s1.z + t1.z), f2bf(d7 * rstd * s1.w + t1.w));
    } else {
        *(ushort4*)(op + lane * 8) = make_ushort4(f2bf(a0.x), f2bf(a0.y), f2bf(a0.z), f2bf(a0.w));
        *(ushort4*)(op + lane * 8 + 4) =
            make_ushort4(f2bf(a1.x), f2bf(a1.y), f2bf(a1.z), f2bf(a1.w));
    }
}

// fused: pin(split-K)+LN0 -> 6x{w1-GELU, w2 split-K, reduce+res+LN} -> pout. 20 grid syncs.
__global__ __launch_bounds__(256) void head_k(
    const unsigned short* __restrict__ pertbf, const unsigned short* __restrict__ pinT,
    const float* __restrict__ pin_b, const float* __restrict__ blk_ln_s,
    const float* __restrict__ blk_ln_b, const unsigned short* __restrict__ w1T,
    const float* __restrict__ blk_b1, const unsigned short* __restrict__ w2T,
    const float* __restrict__ blk_b2, const unsigned short* __restrict__ poutT,
    const float* __restrict__ pout_b, float* __restrict__ hbuf,
    unsigned short* __restrict__ zlnbf, unsigned short* __restrict__ z1bf,
    float* __restrict__ part, unsigned short* __restrict__ hbufbf,
    unsigned short* __restrict__ projb, int* __restrict__ bar) {
    __shared__ unsigned short As[32 * LDP];
    __shared__ unsigned short Bs[64 * LDP];
    int b = blockIdx.x;
    int ph = 0;
    f32x4 acc[2];
    const f32x4 zz = {0.f, 0.f, 0.f, 0.f};

    // P0: pin split-K partials (M=256, N=512, K=256; 64 tiles x S=4)
    {
        int s = b >> 6, t = b & 63;
        int m0 = (t >> 3) * 32, n0 = (t & 7) * 64;
        acc[0] = zz; acc[1] = zz;
        gemm32x64(pertbf, GDIM, pinT, GDIM, m0, n0, s * 64, 64, As, Bs, acc);
        epi32x64_f32(acc, part + (size_t)s * BSZ * HID, HID, m0, n0);
    }
    gsync(bar, ++ph * HGRID);
    // P1: reduce + pin_b + LN(block0)
    if (b < 64) redln_dev<false, true>(part, pin_b, blk_ln_s, blk_ln_b, hbuf, zlnbf);
    gsync(bar, ++ph * HGRID);

    for (int i = 0; i < 6; i++) {
        {   // A: z1 = gelu(zln @ w1 + b1)   (M=256, N=2048, K=512; 8x32 tiles)
            int m0 = (b >> 5) * 32, n0 = (b & 31) * 64;
            acc[0] = zz; acc[1] = zz;
            gemm32x64(zlnbf, HID, w1T + (size_t)i * INNER * HID, HID, m0, n0, 0, HID, As, Bs,
                      acc);
            epi32x64_bf<2>(acc, blk_b1 + (size_t)i * INNER, z1bf, INNER, m0, n0);
        }
        gsync(bar, ++ph * HGRID);
        {   // B: part[s] = z1 @ w2 K-chunk  (M=256, N=512, K=2048; 64 tiles x S=4)
            int s = b >> 6, t = b & 63;
            int m0 = (t >> 3) * 32, n0 = (t & 7) * 64;
            acc[0] = zz; acc[1] = zz;
            gemm32x64(z1bf, INNER, w2T + (size_t)i * HID * INNER, INNER, m0, n0, s * 512, 512,
                      As, Bs, acc);
            epi32x64_f32(acc, part + (size_t)s * BSZ * HID, HID, m0, n0);
        }
        gsync(bar, ++ph * HGRID);
        // C: h += sum(part) + b2  (+LN for next layer / bf16 out for last)
        if (b < 64) {
            if (i < 5)
                redln_dev<true, true>(part, blk_b2 + (size_t)i * HID,
                                      blk_ln_s + (size_t)(i + 1) * HID,
                                      blk_ln_b + (size_t)(i + 1) * HID, hbuf, zlnbf);
            else
                redln_dev<true, false>(part, blk_b2 + (size_t)i * HID, nullptr, nullptr, hbuf,
                                       hbufbf);
        }
        gsync(bar, ++ph * HGRID);
    }

    // P2: proj = h @ pout + b (M=256, N=1536, K=512; 8x24=192 tiles)
    if (b < 192) {
        int m0 = (b / 24) * 32, n0 = (b % 24) * 64;
        acc[0] = zz; acc[1] = zz;
        gemm32x64(hbufbf, HID, poutT, HID, m0, n0, 0, HID, As, Bs, acc);
        epi32x64_bf<0>(acc, pout_b, projb, NCLS * RANK, m0, n0);
    }
}

// ---------------- launch ----------------
extern "C" void kernel_launch(void* const* d_in, const int* in_sizes, int n_in,
                              void* d_out, int out_size, void* d_ws, size_t ws_size,
                              hipStream_t stream) {
    const int* node_indices = (const int*)d_in[0];
    const int* edge_src = (const int*)d_in[1];
    const int* edge_dst = edge_src + NEDGES;
    const float* edge_w = (const float*)d_in[2];
    const float* partial_emb = (const float*)d_in[3];
    const float* oov_emb = (const float*)d_in[4];
    const float* gnn_ln_s = (const float*)d_in[5];
    const float* gnn_ln_b = (const float*)d_in[6];
    const float* gnn_w = (const float*)d_in[7];
    const float* gnn_b = (const float*)d_in[8];
    const float* post_w = (const float*)d_in[9];
    const float* post_b = (const float*)d_in[10];
    const float* pin_w = (const float*)d_in[11];
    const float* pin_b = (const float*)d_in[12];
    const float* blk_ln_s = (const float*)d_in[13];
    const float* blk_ln_b = (const float*)d_in[14];
    const float* blk_w1 = (const float*)d_in[15];
    const float* blk_b1 = (const float*)d_in[16];
    const float* blk_w2 = (const float*)d_in[17];
    const float* blk_b2 = (const float*)d_in[18];
    const float* pout_w = (const float*)d_in[19];
    const float* pout_b = (const float*)d_in[20];
    const float* gene = (const float*)d_in[21];
    float* out = (float*)d_out;

    char* p = (char*)d_ws;
    auto alloc = [&](size_t bytes) {
        char* r = p;
        p += (bytes + 255) & ~(size_t)255;
        return r;
    };
    int* counts = (int*)alloc(NNODES * 4);
    int* incl = (int*)alloc(NNODES * 4);
    int* bsums = (int*)alloc(128 * 4);
    int* boffs = (int*)alloc(128 * 4);
    int* row_start = (int*)alloc(NNODES * 4);
    int* cursor = (int*)alloc(NNODES * 4);
    int2* epack = (int2*)alloc((size_t)NEDGES * 8);
    // 'part': GNN phase = ln_bf + aggbf (bf16); head phase = split-K fp32 partials (4x256x512)
    float* part = (float*)alloc((size_t)NNODES * GDIM * 4);
    unsigned short* ln_bf = (unsigned short*)part;
    unsigned short* aggbf = (unsigned short*)((char*)part + (size_t)NNODES * GDIM * 2);
    float* xa = (float*)alloc((size_t)NNODES * GDIM * 4);
    float* xb = (float*)alloc((size_t)NNODES * GDIM * 4);
    float* hbuf = (float*)alloc((size_t)BSZ * HID * 4);
    unsigned short* aggselb = (unsigned short*)alloc((size_t)BSZ * GDIM * 2);
    unsigned short* pertinbf = (unsigned short*)alloc((size_t)BSZ * GDIM * 2);
    unsigned short* pertbf = (unsigned short*)alloc((size_t)BSZ * GDIM * 2);
    unsigned short* zlnbf = (unsigned short*)alloc((size_t)BSZ * HID * 2);
    unsigned short* z1bf = (unsigned short*)alloc((size_t)BSZ * INNER * 2);
    unsigned short* hbufbf = (unsigned short*)alloc((size_t)BSZ * HID * 2);
    unsigned short* projb = (unsigned short*)alloc((size_t)BSZ * NCLS * RANK * 2);
    unsigned short* gnnT = (unsigned short*)alloc((size_t)3 * GDIM * GDIM * 2);
    unsigned short* postT = (unsigned short*)alloc((size_t)GDIM * GDIM * 2);
    unsigned short* pinT = (unsigned short*)alloc((size_t)HID * GDIM * 2);
    unsigned short* w1T = (unsigned short*)alloc((size_t)6 * INNER * HID * 2);
    unsigned short* w2T = (unsigned short*)alloc((size_t)6 * HID * INNER * 2);
    unsigned short* poutT = (unsigned short*)alloc((size_t)NCLS * RANK * HID * 2);
    unsigned short* geneb = (unsigned short*)alloc((size_t)NGENES * RANK * 2);
    int* bar = (int*)alloc(256);

    const int EB = (NEDGES + 255) / 256;
    const int NB = (NNODES + 255) / 256;

    // all weight conversions in one dispatch
    convall_k<<<15100, 256, 0, stream>>>(gnn_w, post_w, pin_w, blk_w1, blk_w2, pout_w, gene,
                                         gnnT, postT, pinT, w1T, w2T, poutT, geneb);

    // CSR build
    hipMemsetAsync(counts, 0, NNODES * 4, stream);
    hipMemsetAsync(bar, 0, 4, stream);
    hist_k<<<EB, 256, 0, stream>>>(edge_dst, counts, NEDGES);
    scan1_k<<<NB, 256, 0, stream>>>(counts, incl, bsums, NNODES);
    scan2_k<<<1, 128, 0, stream>>>(bsums, boffs, NB);
    scan3_k<<<NB, 256, 0, stream>>>(incl, counts, boffs, row_start, cursor, NNODES);
    scatter_k<<<EB, 256, 0, stream>>>(edge_src, edge_dst, edge_w, cursor, epack, NEDGES);

    // GNN layers 1 & 2 (full), layer 3 (selective)
    const float* x_in = partial_emb;
    float* bufs[2] = {xa, xb};
    for (int i = 0; i < 2; i++) {
        lnb_k<<<(NNODES + 3) / 4, 256, 0, stream>>>(x_in, gnn_ln_s + i * GDIM,
                                                    gnn_ln_b + i * GDIM, ln_bf, NNODES);
        aggb_k<<<(NNODES + 3) / 4, 256, 0, stream>>>(row_start, counts, epack, ln_bf, aggbf,
                                                     NNODES);
        float* x_out = bufs[i];
        mgemm_k<1, true, true><<<dim3(GDIM / 128, (NNODES + 127) / 128), 256, 0, stream>>>(
            aggbf, gnnT + (size_t)i * GDIM * GDIM, gnn_b + i * GDIM, x_in, x_out, NNODES, GDIM,
            GDIM);
        x_in = x_out;
    }
    lnb_k<<<(NNODES + 3) / 4, 256, 0, stream>>>(xb, gnn_ln_s + 2 * GDIM, gnn_ln_b + 2 * GDIM,
                                                ln_bf, NNODES);
    aggsel_k<<<BSZ / 4, 256, 0, stream>>>(node_indices, row_start, counts, epack, ln_bf, aggselb);
    mfull_k<1, 2><<<dim3(GDIM / 64, BSZ / 64), 256, 0, stream>>>(
        aggselb, gnnT + (size_t)2 * GDIM * GDIM, gnn_b + 2 * GDIM, node_indices, xb, pertinbf,
        BSZ, GDIM, GDIM);

    // post_mp + OOV replace (fused)
    mfull_k<0, 1><<<dim3(GDIM / 64, BSZ / 64), 256, 0, stream>>>(
        pertinbf, postT, post_b, node_indices, oov_emb, pertbf, BSZ, GDIM, GDIM);

    // fused head: pin + 6 blocks + pout in ONE persistent kernel
    head_k<<<HGRID, 256, 0, stream>>>(pertbf, pinT, pin_b, blk_ln_s, blk_ln_b, w1T, blk_b1, w2T,
                                      blk_b2, poutT, pout_b, hbuf, zlnbf, z1bf, part, hbufbf,
                                      projb, bar);

    // logits
    mgemm_k<0, false, false><<<dim3((NGENES + 127) / 128, (BSZ * NCLS) / 128), 256, 0, stream>>>(
        projb, geneb, nullptr, nullptr, out, BSZ * NCLS, NGENES, RANK);
}

// Round 4
// 635.690 us; speedup vs baseline: 1.5746x; 1.2677x over previous
//
#include <hip/hip_runtime.h>
#include <hip/hip_bf16.h>
#include <math.h>

#define NNODES 20000
#define NEDGES 640000
#define BSZ 256
#define GDIM 256
#define HID 512
#define INNER 2048
#define RANK 512
#define NCLS 3
#define NGENES 6640

typedef __attribute__((ext_vector_type(8))) short bf16x8;
typedef __attribute__((ext_vector_type(4))) float f32x4;
typedef __attribute__((ext_vector_type(4))) unsigned u32x4;   // native vector: legal asm "v" operand

__device__ inline float bf2f(unsigned short u) {
    return __uint_as_float(((unsigned)u) << 16);
}
__device__ inline unsigned short f2bf(float f) {
    unsigned u = __float_as_uint(f);
    u = u + 0x7fff + ((u >> 16) & 1);   // RNE
    return (unsigned short)(u >> 16);
}

// ---- device-coherent (cross-XCD) loads/stores: bypass L1/L2, hit the
// memory-side coherence point. Used ONLY for the head's cross-phase
// activation buffers so the grid barrier needs NO cache maintenance
// (no buffer_wbl2 / buffer_inv -> weights stay L2-hot).
// NOTE: uint4 (struct) is NOT a valid asm "v" operand; u32x4 (ext_vector) is.
__device__ inline u32x4 ld16_cg(const void* p) {
    u32x4 r;
    asm volatile("global_load_dwordx4 %0, %1, off sc0 sc1" : "=v"(r) : "v"(p) : "memory");
    return r;
}
__device__ inline void st16_cg(void* p, u32x4 v) {
    asm volatile("global_store_dwordx4 %0, %1, off sc0 sc1" :: "v"(p), "v"(v) : "memory");
}
__device__ inline void st4f_cg(void* p, float v) {
    asm volatile("global_store_dword %0, %1, off sc0 sc1" :: "v"(p), "v"(v) : "memory");
}
__device__ inline void st2_cg(void* p, unsigned short v) {
    unsigned w = v;
    asm volatile("global_store_short %0, %1, off sc0 sc1" :: "v"(p), "v"(w) : "memory");
}
__device__ inline void waitvm0(void) {
    asm volatile("s_waitcnt vmcnt(0)" ::: "memory");
    __builtin_amdgcn_sched_barrier(0);
}

// ---------------- CSR build ----------------
__global__ void hist_k(const int* __restrict__ dst, int* __restrict__ counts, int E) {
    int e = blockIdx.x * 256 + threadIdx.x;
    if (e < E) atomicAdd(&counts[dst[e]], 1);
}

__global__ void scan1_k(const int* __restrict__ counts, int* __restrict__ incl,
                        int* __restrict__ bsums, int n) {
    __shared__ int s[256];
    int i = blockIdx.x * 256 + threadIdx.x;
    int v = (i < n) ? counts[i] : 0;
    s[threadIdx.x] = v;
    __syncthreads();
    for (int off = 1; off < 256; off <<= 1) {
        int t = (threadIdx.x >= off) ? s[threadIdx.x - off] : 0;
        __syncthreads();
        s[threadIdx.x] += t;
        __syncthreads();
    }
    if (i < n) incl[i] = s[threadIdx.x];
    if (threadIdx.x == 255) bsums[blockIdx.x] = s[255];
}

__global__ void scan2_k(const int* __restrict__ bsums, int* __restrict__ boffs, int nb) {
    __shared__ int s[128];
    int tid = threadIdx.x;
    int v = (tid < nb) ? bsums[tid] : 0;
    s[tid] = v;
    __syncthreads();
    for (int off = 1; off < 128; off <<= 1) {
        int t = (tid >= off) ? s[tid - off] : 0;
        __syncthreads();
        s[tid] += t;
        __syncthreads();
    }
    if (tid < nb) boffs[tid] = s[tid] - v;
}

__global__ void scan3_k(const int* __restrict__ incl, const int* __restrict__ counts,
                        const int* __restrict__ boffs, int* __restrict__ row_start,
                        int* __restrict__ cursor, int n) {
    int i = blockIdx.x * 256 + threadIdx.x;
    if (i < n) {
        int st = incl[i] - counts[i] + boffs[blockIdx.x];
        row_start[i] = st;
        cursor[i] = st;
    }
}

__global__ void scatter_k(const int* __restrict__ src, const int* __restrict__ dst,
                          const float* __restrict__ w, int* __restrict__ cursor,
                          int2* __restrict__ ep, int E) {
    int e = blockIdx.x * 256 + threadIdx.x;
    if (e < E) {
        int d = dst[e];
        int p = atomicAdd(&cursor[d], 1);
        ep[p] = make_int2(src[e], __float_as_int(w[e]));
    }
}

// ---------------- combined weight conversion (replaces 7 kernels) ----------------
__global__ void convall_k(const float* __restrict__ gnn_w, const float* __restrict__ post_w,
                          const float* __restrict__ pin_w, const float* __restrict__ blk_w1,
                          const float* __restrict__ blk_w2, const float* __restrict__ pout_w,
                          const float* __restrict__ gene, unsigned short* __restrict__ gnnT,
                          unsigned short* __restrict__ postT, unsigned short* __restrict__ pinT,
                          unsigned short* __restrict__ w1T, unsigned short* __restrict__ w2T,
                          unsigned short* __restrict__ poutT,
                          unsigned short* __restrict__ geneb) {
    int b = blockIdx.x;
    if (b >= 13440) {   // gene: plain fp32 -> bf16 convert, 2048 elems/block
        int t = b - 13440;
        const float4* xp = (const float4*)gene;
        int i = t * 512 + threadIdx.x * 2;    // float4 index
        float4 a = xp[i], c = xp[i + 1];
        *(ushort4*)(geneb + (size_t)i * 4) =
            make_ushort4(f2bf(a.x), f2bf(a.y), f2bf(a.z), f2bf(a.w));
        *(ushort4*)(geneb + (size_t)i * 4 + 4) =
            make_ushort4(f2bf(c.x), f2bf(c.y), f2bf(c.z), f2bf(c.w));
        return;
    }
    const float* W;
    unsigned short* WT;
    int K, N, tile;
    if (b < 192) {
        int l = b >> 6;
        tile = b & 63;
        W = gnn_w + (size_t)l * GDIM * GDIM;
        WT = gnnT + (size_t)l * GDIM * GDIM;
        K = GDIM; N = GDIM;
    } else if (b < 256) {
        tile = b - 192; W = post_w; WT = postT; K = GDIM; N = GDIM;
    } else if (b < 384) {
        tile = b - 256; W = pin_w; WT = pinT; K = GDIM; N = HID;
    } else if (b < 6528) {
        int t = b - 384;
        int l = t >> 10;
        tile = t & 1023;
        W = blk_w1 + (size_t)l * HID * INNER;
        WT = w1T + (size_t)l * INNER * HID;
        K = HID; N = INNER;
    } else if (b < 12672) {
        int t = b - 6528;
        int l = t >> 10;
        tile = t & 1023;
        W = blk_w2 + (size_t)l * INNER * HID;
        WT = w2T + (size_t)l * HID * INNER;
        K = INNER; N = HID;
    } else {
        tile = b - 12672; W = pout_w; WT = poutT; K = HID; N = NCLS * RANK;
    }
    __shared__ float s[32][33];
    int ntx = N >> 5;
    int k0 = (tile / ntx) << 5;
    int n0 = (tile % ntx) << 5;
    int tx = threadIdx.x & 31, ty = threadIdx.x >> 5;
#pragma unroll
    for (int i = 0; i < 4; i++)
        s[ty + 8 * i][tx] = W[(size_t)(k0 + ty + 8 * i) * N + n0 + tx];
    __syncthreads();
#pragma unroll
    for (int i = 0; i < 4; i++)
        WT[(size_t)(n0 + ty + 8 * i) * K + k0 + tx] = f2bf(s[tx][ty + 8 * i]);
}

// ---------------- GNN LayerNorm (D=256), bf16 out ----------------
__global__ void lnb_k(const float* __restrict__ X, const float* __restrict__ sc,
                      const float* __restrict__ bi, unsigned short* __restrict__ Y, int M) {
    int row = blockIdx.x * 4 + (threadIdx.x >> 6);
    int lane = threadIdx.x & 63;
    if (row >= M) return;
    float4 v = ((const float4*)(X + (size_t)row * GDIM))[lane];
    float sum = v.x + v.y + v.z + v.w;
#pragma unroll
    for (int off = 32; off >= 1; off >>= 1) sum += __shfl_xor(sum, off);
    float mu = sum / GDIM;
    float a = v.x - mu, b = v.y - mu, c = v.z - mu, d = v.w - mu;
    float sq = a * a + b * b + c * c + d * d;
#pragma unroll
    for (int off = 32; off >= 1; off >>= 1) sq += __shfl_xor(sq, off);
    float rstd = rsqrtf(sq / GDIM + 1e-5f);
    float4 s4 = ((const float4*)sc)[lane];
    float4 b4 = ((const float4*)bi)[lane];
    *(ushort4*)(Y + (size_t)row * GDIM + lane * 4) =
        make_ushort4(f2bf(a * rstd * s4.x + b4.x), f2bf(b * rstd * s4.y + b4.y),
                     f2bf(c * rstd * s4.z + b4.z), f2bf(d * rstd * s4.w + b4.w));
}

// ---------------- CSR aggregation, 16-deep MLP unroll ----------------
__device__ inline void agg_row(int beg, int cnt, int lane, const int2* __restrict__ ep,
                               const unsigned short* __restrict__ H, float& a0, float& a1,
                               float& a2, float& a3) {
    int t = 0;
    for (; t + 16 <= cnt; t += 16) {
        int2 e[16];
#pragma unroll
        for (int u = 0; u < 16; u++) e[u] = ep[beg + t + u];
        ushort4 v[16];
#pragma unroll
        for (int u = 0; u < 16; u++)
            v[u] = *(const ushort4*)(H + (size_t)e[u].x * GDIM + lane * 4);
#pragma unroll
        for (int u = 0; u < 16; u++) {
            float w = __int_as_float(e[u].y);
            a0 = fmaf(bf2f(v[u].x), w, a0);
            a1 = fmaf(bf2f(v[u].y), w, a1);
            a2 = fmaf(bf2f(v[u].z), w, a2);
            a3 = fmaf(bf2f(v[u].w), w, a3);
        }
    }
    for (; t + 4 <= cnt; t += 4) {
        int2 e[4];
#pragma unroll
        for (int u = 0; u < 4; u++) e[u] = ep[beg + t + u];
        ushort4 v[4];
#pragma unroll
        for (int u = 0; u < 4; u++)
            v[u] = *(const ushort4*)(H + (size_t)e[u].x * GDIM + lane * 4);
#pragma unroll
        for (int u = 0; u < 4; u++) {
            float w = __int_as_float(e[u].y);
            a0 = fmaf(bf2f(v[u].x), w, a0);
            a1 = fmaf(bf2f(v[u].y), w, a1);
            a2 = fmaf(bf2f(v[u].z), w, a2);
            a3 = fmaf(bf2f(v[u].w), w, a3);
        }
    }
    for (; t < cnt; t++) {
        int2 e = ep[beg + t];
        float w = __int_as_float(e.y);
        ushort4 v = *(const ushort4*)(H + (size_t)e.x * GDIM + lane * 4);
        a0 = fmaf(bf2f(v.x), w, a0);
        a1 = fmaf(bf2f(v.y), w, a1);
        a2 = fmaf(bf2f(v.z), w, a2);
        a3 = fmaf(bf2f(v.w), w, a3);
    }
}

__global__ void aggb_k(const int* __restrict__ row_start, const int* __restrict__ counts,
                       const int2* __restrict__ ep, const unsigned short* __restrict__ H,
                       unsigned short* __restrict__ AGG, int n) {
    int row = blockIdx.x * 4 + (threadIdx.x >> 6);
    int lane = threadIdx.x & 63;
    if (row >= n) return;
    float a0 = 0.f, a1 = 0.f, a2 = 0.f, a3 = 0.f;
    agg_row(row_start[row], counts[row], lane, ep, H, a0, a1, a2, a3);
    *(ushort4*)(AGG + (size_t)row * GDIM + lane * 4) =
        make_ushort4(f2bf(a0), f2bf(a1), f2bf(a2), f2bf(a3));
}

__global__ void aggsel_k(const int* __restrict__ idx, const int* __restrict__ row_start,
                         const int* __restrict__ counts, const int2* __restrict__ ep,
                         const unsigned short* __restrict__ H, unsigned short* __restrict__ AGG) {
    int b = blockIdx.x * 4 + (threadIdx.x >> 6);
    int lane = threadIdx.x & 63;
    int id = idx[b];
    int row = id < 0 ? 0 : id;
    float a0 = 0.f, a1 = 0.f, a2 = 0.f, a3 = 0.f;
    agg_row(row_start[row], counts[row], lane, ep, H, a0, a1, a2, a3);
    *(ushort4*)(AGG + (size_t)b * GDIM + lane * 4) =
        make_ushort4(f2bf(a0), f2bf(a1), f2bf(a2), f2bf(a3));
}

// ---------------- bf16 MFMA GEMM (full-K, fp32 out, fused epilogue) — GNN L1/L2 & logits ----------------
template <int ACT, bool RES, bool BIAS>
__global__ __launch_bounds__(256) void mgemm_k(const unsigned short* __restrict__ A,
                                               const unsigned short* __restrict__ BT,
                                               const float* __restrict__ bias,
                                               const float* __restrict__ R,
                                               float* __restrict__ C, int M, int N, int K) {
    __shared__ unsigned short As[128 * 32];
    __shared__ unsigned short Bs[128 * 32];
    int m0 = blockIdx.y * 128, n0 = blockIdx.x * 128;
    int tid = threadIdx.x;
    int wave = tid >> 6, lane = tid & 63;
    int wm = (wave >> 1) * 64, wn = (wave & 1) * 64;
    int lrow = lane & 15, lq = lane >> 4;

    f32x4 acc[4][4];
    const f32x4 zz = {0.f, 0.f, 0.f, 0.f};
#pragma unroll
    for (int i = 0; i < 4; i++)
#pragma unroll
        for (int j = 0; j < 4; j++) acc[i][j] = zz;

    int r0 = tid >> 2;
    int q = tid & 3;

    for (int k0 = 0; k0 < K; k0 += 32) {
#pragma unroll
        for (int p = 0; p < 2; p++) {
            int row = r0 + p * 64;
            int gm = m0 + row;
            uint4 va = make_uint4(0, 0, 0, 0);
            if (gm < M) va = *(const uint4*)(A + (size_t)gm * K + k0 + q * 8);
            *(uint4*)&As[row * 32 + q * 8] = va;
            int gn = n0 + row;
            uint4 vb = make_uint4(0, 0, 0, 0);
            if (gn < N) vb = *(const uint4*)(BT + (size_t)gn * K + k0 + q * 8);
            *(uint4*)&Bs[row * 32 + q * 8] = vb;
        }
        __syncthreads();
        bf16x8 af[4], bf[4];
#pragma unroll
        for (int i = 0; i < 4; i++)
            af[i] = *(const bf16x8*)&As[(wm + i * 16 + lrow) * 32 + lq * 8];
#pragma unroll
        for (int j = 0; j < 4; j++)
            bf[j] = *(const bf16x8*)&Bs[(wn + j * 16 + lrow) * 32 + lq * 8];
#pragma unroll
        for (int i = 0; i < 4; i++)
#pragma unroll
            for (int j = 0; j < 4; j++)
                acc[i][j] =
                    __builtin_amdgcn_mfma_f32_16x16x32_bf16(af[i], bf[j], acc[i][j], 0, 0, 0);
        __syncthreads();
    }

#pragma unroll
    for (int i = 0; i < 4; i++) {
#pragma unroll
        for (int j = 0; j < 4; j++) {
            int gn = n0 + wn + j * 16 + lrow;
            if (gn >= N) continue;
            float bv = BIAS ? bias[gn] : 0.f;
#pragma unroll
            for (int r = 0; r < 4; r++) {
                int gm = m0 + wm + i * 16 + lq * 4 + r;
                if (gm >= M) continue;
                float v = acc[i][j][r] + bv;
                if (ACT == 1) v = fmaxf(v, 0.f);
                if (RES) v += R[(size_t)gm * N + gn];
                C[(size_t)gm * N + gn] = v;
            }
        }
    }
}

// ---------------- bf16 MFMA full-K, bf16 out, fused epilogue (GNN L3 / post) ----------------
template <int ACT, int EPI>
__global__ __launch_bounds__(256) void mfull_k(const unsigned short* __restrict__ A,
                                               const unsigned short* __restrict__ BT,
                                               const float* __restrict__ bias,
                                               const int* __restrict__ idx,
                                               const float* __restrict__ aux,
                                               unsigned short* __restrict__ O, int M, int N,
                                               int K) {
    __shared__ unsigned short As[64 * 32];
    __shared__ unsigned short Bs[64 * 32];
    int m0 = blockIdx.y * 64, n0 = blockIdx.x * 64;
    int tid = threadIdx.x;
    int wave = tid >> 6, lane = tid & 63;
    int wm = wave * 16;
    int lrow = lane & 15, lq = lane >> 4;
    f32x4 acc[4];
    const f32x4 zz = {0.f, 0.f, 0.f, 0.f};
#pragma unroll
    for (int j = 0; j < 4; j++) acc[j] = zz;
    int r0 = tid >> 2;
    int q = tid & 3;
    for (int k0 = 0; k0 < K; k0 += 32) {
        *(uint4*)&As[r0 * 32 + q * 8] = *(const uint4*)(A + (size_t)(m0 + r0) * K + k0 + q * 8);
        *(uint4*)&Bs[r0 * 32 + q * 8] = *(const uint4*)(BT + (size_t)(n0 + r0) * K + k0 + q * 8);
        __syncthreads();
        bf16x8 af = *(const bf16x8*)&As[(wm + lrow) * 32 + lq * 8];
#pragma unroll
        for (int j = 0; j < 4; j++) {
            bf16x8 bfr = *(const bf16x8*)&Bs[(j * 16 + lrow) * 32 + lq * 8];
            acc[j] = __builtin_amdgcn_mfma_f32_16x16x32_bf16(af, bfr, acc[j], 0, 0, 0);
        }
        __syncthreads();
    }
#pragma unroll
    for (int j = 0; j < 4; j++) {
        int gn = n0 + j * 16 + lrow;
        float bv = bias[gn];
#pragma unroll
        for (int r = 0; r < 4; r++) {
            int gm = m0 + wm + lq * 4 + r;
            float v = acc[j][r] + bv;
            if (ACT == 1) v = fmaxf(v, 0.f);
            if (ACT == 2) v = 0.5f * v * (1.f + erff(v * 0.70710678118654752f));
            if (EPI == 2) {
                int id = idx[gm];
                int safe = id < 0 ? 0 : id;
                v += aux[(size_t)safe * N + gn];
            }
            if (EPI == 1) {
                if (idx[gm] < 0) v = aux[gn];
            }
            O[(size_t)gm * N + gn] = f2bf(v);
        }
    }
}

// ================= fused persistent head =================
// grid = 256 blocks x 256 threads, guaranteed co-resident (256 CUs, 1 block/CU floor).
// All cross-phase activation traffic goes through sc0sc1 (device coherence point),
// so the grid barrier is pure-RELAXED: NO buffer_wbl2 / buffer_inv anywhere ->
// weights stay L2-resident across phases; barrier cost = arrival skew only.

#define HGRID 256
#define LDP 72   // padded LDS row stride (ushort): keeps ds_read_b128 conflict-free at BK=64

__device__ inline void gsync(int* bar, int target) {
    // every thread drains its own (asm sc0sc1) stores; they are globally
    // visible once vmcnt retires.
    waitvm0();
    __syncthreads();
    if (threadIdx.x == 0) {
        __hip_atomic_fetch_add(bar, 1, __ATOMIC_RELAXED, __HIP_MEMORY_SCOPE_AGENT);
        while (__hip_atomic_load(bar, __ATOMIC_RELAXED, __HIP_MEMORY_SCOPE_AGENT) < target)
            __builtin_amdgcn_s_sleep(2);
    }
    __syncthreads();
}

// 32x64 tile GEMM, BK=64, reg-double-buffered staging.
// ACG: A-matrix is a cross-phase activation -> coherent (sc0sc1) loads.
// B (weights) always normal cached loads.
template <bool ACG>
__device__ inline void gemm32x64(const unsigned short* __restrict__ A, int lda,
                                 const unsigned short* __restrict__ BT, int ldb, int m0, int n0,
                                 int kbeg, int kcnt, unsigned short* As, unsigned short* Bs,
                                 f32x4 acc[2]) {
    int tid = threadIdx.x;
    int wave = tid >> 6, lane = tid & 63;
    int wm = (wave >> 1) * 16, wn = (wave & 1) * 32;
    int lrow = lane & 15, lq = lane >> 4;
    int rb = tid >> 2, qb = tid & 3;   // B rows 0..63
    int ra = rb & 31;                  // A rows 0..31 (tid<128)
    const unsigned short* bp = BT + (size_t)(n0 + rb) * ldb + kbeg + qb * 16;
    const unsigned short* ap = A + (size_t)(m0 + ra) * lda + kbeg + qb * 16;
    u32x4 vb0 = *(const u32x4*)bp, vb1 = *(const u32x4*)(bp + 8);
    u32x4 va0 = {0, 0, 0, 0}, va1 = {0, 0, 0, 0};
    if (tid < 128) {
        if (ACG) {
            va0 = ld16_cg(ap);
            va1 = ld16_cg(ap + 8);
        } else {
            va0 = *(const u32x4*)ap;
            va1 = *(const u32x4*)(ap + 8);
        }
    }
    for (int k0 = 0; k0 < kcnt; k0 += 64) {
        waitvm0();   // asm loads are untracked by the compiler: drain before LDS write
        *(u32x4*)&Bs[rb * LDP + qb * 16] = vb0;
        *(u32x4*)&Bs[rb * LDP + qb * 16 + 8] = vb1;
        if (tid < 128) {
            *(u32x4*)&As[ra * LDP + qb * 16] = va0;
            *(u32x4*)&As[ra * LDP + qb * 16 + 8] = va1;
        }
        __syncthreads();
        if (k0 + 64 < kcnt) {   // prefetch next K-slab; overlaps the MFMA section below
            vb0 = *(const u32x4*)(bp + k0 + 64);
            vb1 = *(const u32x4*)(bp + k0 + 72);
            if (tid < 128) {
                if (ACG) {
                    va0 = ld16_cg(ap + k0 + 64);
                    va1 = ld16_cg(ap + k0 + 72);
                } else {
                    va0 = *(const u32x4*)(ap + k0 + 64);
                    va1 = *(const u32x4*)(ap + k0 + 72);
                }
            }
        }
#pragma unroll
        for (int kk = 0; kk < 2; kk++) {
            bf16x8 af = *(const bf16x8*)&As[(wm + lrow) * LDP + kk * 32 + lq * 8];
#pragma unroll
            for (int j = 0; j < 2; j++) {
                bf16x8 bfr = *(const bf16x8*)&Bs[(wn + j * 16 + lrow) * LDP + kk * 32 + lq * 8];
                acc[j] = __builtin_amdgcn_mfma_f32_16x16x32_bf16(af, bfr, acc[j], 0, 0, 0);
            }
        }
        __syncthreads();
    }
}

// bf16 epilogue, coherent stores (cross-phase activations)
template <int ACT>
__device__ inline void epi32x64_bf_cg(const f32x4 acc[2], const float* __restrict__ bias,
                                      unsigned short* __restrict__ O, int ldo, int m0, int n0) {
    int tid = threadIdx.x, wave = tid >> 6, lane = tid & 63;
    int wm = (wave >> 1) * 16, wn = (wave & 1) * 32;
    int lrow = lane & 15, lq = lane >> 4;
#pragma unroll
    for (int j = 0; j < 2; j++) {
        int gn = n0 + wn + j * 16 + lrow;
        float bv = bias[gn];
#pragma unroll
        for (int r = 0; r < 4; r++) {
            int gm = m0 + wm + lq * 4 + r;
            float v = acc[j][r] + bv;
            if (ACT == 2) v = 0.5f * v * (1.f + erff(v * 0.70710678118654752f));
            st2_cg(O + (size_t)gm * ldo + gn, f2bf(v));
        }
    }
}

// bf16 epilogue, normal stores (kernel-boundary output: projb)
template <int ACT>
__device__ inline void epi32x64_bf(const f32x4 acc[2], const float* __restrict__ bias,
                                   unsigned short* __restrict__ O, int ldo, int m0, int n0) {
    int tid = threadIdx.x, wave = tid >> 6, lane = tid & 63;
    int wm = (wave >> 1) * 16, wn = (wave & 1) * 32;
    int lrow = lane & 15, lq = lane >> 4;
#pragma unroll
    for (int j = 0; j < 2; j++) {
        int gn = n0 + wn + j * 16 + lrow;
        float bv = bias[gn];
#pragma unroll
        for (int r = 0; r < 4; r++) {
            int gm = m0 + wm + lq * 4 + r;
            float v = acc[j][r] + bv;
            if (ACT == 2) v = 0.5f * v * (1.f + erff(v * 0.70710678118654752f));
            O[(size_t)gm * ldo + gn] = f2bf(v);
        }
    }
}

// fp32 partials epilogue, coherent stores
__device__ inline void epi32x64_f32_cg(const f32x4 acc[2], float* __restrict__ C, int ldo,
                                       int m0, int n0) {
    int tid = threadIdx.x, wave = tid >> 6, lane = tid & 63;
    int wm = (wave >> 1) * 16, wn = (wave & 1) * 32;
    int lrow = lane & 15, lq = lane >> 4;
#pragma unroll
    for (int j = 0; j < 2; j++) {
        int gn = n0 + wn + j * 16 + lrow;
#pragma unroll
        for (int r = 0; r < 4; r++) {
            int gm = m0 + wm + lq * 4 + r;
            st4f_cg(C + (size_t)gm * ldo + gn, acc[j][r]);
        }
    }
}

// reduce 4 split-K partials (coherent loads) + bias (+residual) -> hbuf (private),
// optional LN -> bf16 out (coherent stores). blocks 0..63, 4 rows each.
template <bool RESID, bool DO_LN>
__device__ inline void redln_dev(const float* __restrict__ Cp, const float* __restrict__ bias,
                                 const float* __restrict__ ln_s, const float* __restrict__ ln_b,
                                 float* __restrict__ hbuf, unsigned short* __restrict__ outbf) {
    int row = blockIdx.x * 4 + (threadIdx.x >> 6);
    int lane = threadIdx.x & 63;
    u32x4 raw[8];
#pragma unroll
    for (int s = 0; s < 4; s++) {
        const float* pp = Cp + ((size_t)s * BSZ + row) * HID + lane * 8;
        raw[2 * s] = ld16_cg(pp);
        raw[2 * s + 1] = ld16_cg(pp + 4);
    }
    waitvm0();   // rule-18: register-only consumers follow
    float4 a0 = {0.f, 0.f, 0.f, 0.f}, a1 = a0;
#pragma unroll
    for (int s = 0; s < 4; s++) {
        a0.x += __uint_as_float(raw[2 * s][0]);
        a0.y += __uint_as_float(raw[2 * s][1]);
        a0.z += __uint_as_float(raw[2 * s][2]);
        a0.w += __uint_as_float(raw[2 * s][3]);
        a1.x += __uint_as_float(raw[2 * s + 1][0]);
        a1.y += __uint_as_float(raw[2 * s + 1][1]);
        a1.z += __uint_as_float(raw[2 * s + 1][2]);
        a1.w += __uint_as_float(raw[2 * s + 1][3]);
    }
    const float4* bb = (const float4*)bias;
    float4 c0 = bb[lane * 2], c1 = bb[lane * 2 + 1];
    a0.x += c0.x; a0.y += c0.y; a0.z += c0.z; a0.w += c0.w;
    a1.x += c1.x; a1.y += c1.y; a1.z += c1.z; a1.w += c1.w;
    // hbuf is same-block-same-thread private across phases: normal cached ops
    float4* hp = (float4*)(hbuf + (size_t)row * HID);
    if (RESID) {
        float4 r0 = hp[lane * 2], r1 = hp[lane * 2 + 1];
        a0.x += r0.x; a0.y += r0.y; a0.z += r0.z; a0.w += r0.w;
        a1.x += r1.x; a1.y += r1.y; a1.z += r1.z; a1.w += r1.w;
    }
    hp[lane * 2] = a0;
    hp[lane * 2 + 1] = a1;
    unsigned short* op = outbf + (size_t)row * HID + lane * 8;
    float o0, o1, o2, o3, o4, o5, o6, o7;
    if (DO_LN) {
        float sum = a0.x + a0.y + a0.z + a0.w + a1.x + a1.y + a1.z + a1.w;
#pragma unroll
        for (int off = 32; off >= 1; off >>= 1) sum += __shfl_xor(sum, off);
        float mu = sum / HID;
        float d0 = a0.x - mu, d1 = a0.y - mu, d2 = a0.z - mu, d3 = a0.w - mu;
        float d4 = a1.x - mu, d5 = a1.y - mu, d6 = a1.z - mu, d7 = a1.w - mu;
        float sq = d0 * d0 + d1 * d1 + d2 * d2 + d3 * d3 + d4 * d4 + d5 * d5 + d6 * d6 + d7 * d7;
#pragma unroll
        for (int off = 32; off >= 1; off >>= 1) sq += __shfl_xor(sq, off);
        float rstd = rsqrtf(sq / HID + 1e-5f);
        const float4* sp = (const float4*)ln_s;
        const float4* bp2 = (const float4*)ln_b;
        float4 s0 = sp[lane * 2], s1 = sp[lane * 2 + 1];
        float4 t0 = bp2[lane * 2], t1 = bp2[lane * 2 + 1];
        o0 = d0 * rstd * s0.x + t0.x; o1 = d1 * rstd * s0.y + t0.y;
        o2 = d2 * rstd * s0.z + t0.z; o3 = d3 * rstd * s0.w + t0.w;
        o4 = d4 * rstd * s1.x + t1.x; o5 = d5 * rstd * s1.y + t1.y;
        o6 = d6 * rstd * s1.z + t1.z; o7 = d7 * rstd * s1.w + t1.w;
    } else {
        o0 = a0.x; o1 = a0.y; o2 = a0.z; o3 = a0.w;
        o4 = a1.x; o5 = a1.y; o6 = a1.z; o7 = a1.w;
    }
    u32x4 pack;
    pack[0] = f2bf(o0) | ((unsigned)f2bf(o1) << 16);
    pack[1] = f2bf(o2) | ((unsigned)f2bf(o3) << 16);
    pack[2] = f2bf(o4) | ((unsigned)f2bf(o5) << 16);
    pack[3] = f2bf(o6) | ((unsigned)f2bf(o7) << 16);
    st16_cg(op, pack);
}

// fused: pin(split-K)+LN0 -> 6x{w1-GELU, w2 split-K, reduce+res+LN} -> pout. 20 grid syncs.
__global__ __launch_bounds__(256) void head_k(
    const unsigned short* __restrict__ pertbf, const unsigned short* __restrict__ pinT,
    const float* __restrict__ pin_b, const float* __restrict__ blk_ln_s,
    const float* __restrict__ blk_ln_b, const unsigned short* __restrict__ w1T,
    const float* __restrict__ blk_b1, const unsigned short* __restrict__ w2T,
    const float* __restrict__ blk_b2, const unsigned short* __restrict__ poutT,
    const float* __restrict__ pout_b, float* __restrict__ hbuf,
    unsigned short* __restrict__ zlnbf, unsigned short* __restrict__ z1bf,
    float* __restrict__ part, unsigned short* __restrict__ hbufbf,
    unsigned short* __restrict__ projb, int* __restrict__ bar) {
    __shared__ unsigned short As[32 * LDP];
    __shared__ unsigned short Bs[64 * LDP];
    int b = blockIdx.x;
    int ph = 0;
    f32x4 acc[2];
    const f32x4 zz = {0.f, 0.f, 0.f, 0.f};

    // P0: pin split-K partials (M=256, N=512, K=256; 64 tiles x S=4). A=pertbf (input, normal)
    {
        int s = b >> 6, t = b & 63;
        int m0 = (t >> 3) * 32, n0 = (t & 7) * 64;
        acc[0] = zz; acc[1] = zz;
        gemm32x64<false>(pertbf, GDIM, pinT, GDIM, m0, n0, s * 64, 64, As, Bs, acc);
        epi32x64_f32_cg(acc, part + (size_t)s * BSZ * HID, HID, m0, n0);
    }
    gsync(bar, ++ph * HGRID);
    // P1: reduce + pin_b + LN(block0)
    if (b < 64) redln_dev<false, true>(part, pin_b, blk_ln_s, blk_ln_b, hbuf, zlnbf);
    gsync(bar, ++ph * HGRID);

    for (int i = 0; i < 6; i++) {
        {   // A: z1 = gelu(zln @ w1 + b1)   (M=256, N=2048, K=512; 8x32 tiles). A=zlnbf (coherent)
            int m0 = (b >> 5) * 32, n0 = (b & 31) * 64;
            acc[0] = zz; acc[1] = zz;
            gemm32x64<true>(zlnbf, HID, w1T + (size_t)i * INNER * HID, HID, m0, n0, 0, HID, As,
                            Bs, acc);
            epi32x64_bf_cg<2>(acc, blk_b1 + (size_t)i * INNER, z1bf, INNER, m0, n0);
        }
        gsync(bar, ++ph * HGRID);
        {   // B: part[s] = z1 @ w2 K-chunk  (M=256, N=512, K=2048; 64 tiles x S=4). A=z1bf (coherent)
            int s = b >> 6, t = b & 63;
            int m0 = (t >> 3) * 32, n0 = (t & 7) * 64;
            acc[0] = zz; acc[1] = zz;
            gemm32x64<true>(z1bf, INNER, w2T + (size_t)i * HID * INNER, INNER, m0, n0, s * 512,
                            512, As, Bs, acc);
            epi32x64_f32_cg(acc, part + (size_t)s * BSZ * HID, HID, m0, n0);
        }
        gsync(bar, ++ph * HGRID);
        // C: h += sum(part) + b2  (+LN for next layer / bf16 out for last)
        if (b < 64) {
            if (i < 5)
                redln_dev<true, true>(part, blk_b2 + (size_t)i * HID,
                                      blk_ln_s + (size_t)(i + 1) * HID,
                                      blk_ln_b + (size_t)(i + 1) * HID, hbuf, zlnbf);
            else
                redln_dev<true, false>(part, blk_b2 + (size_t)i * HID, nullptr, nullptr, hbuf,
                                       hbufbf);
        }
        gsync(bar, ++ph * HGRID);
    }

    // P2: proj = h @ pout + b (M=256, N=1536, K=512; 8x24=192 tiles). A=hbufbf (coherent)
    if (b < 192) {
        int m0 = (b / 24) * 32, n0 = (b % 24) * 64;
        acc[0] = zz; acc[1] = zz;
        gemm32x64<true>(hbufbf, HID, poutT, HID, m0, n0, 0, HID, As, Bs, acc);
        epi32x64_bf<0>(acc, pout_b, projb, NCLS * RANK, m0, n0);   // normal: next-kernel boundary
    }
}

// ---------------- launch ----------------
extern "C" void kernel_launch(void* const* d_in, const int* in_sizes, int n_in,
                              void* d_out, int out_size, void* d_ws, size_t ws_size,
                              hipStream_t stream) {
    const int* node_indices = (const int*)d_in[0];
    const int* edge_src = (const int*)d_in[1];
    const int* edge_dst = edge_src + NEDGES;
    const float* edge_w = (const float*)d_in[2];
    const float* partial_emb = (const float*)d_in[3];
    const float* oov_emb = (const float*)d_in[4];
    const float* gnn_ln_s = (const float*)d_in[5];
    const float* gnn_ln_b = (const float*)d_in[6];
    const float* gnn_w = (const float*)d_in[7];
    const float* gnn_b = (const float*)d_in[8];
    const float* post_w = (const float*)d_in[9];
    const float* post_b = (const float*)d_in[10];
    const float* pin_w = (const float*)d_in[11];
    const float* pin_b = (const float*)d_in[12];
    const float* blk_ln_s = (const float*)d_in[13];
    const float* blk_ln_b = (const float*)d_in[14];
    const float* blk_w1 = (const float*)d_in[15];
    const float* blk_b1 = (const float*)d_in[16];
    const float* blk_w2 = (const float*)d_in[17];
    const float* blk_b2 = (const float*)d_in[18];
    const float* pout_w = (const float*)d_in[19];
    const float* pout_b = (const float*)d_in[20];
    const float* gene = (const float*)d_in[21];
    float* out = (float*)d_out;

    char* p = (char*)d_ws;
    auto alloc = [&](size_t bytes) {
        char* r = p;
        p += (bytes + 255) & ~(size_t)255;
        return r;
    };
    int* counts = (int*)alloc(NNODES * 4);
    int* incl = (int*)alloc(NNODES * 4);
    int* bsums = (int*)alloc(128 * 4);
    int* boffs = (int*)alloc(128 * 4);
    int* row_start = (int*)alloc(NNODES * 4);
    int* cursor = (int*)alloc(NNODES * 4);
    int2* epack = (int2*)alloc((size_t)NEDGES * 8);
    // 'part': GNN phase = ln_bf + aggbf (bf16); head phase = split-K fp32 partials (4x256x512)
    float* part = (float*)alloc((size_t)NNODES * GDIM * 4);
    unsigned short* ln_bf = (unsigned short*)part;
    unsigned short* aggbf = (unsigned short*)((char*)part + (size_t)NNODES * GDIM * 2);
    float* xa = (float*)alloc((size_t)NNODES * GDIM * 4);
    float* xb = (float*)alloc((size_t)NNODES * GDIM * 4);
    float* hbuf = (float*)alloc((size_t)BSZ * HID * 4);
    unsigned short* aggselb = (unsigned short*)alloc((size_t)BSZ * GDIM * 2);
    unsigned short* pertinbf = (unsigned short*)alloc((size_t)BSZ * GDIM * 2);
    unsigned short* pertbf = (unsigned short*)alloc((size_t)BSZ * GDIM * 2);
    unsigned short* zlnbf = (unsigned short*)alloc((size_t)BSZ * HID * 2);
    unsigned short* z1bf = (unsigned short*)alloc((size_t)BSZ * INNER * 2);
    unsigned short* hbufbf = (unsigned short*)alloc((size_t)BSZ * HID * 2);
    unsigned short* projb = (unsigned short*)alloc((size_t)BSZ * NCLS * RANK * 2);
    unsigned short* gnnT = (unsigned short*)alloc((size_t)3 * GDIM * GDIM * 2);
    unsigned short* postT = (unsigned short*)alloc((size_t)GDIM * GDIM * 2);
    unsigned short* pinT = (unsigned short*)alloc((size_t)HID * GDIM * 2);
    unsigned short* w1T = (unsigned short*)alloc((size_t)6 * INNER * HID * 2);
    unsigned short* w2T = (unsigned short*)alloc((size_t)6 * HID * INNER * 2);
    unsigned short* poutT = (unsigned short*)alloc((size_t)NCLS * RANK * HID * 2);
    unsigned short* geneb = (unsigned short*)alloc((size_t)NGENES * RANK * 2);
    int* bar = (int*)alloc(256);

    const int EB = (NEDGES + 255) / 256;
    const int NB = (NNODES + 255) / 256;

    // all weight conversions in one dispatch
    convall_k<<<15100, 256, 0, stream>>>(gnn_w, post_w, pin_w, blk_w1, blk_w2, pout_w, gene,
                                         gnnT, postT, pinT, w1T, w2T, poutT, geneb);

    // CSR build
    (void)hipMemsetAsync(counts, 0, NNODES * 4, stream);
    (void)hipMemsetAsync(bar, 0, 4, stream);
    hist_k<<<EB, 256, 0, stream>>>(edge_dst, counts, NEDGES);
    scan1_k<<<NB, 256, 0, stream>>>(counts, incl, bsums, NNODES);
    scan2_k<<<1, 128, 0, stream>>>(bsums, boffs, NB);
    scan3_k<<<NB, 256, 0, stream>>>(incl, counts, boffs, row_start, cursor, NNODES);
    scatter_k<<<EB, 256, 0, stream>>>(edge_src, edge_dst, edge_w, cursor, epack, NEDGES);

    // GNN layers 1 & 2 (full), layer 3 (selective)
    const float* x_in = partial_emb;
    float* bufs[2] = {xa, xb};
    for (int i = 0; i < 2; i++) {
        lnb_k<<<(NNODES + 3) / 4, 256, 0, stream>>>(x_in, gnn_ln_s + i * GDIM,
                                                    gnn_ln_b + i * GDIM, ln_bf, NNODES);
        aggb_k<<<(NNODES + 3) / 4, 256, 0, stream>>>(row_start, counts, epack, ln_bf, aggbf,
                                                     NNODES);
        float* x_out = bufs[i];
        mgemm_k<1, true, true><<<dim3(GDIM / 128, (NNODES + 127) / 128), 256, 0, stream>>>(
            aggbf, gnnT + (size_t)i * GDIM * GDIM, gnn_b + i * GDIM, x_in, x_out, NNODES, GDIM,
            GDIM);
        x_in = x_out;
    }
    lnb_k<<<(NNODES + 3) / 4, 256, 0, stream>>>(xb, gnn_ln_s + 2 * GDIM, gnn_ln_b + 2 * GDIM,
                                                ln_bf, NNODES);
    aggsel_k<<<BSZ / 4, 256, 0, stream>>>(node_indices, row_start, counts, epack, ln_bf, aggselb);
    mfull_k<1, 2><<<dim3(GDIM / 64, BSZ / 64), 256, 0, stream>>>(
        aggselb, gnnT + (size_t)2 * GDIM * GDIM, gnn_b + 2 * GDIM, node_indices, xb, pertinbf,
        BSZ, GDIM, GDIM);

    // post_mp + OOV replace (fused)
    mfull_k<0, 1><<<dim3(GDIM / 64, BSZ / 64), 256, 0, stream>>>(
        pertinbf, postT, post_b, node_indices, oov_emb, pertbf, BSZ, GDIM, GDIM);

    // fused head: pin + 6 blocks + pout in ONE persistent kernel
    head_k<<<HGRID, 256, 0, stream>>>(pertbf, pinT, pin_b, blk_ln_s, blk_ln_b, w1T, blk_b1, w2T,
                                      blk_b2, poutT, pout_b, hbuf, zlnbf, z1bf, part, hbufbf,
                                      projb, bar);

    // logits
    mgemm_k<0, false, false><<<dim3((NGENES + 127) / 128, (BSZ * NCLS) / 128), 256, 0, stream>>>(
        projb, geneb, nullptr, nullptr, out, BSZ * NCLS, NGENES, RANK);
}

// Round 5
// 617.070 us; speedup vs baseline: 1.6221x; 1.0302x over previous
//
#include <hip/hip_runtime.h>
#include <hip/hip_bf16.h>
#include <math.h>

#define NNODES 20000
#define NEDGES 640000
#define BSZ 256
#define GDIM 256
#define HID 512
#define INNER 2048
#define RANK 512
#define NCLS 3
#define NGENES 6640

typedef __attribute__((ext_vector_type(8))) short bf16x8;
typedef __attribute__((ext_vector_type(4))) float f32x4;
typedef __attribute__((ext_vector_type(4))) unsigned u32x4;   // native vector: legal asm "v" operand

__device__ inline float bf2f(unsigned short u) {
    return __uint_as_float(((unsigned)u) << 16);
}
__device__ inline unsigned short f2bf(float f) {
    unsigned u = __float_as_uint(f);
    u = u + 0x7fff + ((u >> 16) & 1);   // RNE
    return (unsigned short)(u >> 16);
}
__device__ inline unsigned pk2(float a, float b) {
    return (unsigned)f2bf(a) | ((unsigned)f2bf(b) << 16);
}

// ---- device-coherent (cross-XCD) loads/stores: bypass L1/L2, complete at the
// memory-side coherence point. Used ONLY for the head's cross-phase activation
// buffers so the grid barrier needs NO cache maintenance (no buffer_wbl2 /
// buffer_inv -> weights stay L2-hot). Proven: 565 -> 365 -> 199 us.
__device__ inline u32x4 ld16_cg(const void* p) {
    u32x4 r;
    asm volatile("global_load_dwordx4 %0, %1, off sc0 sc1" : "=v"(r) : "v"(p) : "memory");
    return r;
}
__device__ inline void st4f_cg(void* p, float v) {
    asm volatile("global_store_dword %0, %1, off sc0 sc1" :: "v"(p), "v"(v) : "memory");
}
__device__ inline void st2_cg(void* p, unsigned short v) {
    unsigned w = v;
    asm volatile("global_store_short %0, %1, off sc0 sc1" :: "v"(p), "v"(w) : "memory");
}
__device__ inline void waitvm0(void) {
    asm volatile("s_waitcnt vmcnt(0)" ::: "memory");
    __builtin_amdgcn_sched_barrier(0);
}

// ---------------- CSR build ----------------
__global__ void hist_k(const int* __restrict__ dst, int* __restrict__ counts, int E) {
    int e = blockIdx.x * 256 + threadIdx.x;
    if (e < E) atomicAdd(&counts[dst[e]], 1);
}

__global__ void scan1_k(const int* __restrict__ counts, int* __restrict__ incl,
                        int* __restrict__ bsums, int n) {
    __shared__ int s[256];
    int i = blockIdx.x * 256 + threadIdx.x;
    int v = (i < n) ? counts[i] : 0;
    s[threadIdx.x] = v;
    __syncthreads();
    for (int off = 1; off < 256; off <<= 1) {
        int t = (threadIdx.x >= off) ? s[threadIdx.x - off] : 0;
        __syncthreads();
        s[threadIdx.x] += t;
        __syncthreads();
    }
    if (i < n) incl[i] = s[threadIdx.x];
    if (threadIdx.x == 255) bsums[blockIdx.x] = s[255];
}

__global__ void scan2_k(const int* __restrict__ bsums, int* __restrict__ boffs, int nb) {
    __shared__ int s[128];
    int tid = threadIdx.x;
    int v = (tid < nb) ? bsums[tid] : 0;
    s[tid] = v;
    __syncthreads();
    for (int off = 1; off < 128; off <<= 1) {
        int t = (tid >= off) ? s[tid - off] : 0;
        __syncthreads();
        s[tid] += t;
        __syncthreads();
    }
    if (tid < nb) boffs[tid] = s[tid] - v;
}

__global__ void scan3_k(const int* __restrict__ incl, const int* __restrict__ counts,
                        const int* __restrict__ boffs, int* __restrict__ row_start,
                        int* __restrict__ cursor, int n) {
    int i = blockIdx.x * 256 + threadIdx.x;
    if (i < n) {
        int st = incl[i] - counts[i] + boffs[blockIdx.x];
        row_start[i] = st;
        cursor[i] = st;
    }
}

__global__ void scatter_k(const int* __restrict__ src, const int* __restrict__ dst,
                          const float* __restrict__ w, int* __restrict__ cursor,
                          int2* __restrict__ ep, int E) {
    int e = blockIdx.x * 256 + threadIdx.x;
    if (e < E) {
        int d = dst[e];
        int p = atomicAdd(&cursor[d], 1);
        ep[p] = make_int2(src[e], __float_as_int(w[e]));
    }
}

// ---------------- combined weight conversion ----------------
__global__ void convall_k(const float* __restrict__ gnn_w, const float* __restrict__ post_w,
                          const float* __restrict__ pin_w, const float* __restrict__ blk_w1,
                          const float* __restrict__ blk_w2, const float* __restrict__ pout_w,
                          const float* __restrict__ gene, unsigned short* __restrict__ gnnT,
                          unsigned short* __restrict__ postT, unsigned short* __restrict__ pinT,
                          unsigned short* __restrict__ w1T, unsigned short* __restrict__ w2T,
                          unsigned short* __restrict__ poutT,
                          unsigned short* __restrict__ geneb) {
    int b = blockIdx.x;
    if (b >= 13440) {   // gene: plain fp32 -> bf16 convert, 2048 elems/block
        int t = b - 13440;
        const float4* xp = (const float4*)gene;
        int i = t * 512 + threadIdx.x * 2;    // float4 index
        float4 a = xp[i], c = xp[i + 1];
        *(ushort4*)(geneb + (size_t)i * 4) =
            make_ushort4(f2bf(a.x), f2bf(a.y), f2bf(a.z), f2bf(a.w));
        *(ushort4*)(geneb + (size_t)i * 4 + 4) =
            make_ushort4(f2bf(c.x), f2bf(c.y), f2bf(c.z), f2bf(c.w));
        return;
    }
    const float* W;
    unsigned short* WT;
    int K, N, tile;
    if (b < 192) {
        int l = b >> 6;
        tile = b & 63;
        W = gnn_w + (size_t)l * GDIM * GDIM;
        WT = gnnT + (size_t)l * GDIM * GDIM;
        K = GDIM; N = GDIM;
    } else if (b < 256) {
        tile = b - 192; W = post_w; WT = postT; K = GDIM; N = GDIM;
    } else if (b < 384) {
        tile = b - 256; W = pin_w; WT = pinT; K = GDIM; N = HID;
    } else if (b < 6528) {
        int t = b - 384;
        int l = t >> 10;
        tile = t & 1023;
        W = blk_w1 + (size_t)l * HID * INNER;
        WT = w1T + (size_t)l * INNER * HID;
        K = HID; N = INNER;
    } else if (b < 12672) {
        int t = b - 6528;
        int l = t >> 10;
        tile = t & 1023;
        W = blk_w2 + (size_t)l * INNER * HID;
        WT = w2T + (size_t)l * HID * INNER;
        K = INNER; N = HID;
    } else {
        tile = b - 12672; W = pout_w; WT = poutT; K = HID; N = NCLS * RANK;
    }
    __shared__ float s[32][33];
    int ntx = N >> 5;
    int k0 = (tile / ntx) << 5;
    int n0 = (tile % ntx) << 5;
    int tx = threadIdx.x & 31, ty = threadIdx.x >> 5;
#pragma unroll
    for (int i = 0; i < 4; i++)
        s[ty + 8 * i][tx] = W[(size_t)(k0 + ty + 8 * i) * N + n0 + tx];
    __syncthreads();
#pragma unroll
    for (int i = 0; i < 4; i++)
        WT[(size_t)(n0 + ty + 8 * i) * K + k0 + tx] = f2bf(s[tx][ty + 8 * i]);
}

// ---------------- GNN LayerNorm (D=256), bf16 out ----------------
__global__ void lnb_k(const float* __restrict__ X, const float* __restrict__ sc,
                      const float* __restrict__ bi, unsigned short* __restrict__ Y, int M) {
    int row = blockIdx.x * 4 + (threadIdx.x >> 6);
    int lane = threadIdx.x & 63;
    if (row >= M) return;
    float4 v = ((const float4*)(X + (size_t)row * GDIM))[lane];
    float sum = v.x + v.y + v.z + v.w;
#pragma unroll
    for (int off = 32; off >= 1; off >>= 1) sum += __shfl_xor(sum, off);
    float mu = sum / GDIM;
    float a = v.x - mu, b = v.y - mu, c = v.z - mu, d = v.w - mu;
    float sq = a * a + b * b + c * c + d * d;
#pragma unroll
    for (int off = 32; off >= 1; off >>= 1) sq += __shfl_xor(sq, off);
    float rstd = rsqrtf(sq / GDIM + 1e-5f);
    float4 s4 = ((const float4*)sc)[lane];
    float4 b4 = ((const float4*)bi)[lane];
    *(ushort4*)(Y + (size_t)row * GDIM + lane * 4) =
        make_ushort4(f2bf(a * rstd * s4.x + b4.x), f2bf(b * rstd * s4.y + b4.y),
                     f2bf(c * rstd * s4.z + b4.z), f2bf(d * rstd * s4.w + b4.w));
}

// ---------------- CSR aggregation, 16-deep MLP unroll ----------------
__device__ inline void agg_row(int beg, int cnt, int lane, const int2* __restrict__ ep,
                               const unsigned short* __restrict__ H, float& a0, float& a1,
                               float& a2, float& a3) {
    int t = 0;
    for (; t + 16 <= cnt; t += 16) {
        int2 e[16];
#pragma unroll
        for (int u = 0; u < 16; u++) e[u] = ep[beg + t + u];
        ushort4 v[16];
#pragma unroll
        for (int u = 0; u < 16; u++)
            v[u] = *(const ushort4*)(H + (size_t)e[u].x * GDIM + lane * 4);
#pragma unroll
        for (int u = 0; u < 16; u++) {
            float w = __int_as_float(e[u].y);
            a0 = fmaf(bf2f(v[u].x), w, a0);
            a1 = fmaf(bf2f(v[u].y), w, a1);
            a2 = fmaf(bf2f(v[u].z), w, a2);
            a3 = fmaf(bf2f(v[u].w), w, a3);
        }
    }
    for (; t + 4 <= cnt; t += 4) {
        int2 e[4];
#pragma unroll
        for (int u = 0; u < 4; u++) e[u] = ep[beg + t + u];
        ushort4 v[4];
#pragma unroll
        for (int u = 0; u < 4; u++)
            v[u] = *(const ushort4*)(H + (size_t)e[u].x * GDIM + lane * 4);
#pragma unroll
        for (int u = 0; u < 4; u++) {
            float w = __int_as_float(e[u].y);
            a0 = fmaf(bf2f(v[u].x), w, a0);
            a1 = fmaf(bf2f(v[u].y), w, a1);
            a2 = fmaf(bf2f(v[u].z), w, a2);
            a3 = fmaf(bf2f(v[u].w), w, a3);
        }
    }
    for (; t < cnt; t++) {
        int2 e = ep[beg + t];
        float w = __int_as_float(e.y);
        ushort4 v = *(const ushort4*)(H + (size_t)e.x * GDIM + lane * 4);
        a0 = fmaf(bf2f(v.x), w, a0);
        a1 = fmaf(bf2f(v.y), w, a1);
        a2 = fmaf(bf2f(v.z), w, a2);
        a3 = fmaf(bf2f(v.w), w, a3);
    }
}

__global__ void aggb_k(const int* __restrict__ row_start, const int* __restrict__ counts,
                       const int2* __restrict__ ep, const unsigned short* __restrict__ H,
                       unsigned short* __restrict__ AGG, int n) {
    int row = blockIdx.x * 4 + (threadIdx.x >> 6);
    int lane = threadIdx.x & 63;
    if (row >= n) return;
    float a0 = 0.f, a1 = 0.f, a2 = 0.f, a3 = 0.f;
    agg_row(row_start[row], counts[row], lane, ep, H, a0, a1, a2, a3);
    *(ushort4*)(AGG + (size_t)row * GDIM + lane * 4) =
        make_ushort4(f2bf(a0), f2bf(a1), f2bf(a2), f2bf(a3));
}

__global__ void aggsel_k(const int* __restrict__ idx, const int* __restrict__ row_start,
                         const int* __restrict__ counts, const int2* __restrict__ ep,
                         const unsigned short* __restrict__ H, unsigned short* __restrict__ AGG) {
    int b = blockIdx.x * 4 + (threadIdx.x >> 6);
    int lane = threadIdx.x & 63;
    int id = idx[b];
    int row = id < 0 ? 0 : id;
    float a0 = 0.f, a1 = 0.f, a2 = 0.f, a3 = 0.f;
    agg_row(row_start[row], counts[row], lane, ep, H, a0, a1, a2, a3);
    *(ushort4*)(AGG + (size_t)b * GDIM + lane * 4) =
        make_ushort4(f2bf(a0), f2bf(a1), f2bf(a2), f2bf(a3));
}

// ---------------- bf16 MFMA GEMM (full-K, fp32 out, fused epilogue) — GNN L1/L2 & logits ----------------
template <int ACT, bool RES, bool BIAS>
__global__ __launch_bounds__(256) void mgemm_k(const unsigned short* __restrict__ A,
                                               const unsigned short* __restrict__ BT,
                                               const float* __restrict__ bias,
                                               const float* __restrict__ R,
                                               float* __restrict__ C, int M, int N, int K) {
    __shared__ unsigned short As[128 * 32];
    __shared__ unsigned short Bs[128 * 32];
    int m0 = blockIdx.y * 128, n0 = blockIdx.x * 128;
    int tid = threadIdx.x;
    int wave = tid >> 6, lane = tid & 63;
    int wm = (wave >> 1) * 64, wn = (wave & 1) * 64;
    int lrow = lane & 15, lq = lane >> 4;

    f32x4 acc[4][4];
    const f32x4 zz = {0.f, 0.f, 0.f, 0.f};
#pragma unroll
    for (int i = 0; i < 4; i++)
#pragma unroll
        for (int j = 0; j < 4; j++) acc[i][j] = zz;

    int r0 = tid >> 2;
    int q = tid & 3;

    for (int k0 = 0; k0 < K; k0 += 32) {
#pragma unroll
        for (int p = 0; p < 2; p++) {
            int row = r0 + p * 64;
            int gm = m0 + row;
            uint4 va = make_uint4(0, 0, 0, 0);
            if (gm < M) va = *(const uint4*)(A + (size_t)gm * K + k0 + q * 8);
            *(uint4*)&As[row * 32 + q * 8] = va;
            int gn = n0 + row;
            uint4 vb = make_uint4(0, 0, 0, 0);
            if (gn < N) vb = *(const uint4*)(BT + (size_t)gn * K + k0 + q * 8);
            *(uint4*)&Bs[row * 32 + q * 8] = vb;
        }
        __syncthreads();
        bf16x8 af[4], bf[4];
#pragma unroll
        for (int i = 0; i < 4; i++)
            af[i] = *(const bf16x8*)&As[(wm + i * 16 + lrow) * 32 + lq * 8];
#pragma unroll
        for (int j = 0; j < 4; j++)
            bf[j] = *(const bf16x8*)&Bs[(wn + j * 16 + lrow) * 32 + lq * 8];
#pragma unroll
        for (int i = 0; i < 4; i++)
#pragma unroll
            for (int j = 0; j < 4; j++)
                acc[i][j] =
                    __builtin_amdgcn_mfma_f32_16x16x32_bf16(af[i], bf[j], acc[i][j], 0, 0, 0);
        __syncthreads();
    }

#pragma unroll
    for (int i = 0; i < 4; i++) {
#pragma unroll
        for (int j = 0; j < 4; j++) {
            int gn = n0 + wn + j * 16 + lrow;
            if (gn >= N) continue;
            float bv = BIAS ? bias[gn] : 0.f;
#pragma unroll
            for (int r = 0; r < 4; r++) {
                int gm = m0 + wm + i * 16 + lq * 4 + r;
                if (gm >= M) continue;
                float v = acc[i][j][r] + bv;
                if (ACT == 1) v = fmaxf(v, 0.f);
                if (RES) v += R[(size_t)gm * N + gn];
                C[(size_t)gm * N + gn] = v;
            }
        }
    }
}

// ---------------- bf16 MFMA full-K, bf16 out, fused epilogue (GNN L3 / post) ----------------
template <int ACT, int EPI>
__global__ __launch_bounds__(256) void mfull_k(const unsigned short* __restrict__ A,
                                               const unsigned short* __restrict__ BT,
                                               const float* __restrict__ bias,
                                               const int* __restrict__ idx,
                                               const float* __restrict__ aux,
                                               unsigned short* __restrict__ O, int M, int N,
                                               int K) {
    __shared__ unsigned short As[64 * 32];
    __shared__ unsigned short Bs[64 * 32];
    int m0 = blockIdx.y * 64, n0 = blockIdx.x * 64;
    int tid = threadIdx.x;
    int wave = tid >> 6, lane = tid & 63;
    int wm = wave * 16;
    int lrow = lane & 15, lq = lane >> 4;
    f32x4 acc[4];
    const f32x4 zz = {0.f, 0.f, 0.f, 0.f};
#pragma unroll
    for (int j = 0; j < 4; j++) acc[j] = zz;
    int r0 = tid >> 2;
    int q = tid & 3;
    for (int k0 = 0; k0 < K; k0 += 32) {
        *(uint4*)&As[r0 * 32 + q * 8] = *(const uint4*)(A + (size_t)(m0 + r0) * K + k0 + q * 8);
        *(uint4*)&Bs[r0 * 32 + q * 8] = *(const uint4*)(BT + (size_t)(n0 + r0) * K + k0 + q * 8);
        __syncthreads();
        bf16x8 af = *(const bf16x8*)&As[(wm + lrow) * 32 + lq * 8];
#pragma unroll
        for (int j = 0; j < 4; j++) {
            bf16x8 bfr = *(const bf16x8*)&Bs[(j * 16 + lrow) * 32 + lq * 8];
            acc[j] = __builtin_amdgcn_mfma_f32_16x16x32_bf16(af, bfr, acc[j], 0, 0, 0);
        }
        __syncthreads();
    }
#pragma unroll
    for (int j = 0; j < 4; j++) {
        int gn = n0 + j * 16 + lrow;
        float bv = bias[gn];
#pragma unroll
        for (int r = 0; r < 4; r++) {
            int gm = m0 + wm + lq * 4 + r;
            float v = acc[j][r] + bv;
            if (ACT == 1) v = fmaxf(v, 0.f);
            if (ACT == 2) v = 0.5f * v * (1.f + erff(v * 0.70710678118654752f));
            if (EPI == 2) {
                int id = idx[gm];
                int safe = id < 0 ? 0 : id;
                v += aux[(size_t)safe * N + gn];
            }
            if (EPI == 1) {
                if (idx[gm] < 0) v = aux[gn];
            }
            O[(size_t)gm * N + gn] = f2bf(v);
        }
    }
}

// ================= fused persistent head (v3: whole-tile LDS staging, 13 barriers) =================
// grid = 256 blocks x 256 threads, co-resident (1 block/CU). h lives in fp32 coherent
// buffer; per-layer: A-phase = inline-LN(h) + w1-GEMM + GELU -> z1 (coherent);
// B-phase = z1 @ w2 chunk, atomicAdd (relaxed, agent) into h. No split-K partials,
// no reduce phases. Whole K-extent staged to LDS with ONE vmcnt(0) per phase.

#define HGRID 256
#define LDPA 520   // ushort row stride for K<=512 tiles: 1040B -> bank-optimal b128 reads

__device__ inline void gsync(int* bar, int target) {
    waitvm0();   // drain this thread's cg-stores/atomics (globally visible at retire)
    __syncthreads();
    if (threadIdx.x == 0) {
        __hip_atomic_fetch_add(bar, 1, __ATOMIC_RELAXED, __HIP_MEMORY_SCOPE_AGENT);
        while (__hip_atomic_load(bar, __ATOMIC_RELAXED, __HIP_MEMORY_SCOPE_AGENT) < target)
            __builtin_amdgcn_s_sleep(2);
    }
    __syncthreads();
}

// issue ROWSxKC bf16 tile loads (all outstanding), NL = ROWS*KC/2048 regs/thread
template <int ROWS, int KC, bool CG>
__device__ inline void stage_issue(const unsigned short* src, int ld, u32x4* regs) {
    constexpr int NL = ROWS * KC / 8 / 256;
    int tid = threadIdx.x;
#pragma unroll
    for (int it = 0; it < NL; it++) {
        int unit = it * 256 + tid;
        int row = unit / (KC / 8);
        int ucol = unit % (KC / 8);
        const unsigned short* p = src + (size_t)row * ld + ucol * 8;
        if (CG) regs[it] = ld16_cg(p);
        else regs[it] = *(const u32x4*)p;
    }
}
template <int ROWS, int KC>
__device__ inline void stage_write(unsigned short* dst, const u32x4* regs) {
    constexpr int NL = ROWS * KC / 8 / 256;
    int tid = threadIdx.x;
#pragma unroll
    for (int it = 0; it < NL; it++) {
        int unit = it * 256 + tid;
        int row = unit / (KC / 8);
        int ucol = unit % (KC / 8);
        *(u32x4*)&dst[row * LDPA + ucol * 8] = regs[it];
    }
}

// uninterrupted MFMA stream over the fully-staged tile (no inner barriers)
template <int KC>
__device__ inline void mma_all(const unsigned short* As, const unsigned short* Bs, f32x4 acc[2]) {
    int tid = threadIdx.x, wave = tid >> 6, lane = tid & 63;
    int wm = (wave >> 1) * 16, wn = (wave & 1) * 32;
    int lrow = lane & 15, lq = lane >> 4;
#pragma unroll
    for (int kk = 0; kk < KC / 32; kk++) {
        bf16x8 af = *(const bf16x8*)&As[(wm + lrow) * LDPA + kk * 32 + lq * 8];
#pragma unroll
        for (int j = 0; j < 2; j++) {
            bf16x8 bfr = *(const bf16x8*)&Bs[(wn + j * 16 + lrow) * LDPA + kk * 32 + lq * 8];
            acc[j] = __builtin_amdgcn_mfma_f32_16x16x32_bf16(af, bfr, acc[j], 0, 0, 0);
        }
    }
}

__global__ __launch_bounds__(256) void head_k(
    const unsigned short* __restrict__ pertbf, const unsigned short* __restrict__ pinT,
    const float* __restrict__ pin_b, const float* __restrict__ blk_ln_s,
    const float* __restrict__ blk_ln_b, const unsigned short* __restrict__ w1T,
    const float* __restrict__ blk_b1, const unsigned short* __restrict__ w2T,
    const float* __restrict__ blk_b2, const unsigned short* __restrict__ poutT,
    const float* __restrict__ pout_b, float* __restrict__ hbuf,
    unsigned short* __restrict__ z1bf, unsigned short* __restrict__ projb,
    int* __restrict__ bar) {
    __shared__ unsigned short As[32 * LDPA];   // 33.3 KB
    __shared__ unsigned short Bs[64 * LDPA];   // 66.6 KB
    int b = blockIdx.x;
    int tid = threadIdx.x;
    int wave = tid >> 6, lane = tid & 63;
    int wm = (wave >> 1) * 16, wn = (wave & 1) * 32;
    int lrow = lane & 15, lq = lane >> 4;
    int ph = 0;
    f32x4 acc[2];
    const f32x4 zz = {0.f, 0.f, 0.f, 0.f};

    // ---- P0: h = pertbf @ pinT + pin_b  (M=256,N=512,K=256; 64 blocks)
    if (b < 64) {
        int m0 = (b >> 3) * 32, n0 = (b & 7) * 64;
        u32x4 wreg[8], areg[4];
        stage_issue<64, 256, false>(pinT + (size_t)n0 * GDIM, GDIM, wreg);
        stage_issue<32, 256, false>(pertbf + (size_t)m0 * GDIM, GDIM, areg);
        waitvm0();
        stage_write<64, 256>(Bs, wreg);
        stage_write<32, 256>(As, areg);
        __syncthreads();
        acc[0] = zz; acc[1] = zz;
        mma_all<256>(As, Bs, acc);
#pragma unroll
        for (int j = 0; j < 2; j++) {
            int gn = n0 + wn + j * 16 + lrow;
            float bv = pin_b[gn];
#pragma unroll
            for (int r = 0; r < 4; r++) {
                int gm = m0 + wm + lq * 4 + r;
                st4f_cg(hbuf + (size_t)gm * HID + gn, acc[j][r] + bv);
            }
        }
    }
    gsync(bar, ++ph * HGRID);

    for (int i = 0; i < 6; i++) {
        {   // A: z1 = gelu(LN_i(h) @ w1 + b1)  (M=256,N=2048,K=512; 256 blocks)
            int m0 = (b >> 5) * 32, n0 = (b & 31) * 64;
            u32x4 wreg[16], hreg[16];
            stage_issue<64, 512, false>(w1T + (size_t)i * INNER * HID + (size_t)n0 * HID, HID,
                                        wreg);
            // issue h loads: wave w owns rows m0+w*8 .. +8, lane covers 8 f32 of each row
#pragma unroll
            for (int rr = 0; rr < 8; rr++) {
                const float* p = hbuf + (size_t)(m0 + wave * 8 + rr) * HID + lane * 8;
                hreg[2 * rr] = ld16_cg(p);
                hreg[2 * rr + 1] = ld16_cg(p + 4);
            }
            waitvm0();
            stage_write<64, 512>(Bs, wreg);
            // inline LayerNorm (redundant across n-tiles, cheap) -> bf16 As
            const float* ls = blk_ln_s + (size_t)i * HID;
            const float* lb = blk_ln_b + (size_t)i * HID;
            float4 s0 = ((const float4*)ls)[lane * 2], s1 = ((const float4*)ls)[lane * 2 + 1];
            float4 t0 = ((const float4*)lb)[lane * 2], t1 = ((const float4*)lb)[lane * 2 + 1];
#pragma unroll
            for (int rr = 0; rr < 8; rr++) {
                float f0 = __uint_as_float(hreg[2 * rr][0]);
                float f1 = __uint_as_float(hreg[2 * rr][1]);
                float f2 = __uint_as_float(hreg[2 * rr][2]);
                float f3 = __uint_as_float(hreg[2 * rr][3]);
                float f4 = __uint_as_float(hreg[2 * rr + 1][0]);
                float f5 = __uint_as_float(hreg[2 * rr + 1][1]);
                float f6 = __uint_as_float(hreg[2 * rr + 1][2]);
                float f7 = __uint_as_float(hreg[2 * rr + 1][3]);
                float sum = f0 + f1 + f2 + f3 + f4 + f5 + f6 + f7;
#pragma unroll
                for (int off = 32; off >= 1; off >>= 1) sum += __shfl_xor(sum, off);
                float mu = sum * (1.f / HID);
                float d0 = f0 - mu, d1 = f1 - mu, d2 = f2 - mu, d3 = f3 - mu;
                float d4 = f4 - mu, d5 = f5 - mu, d6 = f6 - mu, d7 = f7 - mu;
                float sq = d0 * d0 + d1 * d1 + d2 * d2 + d3 * d3 + d4 * d4 + d5 * d5 +
                           d6 * d6 + d7 * d7;
#pragma unroll
                for (int off = 32; off >= 1; off >>= 1) sq += __shfl_xor(sq, off);
                float rstd = rsqrtf(sq * (1.f / HID) + 1e-5f);
                u32x4 pk;
                pk[0] = pk2(d0 * rstd * s0.x + t0.x, d1 * rstd * s0.y + t0.y);
                pk[1] = pk2(d2 * rstd * s0.z + t0.z, d3 * rstd * s0.w + t0.w);
                pk[2] = pk2(d4 * rstd * s1.x + t1.x, d5 * rstd * s1.y + t1.y);
                pk[3] = pk2(d6 * rstd * s1.z + t1.z, d7 * rstd * s1.w + t1.w);
                *(u32x4*)&As[(wave * 8 + rr) * LDPA + lane * 8] = pk;
            }
            __syncthreads();
            acc[0] = zz; acc[1] = zz;
            mma_all<512>(As, Bs, acc);
#pragma unroll
            for (int j = 0; j < 2; j++) {
                int gn = n0 + wn + j * 16 + lrow;
                float bv = blk_b1[(size_t)i * INNER + gn];
#pragma unroll
                for (int r = 0; r < 4; r++) {
                    int gm = m0 + wm + lq * 4 + r;
                    float v = acc[j][r] + bv;
                    v = 0.5f * v * (1.f + erff(v * 0.70710678118654752f));
                    st2_cg(z1bf + (size_t)gm * INNER + gn, f2bf(v));
                }
            }
        }
        gsync(bar, ++ph * HGRID);
        {   // B: h += z1 @ w2 K-chunk (+b2 once via s==0)  (4 chunks x 64 tiles)
            int s = b >> 6, t = b & 63;
            int m0 = (t >> 3) * 32, n0 = (t & 7) * 64, kbeg = s * 512;
            u32x4 wreg[16], areg[8];
            stage_issue<64, 512, false>(
                w2T + (size_t)i * HID * INNER + (size_t)n0 * INNER + kbeg, INNER, wreg);
            stage_issue<32, 512, true>(z1bf + (size_t)m0 * INNER + kbeg, INNER, areg);
            waitvm0();
            stage_write<64, 512>(Bs, wreg);
            stage_write<32, 512>(As, areg);
            __syncthreads();
            acc[0] = zz; acc[1] = zz;
            mma_all<512>(As, Bs, acc);
#pragma unroll
            for (int j = 0; j < 2; j++) {
                int gn = n0 + wn + j * 16 + lrow;
                float bv = (s == 0) ? blk_b2[(size_t)i * HID + gn] : 0.f;
#pragma unroll
                for (int r = 0; r < 4; r++) {
                    int gm = m0 + wm + lq * 4 + r;
                    __hip_atomic_fetch_add(hbuf + (size_t)gm * HID + gn, acc[j][r] + bv,
                                           __ATOMIC_RELAXED, __HIP_MEMORY_SCOPE_AGENT);
                }
            }
        }
        gsync(bar, ++ph * HGRID);
    }

    // ---- pout: projb = h @ poutT + pout_b  (M=256,N=1536,K=512; 192 blocks)
    if (b < 192) {
        int m0 = (b / 24) * 32, n0 = (b % 24) * 64;
        u32x4 wreg[16], areg[16];
        stage_issue<64, 512, false>(poutT + (size_t)n0 * HID, HID, wreg);
#pragma unroll
        for (int it = 0; it < 16; it++) {
            int unit = it * 256 + tid;
            int row = unit >> 7, ucol = unit & 127;   // 128 units of 4 f32 per row
            areg[it] = ld16_cg(hbuf + (size_t)(m0 + row) * HID + ucol * 4);
        }
        waitvm0();
        stage_write<64, 512>(Bs, wreg);
#pragma unroll
        for (int it = 0; it < 16; it++) {
            int unit = it * 256 + tid;
            int row = unit >> 7, ucol = unit & 127;
            float a = __uint_as_float(areg[it][0]), c = __uint_as_float(areg[it][1]);
            float d = __uint_as_float(areg[it][2]), e = __uint_as_float(areg[it][3]);
            uint2 w2v;
            w2v.x = pk2(a, c);
            w2v.y = pk2(d, e);
            *(uint2*)&As[row * LDPA + ucol * 4] = w2v;
        }
        __syncthreads();
        acc[0] = zz; acc[1] = zz;
        mma_all<512>(As, Bs, acc);
#pragma unroll
        for (int j = 0; j < 2; j++) {
            int gn = n0 + wn + j * 16 + lrow;
            float bv = pout_b[gn];
#pragma unroll
            for (int r = 0; r < 4; r++) {
                int gm = m0 + wm + lq * 4 + r;
                projb[(size_t)gm * (NCLS * RANK) + gn] = f2bf(acc[j][r] + bv);
            }
        }
    }
}

// ---------------- launch ----------------
extern "C" void kernel_launch(void* const* d_in, const int* in_sizes, int n_in,
                              void* d_out, int out_size, void* d_ws, size_t ws_size,
                              hipStream_t stream) {
    const int* node_indices = (const int*)d_in[0];
    const int* edge_src = (const int*)d_in[1];
    const int* edge_dst = edge_src + NEDGES;
    const float* edge_w = (const float*)d_in[2];
    const float* partial_emb = (const float*)d_in[3];
    const float* oov_emb = (const float*)d_in[4];
    const float* gnn_ln_s = (const float*)d_in[5];
    const float* gnn_ln_b = (const float*)d_in[6];
    const float* gnn_w = (const float*)d_in[7];
    const float* gnn_b = (const float*)d_in[8];
    const float* post_w = (const float*)d_in[9];
    const float* post_b = (const float*)d_in[10];
    const float* pin_w = (const float*)d_in[11];
    const float* pin_b = (const float*)d_in[12];
    const float* blk_ln_s = (const float*)d_in[13];
    const float* blk_ln_b = (const float*)d_in[14];
    const float* blk_w1 = (const float*)d_in[15];
    const float* blk_b1 = (const float*)d_in[16];
    const float* blk_w2 = (const float*)d_in[17];
    const float* blk_b2 = (const float*)d_in[18];
    const float* pout_w = (const float*)d_in[19];
    const float* pout_b = (const float*)d_in[20];
    const float* gene = (const float*)d_in[21];
    float* out = (float*)d_out;

    char* p = (char*)d_ws;
    auto alloc = [&](size_t bytes) {
        char* r = p;
        p += (bytes + 255) & ~(size_t)255;
        return r;
    };
    int* counts = (int*)alloc(NNODES * 4);
    int* incl = (int*)alloc(NNODES * 4);
    int* bsums = (int*)alloc(128 * 4);
    int* boffs = (int*)alloc(128 * 4);
    int* row_start = (int*)alloc(NNODES * 4);
    int* cursor = (int*)alloc(NNODES * 4);
    int2* epack = (int2*)alloc((size_t)NEDGES * 8);
    // 'part': GNN phase scratch = ln_bf + aggbf (bf16)
    float* part = (float*)alloc((size_t)NNODES * GDIM * 4);
    unsigned short* ln_bf = (unsigned short*)part;
    unsigned short* aggbf = (unsigned short*)((char*)part + (size_t)NNODES * GDIM * 2);
    float* xa = (float*)alloc((size_t)NNODES * GDIM * 4);
    float* xb = (float*)alloc((size_t)NNODES * GDIM * 4);
    float* hbuf = (float*)alloc((size_t)BSZ * HID * 4);
    unsigned short* aggselb = (unsigned short*)alloc((size_t)BSZ * GDIM * 2);
    unsigned short* pertinbf = (unsigned short*)alloc((size_t)BSZ * GDIM * 2);
    unsigned short* pertbf = (unsigned short*)alloc((size_t)BSZ * GDIM * 2);
    unsigned short* zlnbf = (unsigned short*)alloc((size_t)BSZ * HID * 2);
    unsigned short* z1bf = (unsigned short*)alloc((size_t)BSZ * INNER * 2);
    unsigned short* hbufbf = (unsigned short*)alloc((size_t)BSZ * HID * 2);
    unsigned short* projb = (unsigned short*)alloc((size_t)BSZ * NCLS * RANK * 2);
    unsigned short* gnnT = (unsigned short*)alloc((size_t)3 * GDIM * GDIM * 2);
    unsigned short* postT = (unsigned short*)alloc((size_t)GDIM * GDIM * 2);
    unsigned short* pinT = (unsigned short*)alloc((size_t)HID * GDIM * 2);
    unsigned short* w1T = (unsigned short*)alloc((size_t)6 * INNER * HID * 2);
    unsigned short* w2T = (unsigned short*)alloc((size_t)6 * HID * INNER * 2);
    unsigned short* poutT = (unsigned short*)alloc((size_t)NCLS * RANK * HID * 2);
    unsigned short* geneb = (unsigned short*)alloc((size_t)NGENES * RANK * 2);
    int* bar = (int*)alloc(256);

    const int EB = (NEDGES + 255) / 256;
    const int NB = (NNODES + 255) / 256;

    // all weight conversions in one dispatch
    convall_k<<<15100, 256, 0, stream>>>(gnn_w, post_w, pin_w, blk_w1, blk_w2, pout_w, gene,
                                         gnnT, postT, pinT, w1T, w2T, poutT, geneb);

    // CSR build
    (void)hipMemsetAsync(counts, 0, NNODES * 4, stream);
    (void)hipMemsetAsync(bar, 0, 4, stream);
    hist_k<<<EB, 256, 0, stream>>>(edge_dst, counts, NEDGES);
    scan1_k<<<NB, 256, 0, stream>>>(counts, incl, bsums, NNODES);
    scan2_k<<<1, 128, 0, stream>>>(bsums, boffs, NB);
    scan3_k<<<NB, 256, 0, stream>>>(incl, counts, boffs, row_start, cursor, NNODES);
    scatter_k<<<EB, 256, 0, stream>>>(edge_src, edge_dst, edge_w, cursor, epack, NEDGES);

    // GNN layers 1 & 2 (full), layer 3 (selective)
    const float* x_in = partial_emb;
    float* bufs[2] = {xa, xb};
    for (int i = 0; i < 2; i++) {
        lnb_k<<<(NNODES + 3) / 4, 256, 0, stream>>>(x_in, gnn_ln_s + i * GDIM,
                                                    gnn_ln_b + i * GDIM, ln_bf, NNODES);
        aggb_k<<<(NNODES + 3) / 4, 256, 0, stream>>>(row_start, counts, epack, ln_bf, aggbf,
                                                     NNODES);
        float* x_out = bufs[i];
        mgemm_k<1, true, true><<<dim3(GDIM / 128, (NNODES + 127) / 128), 256, 0, stream>>>(
            aggbf, gnnT + (size_t)i * GDIM * GDIM, gnn_b + i * GDIM, x_in, x_out, NNODES, GDIM,
            GDIM);
        x_in = x_out;
    }
    lnb_k<<<(NNODES + 3) / 4, 256, 0, stream>>>(xb, gnn_ln_s + 2 * GDIM, gnn_ln_b + 2 * GDIM,
                                                ln_bf, NNODES);
    aggsel_k<<<BSZ / 4, 256, 0, stream>>>(node_indices, row_start, counts, epack, ln_bf, aggselb);
    mfull_k<1, 2><<<dim3(GDIM / 64, BSZ / 64), 256, 0, stream>>>(
        aggselb, gnnT + (size_t)2 * GDIM * GDIM, gnn_b + 2 * GDIM, node_indices, xb, pertinbf,
        BSZ, GDIM, GDIM);

    // post_mp + OOV replace (fused)
    mfull_k<0, 1><<<dim3(GDIM / 64, BSZ / 64), 256, 0, stream>>>(
        pertinbf, postT, post_b, node_indices, oov_emb, pertbf, BSZ, GDIM, GDIM);

    // fused head: pin + 6 blocks + pout in ONE persistent kernel (13 grid syncs)
    head_k<<<HGRID, 256, 0, stream>>>(pertbf, pinT, pin_b, blk_ln_s, blk_ln_b, w1T, blk_b1, w2T,
                                      blk_b2, poutT, pout_b, hbuf, z1bf, projb, bar);

    // logits
    mgemm_k<0, false, false><<<dim3((NGENES + 127) / 128, (BSZ * NCLS) / 128), 256, 0, stream>>>(
        projb, geneb, nullptr, nullptr, out, BSZ * NCLS, NGENES, RANK);
}

// Round 6
// 555.203 us; speedup vs baseline: 1.8029x; 1.1114x over previous
//
#include <hip/hip_runtime.h>
#include <hip/hip_bf16.h>
#include <math.h>

#define NNODES 20000
#define NEDGES 640000
#define BSZ 256
#define GDIM 256
#define HID 512
#define INNER 2048
#define RANK 512
#define NCLS 3
#define NGENES 6640

typedef __attribute__((ext_vector_type(8))) short bf16x8;
typedef __attribute__((ext_vector_type(4))) float f32x4;
typedef __attribute__((ext_vector_type(4))) unsigned u32x4;   // native vector: legal asm "v" operand

__device__ inline float bf2f(unsigned short u) {
    return __uint_as_float(((unsigned)u) << 16);
}
__device__ inline unsigned short f2bf(float f) {
    unsigned u = __float_as_uint(f);
    u = u + 0x7fff + ((u >> 16) & 1);   // RNE
    return (unsigned short)(u >> 16);
}
__device__ inline unsigned pk2(float a, float b) {
    return (unsigned)f2bf(a) | ((unsigned)f2bf(b) << 16);
}

// ---- device-coherent (cross-XCD) loads/stores: bypass L1/L2, complete at the
// memory-side coherence point. Used ONLY for the head's cross-phase activation
// buffers so the grid barrier needs NO cache maintenance (no buffer_wbl2 /
// buffer_inv -> weights stay L2-hot). Proven: 565 -> 365 -> 199 -> 178 us.
__device__ inline u32x4 ld16_cg(const void* p) {
    u32x4 r;
    asm volatile("global_load_dwordx4 %0, %1, off sc0 sc1" : "=v"(r) : "v"(p) : "memory");
    return r;
}
__device__ inline void st4f_cg(void* p, float v) {
    asm volatile("global_store_dword %0, %1, off sc0 sc1" :: "v"(p), "v"(v) : "memory");
}
__device__ inline void st2_cg(void* p, unsigned short v) {
    unsigned w = v;
    asm volatile("global_store_short %0, %1, off sc0 sc1" :: "v"(p), "v"(w) : "memory");
}
__device__ inline void waitvm0(void) {
    asm volatile("s_waitcnt vmcnt(0)" ::: "memory");
    __builtin_amdgcn_sched_barrier(0);
}

// ---------------- CSR build ----------------
__global__ void hist_k(const int* __restrict__ dst, int* __restrict__ counts, int E) {
    int e = blockIdx.x * 256 + threadIdx.x;
    if (e < E) atomicAdd(&counts[dst[e]], 1);
}

__global__ void scan1_k(const int* __restrict__ counts, int* __restrict__ incl,
                        int* __restrict__ bsums, int n) {
    __shared__ int s[256];
    int i = blockIdx.x * 256 + threadIdx.x;
    int v = (i < n) ? counts[i] : 0;
    s[threadIdx.x] = v;
    __syncthreads();
    for (int off = 1; off < 256; off <<= 1) {
        int t = (threadIdx.x >= off) ? s[threadIdx.x - off] : 0;
        __syncthreads();
        s[threadIdx.x] += t;
        __syncthreads();
    }
    if (i < n) incl[i] = s[threadIdx.x];
    if (threadIdx.x == 255) bsums[blockIdx.x] = s[255];
}

__global__ void scan2_k(const int* __restrict__ bsums, int* __restrict__ boffs, int nb) {
    __shared__ int s[128];
    int tid = threadIdx.x;
    int v = (tid < nb) ? bsums[tid] : 0;
    s[tid] = v;
    __syncthreads();
    for (int off = 1; off < 128; off <<= 1) {
        int t = (tid >= off) ? s[tid - off] : 0;
        __syncthreads();
        s[tid] += t;
        __syncthreads();
    }
    if (tid < nb) boffs[tid] = s[tid] - v;
}

__global__ void scan3_k(const int* __restrict__ incl, const int* __restrict__ counts,
                        const int* __restrict__ boffs, int* __restrict__ row_start,
                        int* __restrict__ cursor, int n) {
    int i = blockIdx.x * 256 + threadIdx.x;
    if (i < n) {
        int st = incl[i] - counts[i] + boffs[blockIdx.x];
        row_start[i] = st;
        cursor[i] = st;
    }
}

__global__ void scatter_k(const int* __restrict__ src, const int* __restrict__ dst,
                          const float* __restrict__ w, int* __restrict__ cursor,
                          int2* __restrict__ ep, int E) {
    int e = blockIdx.x * 256 + threadIdx.x;
    if (e < E) {
        int d = dst[e];
        int p = atomicAdd(&cursor[d], 1);
        ep[p] = make_int2(src[e], __float_as_int(w[e]));
    }
}

// ---------------- combined weight conversion ----------------
__global__ void convall_k(const float* __restrict__ gnn_w, const float* __restrict__ post_w,
                          const float* __restrict__ pin_w, const float* __restrict__ blk_w1,
                          const float* __restrict__ blk_w2, const float* __restrict__ pout_w,
                          const float* __restrict__ gene, unsigned short* __restrict__ gnnT,
                          unsigned short* __restrict__ postT, unsigned short* __restrict__ pinT,
                          unsigned short* __restrict__ w1T, unsigned short* __restrict__ w2T,
                          unsigned short* __restrict__ poutT,
                          unsigned short* __restrict__ geneb) {
    int b = blockIdx.x;
    if (b >= 13440) {   // gene: plain fp32 -> bf16 convert, 2048 elems/block
        int t = b - 13440;
        const float4* xp = (const float4*)gene;
        int i = t * 512 + threadIdx.x * 2;    // float4 index
        float4 a = xp[i], c = xp[i + 1];
        *(ushort4*)(geneb + (size_t)i * 4) =
            make_ushort4(f2bf(a.x), f2bf(a.y), f2bf(a.z), f2bf(a.w));
        *(ushort4*)(geneb + (size_t)i * 4 + 4) =
            make_ushort4(f2bf(c.x), f2bf(c.y), f2bf(c.z), f2bf(c.w));
        return;
    }
    const float* W;
    unsigned short* WT;
    int K, N, tile;
    if (b < 192) {
        int l = b >> 6;
        tile = b & 63;
        W = gnn_w + (size_t)l * GDIM * GDIM;
        WT = gnnT + (size_t)l * GDIM * GDIM;
        K = GDIM; N = GDIM;
    } else if (b < 256) {
        tile = b - 192; W = post_w; WT = postT; K = GDIM; N = GDIM;
    } else if (b < 384) {
        tile = b - 256; W = pin_w; WT = pinT; K = GDIM; N = HID;
    } else if (b < 6528) {
        int t = b - 384;
        int l = t >> 10;
        tile = t & 1023;
        W = blk_w1 + (size_t)l * HID * INNER;
        WT = w1T + (size_t)l * INNER * HID;
        K = HID; N = INNER;
    } else if (b < 12672) {
        int t = b - 6528;
        int l = t >> 10;
        tile = t & 1023;
        W = blk_w2 + (size_t)l * INNER * HID;
        WT = w2T + (size_t)l * HID * INNER;
        K = INNER; N = HID;
    } else {
        tile = b - 12672; W = pout_w; WT = poutT; K = HID; N = NCLS * RANK;
    }
    __shared__ float s[32][33];
    int ntx = N >> 5;
    int k0 = (tile / ntx) << 5;
    int n0 = (tile % ntx) << 5;
    int tx = threadIdx.x & 31, ty = threadIdx.x >> 5;
#pragma unroll
    for (int i = 0; i < 4; i++)
        s[ty + 8 * i][tx] = W[(size_t)(k0 + ty + 8 * i) * N + n0 + tx];
    __syncthreads();
#pragma unroll
    for (int i = 0; i < 4; i++)
        WT[(size_t)(n0 + ty + 8 * i) * K + k0 + tx] = f2bf(s[tx][ty + 8 * i]);
}

// ---------------- GNN LayerNorm (D=256), bf16 out ----------------
__global__ void lnb_k(const float* __restrict__ X, const float* __restrict__ sc,
                      const float* __restrict__ bi, unsigned short* __restrict__ Y, int M) {
    int row = blockIdx.x * 4 + (threadIdx.x >> 6);
    int lane = threadIdx.x & 63;
    if (row >= M) return;
    float4 v = ((const float4*)(X + (size_t)row * GDIM))[lane];
    float sum = v.x + v.y + v.z + v.w;
#pragma unroll
    for (int off = 32; off >= 1; off >>= 1) sum += __shfl_xor(sum, off);
    float mu = sum / GDIM;
    float a = v.x - mu, b = v.y - mu, c = v.z - mu, d = v.w - mu;
    float sq = a * a + b * b + c * c + d * d;
#pragma unroll
    for (int off = 32; off >= 1; off >>= 1) sq += __shfl_xor(sq, off);
    float rstd = rsqrtf(sq / GDIM + 1e-5f);
    float4 s4 = ((const float4*)sc)[lane];
    float4 b4 = ((const float4*)bi)[lane];
    *(ushort4*)(Y + (size_t)row * GDIM + lane * 4) =
        make_ushort4(f2bf(a * rstd * s4.x + b4.x), f2bf(b * rstd * s4.y + b4.y),
                     f2bf(c * rstd * s4.z + b4.z), f2bf(d * rstd * s4.w + b4.w));
}

// ---------------- CSR aggregation, 16-deep MLP unroll ----------------
__device__ inline void agg_row(int beg, int cnt, int lane, const int2* __restrict__ ep,
                               const unsigned short* __restrict__ H, float& a0, float& a1,
                               float& a2, float& a3) {
    int t = 0;
    for (; t + 16 <= cnt; t += 16) {
        int2 e[16];
#pragma unroll
        for (int u = 0; u < 16; u++) e[u] = ep[beg + t + u];
        ushort4 v[16];
#pragma unroll
        for (int u = 0; u < 16; u++)
            v[u] = *(const ushort4*)(H + (size_t)e[u].x * GDIM + lane * 4);
#pragma unroll
        for (int u = 0; u < 16; u++) {
            float w = __int_as_float(e[u].y);
            a0 = fmaf(bf2f(v[u].x), w, a0);
            a1 = fmaf(bf2f(v[u].y), w, a1);
            a2 = fmaf(bf2f(v[u].z), w, a2);
            a3 = fmaf(bf2f(v[u].w), w, a3);
        }
    }
    for (; t + 4 <= cnt; t += 4) {
        int2 e[4];
#pragma unroll
        for (int u = 0; u < 4; u++) e[u] = ep[beg + t + u];
        ushort4 v[4];
#pragma unroll
        for (int u = 0; u < 4; u++)
            v[u] = *(const ushort4*)(H + (size_t)e[u].x * GDIM + lane * 4);
#pragma unroll
        for (int u = 0; u < 4; u++) {
            float w = __int_as_float(e[u].y);
            a0 = fmaf(bf2f(v[u].x), w, a0);
            a1 = fmaf(bf2f(v[u].y), w, a1);
            a2 = fmaf(bf2f(v[u].z), w, a2);
            a3 = fmaf(bf2f(v[u].w), w, a3);
        }
    }
    for (; t < cnt; t++) {
        int2 e = ep[beg + t];
        float w = __int_as_float(e.y);
        ushort4 v = *(const ushort4*)(H + (size_t)e.x * GDIM + lane * 4);
        a0 = fmaf(bf2f(v.x), w, a0);
        a1 = fmaf(bf2f(v.y), w, a1);
        a2 = fmaf(bf2f(v.z), w, a2);
        a3 = fmaf(bf2f(v.w), w, a3);
    }
}

__global__ void aggb_k(const int* __restrict__ row_start, const int* __restrict__ counts,
                       const int2* __restrict__ ep, const unsigned short* __restrict__ H,
                       unsigned short* __restrict__ AGG, int n) {
    int row = blockIdx.x * 4 + (threadIdx.x >> 6);
    int lane = threadIdx.x & 63;
    if (row >= n) return;
    float a0 = 0.f, a1 = 0.f, a2 = 0.f, a3 = 0.f;
    agg_row(row_start[row], counts[row], lane, ep, H, a0, a1, a2, a3);
    *(ushort4*)(AGG + (size_t)row * GDIM + lane * 4) =
        make_ushort4(f2bf(a0), f2bf(a1), f2bf(a2), f2bf(a3));
}

__global__ void aggsel_k(const int* __restrict__ idx, const int* __restrict__ row_start,
                         const int* __restrict__ counts, const int2* __restrict__ ep,
                         const unsigned short* __restrict__ H, unsigned short* __restrict__ AGG) {
    int b = blockIdx.x * 4 + (threadIdx.x >> 6);
    int lane = threadIdx.x & 63;
    int id = idx[b];
    int row = id < 0 ? 0 : id;
    float a0 = 0.f, a1 = 0.f, a2 = 0.f, a3 = 0.f;
    agg_row(row_start[row], counts[row], lane, ep, H, a0, a1, a2, a3);
    *(ushort4*)(AGG + (size_t)b * GDIM + lane * 4) =
        make_ushort4(f2bf(a0), f2bf(a1), f2bf(a2), f2bf(a3));
}

// ---------------- bf16 MFMA GEMM (full-K, fp32 out, fused epilogue) — GNN L1/L2 & logits ----------------
template <int ACT, bool RES, bool BIAS>
__global__ __launch_bounds__(256) void mgemm_k(const unsigned short* __restrict__ A,
                                               const unsigned short* __restrict__ BT,
                                               const float* __restrict__ bias,
                                               const float* __restrict__ R,
                                               float* __restrict__ C, int M, int N, int K) {
    __shared__ unsigned short As[128 * 32];
    __shared__ unsigned short Bs[128 * 32];
    int m0 = blockIdx.y * 128, n0 = blockIdx.x * 128;
    int tid = threadIdx.x;
    int wave = tid >> 6, lane = tid & 63;
    int wm = (wave >> 1) * 64, wn = (wave & 1) * 64;
    int lrow = lane & 15, lq = lane >> 4;

    f32x4 acc[4][4];
    const f32x4 zz = {0.f, 0.f, 0.f, 0.f};
#pragma unroll
    for (int i = 0; i < 4; i++)
#pragma unroll
        for (int j = 0; j < 4; j++) acc[i][j] = zz;

    int r0 = tid >> 2;
    int q = tid & 3;

    for (int k0 = 0; k0 < K; k0 += 32) {
#pragma unroll
        for (int p = 0; p < 2; p++) {
            int row = r0 + p * 64;
            int gm = m0 + row;
            uint4 va = make_uint4(0, 0, 0, 0);
            if (gm < M) va = *(const uint4*)(A + (size_t)gm * K + k0 + q * 8);
            *(uint4*)&As[row * 32 + q * 8] = va;
            int gn = n0 + row;
            uint4 vb = make_uint4(0, 0, 0, 0);
            if (gn < N) vb = *(const uint4*)(BT + (size_t)gn * K + k0 + q * 8);
            *(uint4*)&Bs[row * 32 + q * 8] = vb;
        }
        __syncthreads();
        bf16x8 af[4], bf[4];
#pragma unroll
        for (int i = 0; i < 4; i++)
            af[i] = *(const bf16x8*)&As[(wm + i * 16 + lrow) * 32 + lq * 8];
#pragma unroll
        for (int j = 0; j < 4; j++)
            bf[j] = *(const bf16x8*)&Bs[(wn + j * 16 + lrow) * 32 + lq * 8];
#pragma unroll
        for (int i = 0; i < 4; i++)
#pragma unroll
            for (int j = 0; j < 4; j++)
                acc[i][j] =
                    __builtin_amdgcn_mfma_f32_16x16x32_bf16(af[i], bf[j], acc[i][j], 0, 0, 0);
        __syncthreads();
    }

#pragma unroll
    for (int i = 0; i < 4; i++) {
#pragma unroll
        for (int j = 0; j < 4; j++) {
            int gn = n0 + wn + j * 16 + lrow;
            if (gn >= N) continue;
            float bv = BIAS ? bias[gn] : 0.f;
#pragma unroll
            for (int r = 0; r < 4; r++) {
                int gm = m0 + wm + i * 16 + lq * 4 + r;
                if (gm >= M) continue;
                float v = acc[i][j][r] + bv;
                if (ACT == 1) v = fmaxf(v, 0.f);
                if (RES) v += R[(size_t)gm * N + gn];
                C[(size_t)gm * N + gn] = v;
            }
        }
    }
}

// ---------------- bf16 MFMA full-K, bf16 out, fused epilogue (GNN L3 / post) ----------------
template <int ACT, int EPI>
__global__ __launch_bounds__(256) void mfull_k(const unsigned short* __restrict__ A,
                                               const unsigned short* __restrict__ BT,
                                               const float* __restrict__ bias,
                                               const int* __restrict__ idx,
                                               const float* __restrict__ aux,
                                               unsigned short* __restrict__ O, int M, int N,
                                               int K) {
    __shared__ unsigned short As[64 * 32];
    __shared__ unsigned short Bs[64 * 32];
    int m0 = blockIdx.y * 64, n0 = blockIdx.x * 64;
    int tid = threadIdx.x;
    int wave = tid >> 6, lane = tid & 63;
    int wm = wave * 16;
    int lrow = lane & 15, lq = lane >> 4;
    f32x4 acc[4];
    const f32x4 zz = {0.f, 0.f, 0.f, 0.f};
#pragma unroll
    for (int j = 0; j < 4; j++) acc[j] = zz;
    int r0 = tid >> 2;
    int q = tid & 3;
    for (int k0 = 0; k0 < K; k0 += 32) {
        *(uint4*)&As[r0 * 32 + q * 8] = *(const uint4*)(A + (size_t)(m0 + r0) * K + k0 + q * 8);
        *(uint4*)&Bs[r0 * 32 + q * 8] = *(const uint4*)(BT + (size_t)(n0 + r0) * K + k0 + q * 8);
        __syncthreads();
        bf16x8 af = *(const bf16x8*)&As[(wm + lrow) * 32 + lq * 8];
#pragma unroll
        for (int j = 0; j < 4; j++) {
            bf16x8 bfr = *(const bf16x8*)&Bs[(j * 16 + lrow) * 32 + lq * 8];
            acc[j] = __builtin_amdgcn_mfma_f32_16x16x32_bf16(af, bfr, acc[j], 0, 0, 0);
        }
        __syncthreads();
    }
#pragma unroll
    for (int j = 0; j < 4; j++) {
        int gn = n0 + j * 16 + lrow;
        float bv = bias[gn];
#pragma unroll
        for (int r = 0; r < 4; r++) {
            int gm = m0 + wm + lq * 4 + r;
            float v = acc[j][r] + bv;
            if (ACT == 1) v = fmaxf(v, 0.f);
            if (ACT == 2) v = 0.5f * v * (1.f + erff(v * 0.70710678118654752f));
            if (EPI == 2) {
                int id = idx[gm];
                int safe = id < 0 ? 0 : id;
                v += aux[(size_t)safe * N + gn];
            }
            if (EPI == 1) {
                if (idx[gm] < 0) v = aux[gn];
            }
            O[(size_t)gm * N + gn] = f2bf(v);
        }
    }
}

// ================= fused persistent head (v4: 8 independent 32-block row-groups) =================
// Group g (blocks g*32..g*32+31) owns rows [32g,32g+32). ALL cross-phase data for
// those rows (h, z1) is produced and consumed within the group -> per-group barrier
// (32 arrivals), groups pipeline independently. XCD locality: b%8 == (rank%8) ==
// n-slice index, so each weight slice lives in exactly one XCD's L2.

#define HGRID 256
#define LDPA 520   // ushort row stride for K<=512 tiles: 1040B -> bank-optimal b128 reads
#define GBLK 32    // blocks per group

__device__ inline void gsync(int* bar, int target) {
    waitvm0();   // drain this thread's cg-stores/atomics (globally visible at retire)
    __syncthreads();
    if (threadIdx.x == 0) {
        __hip_atomic_fetch_add(bar, 1, __ATOMIC_RELAXED, __HIP_MEMORY_SCOPE_AGENT);
        while (__hip_atomic_load(bar, __ATOMIC_RELAXED, __HIP_MEMORY_SCOPE_AGENT) < target)
            __builtin_amdgcn_s_sleep(2);
    }
    __syncthreads();
}

// issue ROWSxKC bf16 tile loads (all outstanding), NL = ROWS*KC/2048 regs/thread
template <int ROWS, int KC, bool CG>
__device__ inline void stage_issue(const unsigned short* src, int ld, u32x4* regs) {
    constexpr int NL = ROWS * KC / 8 / 256;
    int tid = threadIdx.x;
#pragma unroll
    for (int it = 0; it < NL; it++) {
        int unit = it * 256 + tid;
        int row = unit / (KC / 8);
        int ucol = unit % (KC / 8);
        const unsigned short* p = src + (size_t)row * ld + ucol * 8;
        if (CG) regs[it] = ld16_cg(p);
        else regs[it] = *(const u32x4*)p;
    }
}
template <int ROWS, int KC>
__device__ inline void stage_write(unsigned short* dst, const u32x4* regs) {
    constexpr int NL = ROWS * KC / 8 / 256;
    int tid = threadIdx.x;
#pragma unroll
    for (int it = 0; it < NL; it++) {
        int unit = it * 256 + tid;
        int row = unit / (KC / 8);
        int ucol = unit % (KC / 8);
        *(u32x4*)&dst[row * LDPA + ucol * 8] = regs[it];
    }
}

// uninterrupted MFMA stream over the fully-staged tile (no inner barriers)
template <int KC>
__device__ inline void mma_all(const unsigned short* As, const unsigned short* Bs, f32x4 acc[2]) {
    int tid = threadIdx.x, wave = tid >> 6, lane = tid & 63;
    int wm = (wave >> 1) * 16, wn = (wave & 1) * 32;
    int lrow = lane & 15, lq = lane >> 4;
#pragma unroll
    for (int kk = 0; kk < KC / 32; kk++) {
        bf16x8 af = *(const bf16x8*)&As[(wm + lrow) * LDPA + kk * 32 + lq * 8];
#pragma unroll
        for (int j = 0; j < 2; j++) {
            bf16x8 bfr = *(const bf16x8*)&Bs[(wn + j * 16 + lrow) * LDPA + kk * 32 + lq * 8];
            acc[j] = __builtin_amdgcn_mfma_f32_16x16x32_bf16(af, bfr, acc[j], 0, 0, 0);
        }
    }
}

__global__ __launch_bounds__(256) void head_k(
    const unsigned short* __restrict__ pertbf, const unsigned short* __restrict__ pinT,
    const float* __restrict__ pin_b, const float* __restrict__ blk_ln_s,
    const float* __restrict__ blk_ln_b, const unsigned short* __restrict__ w1T,
    const float* __restrict__ blk_b1, const unsigned short* __restrict__ w2T,
    const float* __restrict__ blk_b2, const unsigned short* __restrict__ poutT,
    const float* __restrict__ pout_b, float* __restrict__ hbuf,
    unsigned short* __restrict__ z1bf, unsigned short* __restrict__ projb,
    int* __restrict__ bar) {
    __shared__ unsigned short As[32 * LDPA];   // 33.3 KB
    __shared__ unsigned short Bs[64 * LDPA];   // 66.6 KB
    int b = blockIdx.x;
    int g = b >> 5;          // row-group 0..7: rows [g*32, g*32+32)
    int t = b & 31;          // rank within group; b%8 == t%8 -> XCD locality by n-slice
    int* gbar = bar + g * 32;   // per-group counter, 128 B apart
    int m0 = g * 32;
    int tid = threadIdx.x;
    int wave = tid >> 6, lane = tid & 63;
    int wm = (wave >> 1) * 16, wn = (wave & 1) * 32;
    int lrow = lane & 15, lq = lane >> 4;
    int ph = 0;
    f32x4 acc[2];
    const f32x4 zz = {0.f, 0.f, 0.f, 0.f};

    // ---- P0: h[g-rows] = pertbf @ pinT + pin_b  (8 active blocks/group, full K=256)
    if (t < 8) {
        int n0 = t * 64;
        u32x4 wreg[8], areg[4];
        stage_issue<64, 256, false>(pinT + (size_t)n0 * GDIM, GDIM, wreg);
        stage_issue<32, 256, false>(pertbf + (size_t)m0 * GDIM, GDIM, areg);
        waitvm0();
        stage_write<64, 256>(Bs, wreg);
        stage_write<32, 256>(As, areg);
        __syncthreads();
        acc[0] = zz; acc[1] = zz;
        mma_all<256>(As, Bs, acc);
#pragma unroll
        for (int j = 0; j < 2; j++) {
            int gn = n0 + wn + j * 16 + lrow;
            float bv = pin_b[gn];
#pragma unroll
            for (int r = 0; r < 4; r++) {
                int gm = m0 + wm + lq * 4 + r;
                st4f_cg(hbuf + (size_t)gm * HID + gn, acc[j][r] + bv);
            }
        }
    }
    gsync(gbar, ++ph * GBLK);

    for (int i = 0; i < 6; i++) {
        {   // A: z1[g-rows] = gelu(LN_i(h) @ w1 + b1); 32 blocks x 64-col slices, K=512
            int n0 = t * 64;
            u32x4 wreg[16], hreg[16];
            stage_issue<64, 512, false>(w1T + (size_t)i * INNER * HID + (size_t)n0 * HID, HID,
                                        wreg);
            // issue h loads: wave w owns rows m0+w*8 .. +8, lane covers 8 f32 of each row
#pragma unroll
            for (int rr = 0; rr < 8; rr++) {
                const float* p = hbuf + (size_t)(m0 + wave * 8 + rr) * HID + lane * 8;
                hreg[2 * rr] = ld16_cg(p);
                hreg[2 * rr + 1] = ld16_cg(p + 4);
            }
            waitvm0();
            stage_write<64, 512>(Bs, wreg);
            // inline LayerNorm (redundant across the 32 n-slices, cheap) -> bf16 As
            const float* ls = blk_ln_s + (size_t)i * HID;
            const float* lb = blk_ln_b + (size_t)i * HID;
            float4 s0 = ((const float4*)ls)[lane * 2], s1 = ((const float4*)ls)[lane * 2 + 1];
            float4 t0 = ((const float4*)lb)[lane * 2], t1 = ((const float4*)lb)[lane * 2 + 1];
#pragma unroll
            for (int rr = 0; rr < 8; rr++) {
                float f0 = __uint_as_float(hreg[2 * rr][0]);
                float f1 = __uint_as_float(hreg[2 * rr][1]);
                float f2 = __uint_as_float(hreg[2 * rr][2]);
                float f3 = __uint_as_float(hreg[2 * rr][3]);
                float f4 = __uint_as_float(hreg[2 * rr + 1][0]);
                float f5 = __uint_as_float(hreg[2 * rr + 1][1]);
                float f6 = __uint_as_float(hreg[2 * rr + 1][2]);
                float f7 = __uint_as_float(hreg[2 * rr + 1][3]);
                float sum = f0 + f1 + f2 + f3 + f4 + f5 + f6 + f7;
#pragma unroll
                for (int off = 32; off >= 1; off >>= 1) sum += __shfl_xor(sum, off);
                float mu = sum * (1.f / HID);
                float d0 = f0 - mu, d1 = f1 - mu, d2 = f2 - mu, d3 = f3 - mu;
                float d4 = f4 - mu, d5 = f5 - mu, d6 = f6 - mu, d7 = f7 - mu;
                float sq = d0 * d0 + d1 * d1 + d2 * d2 + d3 * d3 + d4 * d4 + d5 * d5 +
                           d6 * d6 + d7 * d7;
#pragma unroll
                for (int off = 32; off >= 1; off >>= 1) sq += __shfl_xor(sq, off);
                float rstd = rsqrtf(sq * (1.f / HID) + 1e-5f);
                u32x4 pk;
                pk[0] = pk2(d0 * rstd * s0.x + t0.x, d1 * rstd * s0.y + t0.y);
                pk[1] = pk2(d2 * rstd * s0.z + t0.z, d3 * rstd * s0.w + t0.w);
                pk[2] = pk2(d4 * rstd * s1.x + t1.x, d5 * rstd * s1.y + t1.y);
                pk[3] = pk2(d6 * rstd * s1.z + t1.z, d7 * rstd * s1.w + t1.w);
                *(u32x4*)&As[(wave * 8 + rr) * LDPA + lane * 8] = pk;
            }
            __syncthreads();
            acc[0] = zz; acc[1] = zz;
            mma_all<512>(As, Bs, acc);
#pragma unroll
            for (int j = 0; j < 2; j++) {
                int gn = n0 + wn + j * 16 + lrow;
                float bv = blk_b1[(size_t)i * INNER + gn];
#pragma unroll
                for (int r = 0; r < 4; r++) {
                    int gm = m0 + wm + lq * 4 + r;
                    float v = acc[j][r] + bv;
                    v = 0.5f * v * (1.f + erff(v * 0.70710678118654752f));
                    st2_cg(z1bf + (size_t)gm * INNER + gn, f2bf(v));
                }
            }
        }
        gsync(gbar, ++ph * GBLK);
        {   // B: h[g-rows] += z1 @ w2 K-chunk (+b2 once via s==0); 8n x 4s per group
            int s = t >> 3, n0 = (t & 7) * 64, kbeg = s * 512;
            u32x4 wreg[16], areg[8];
            stage_issue<64, 512, false>(
                w2T + (size_t)i * HID * INNER + (size_t)n0 * INNER + kbeg, INNER, wreg);
            stage_issue<32, 512, true>(z1bf + (size_t)m0 * INNER + kbeg, INNER, areg);
            waitvm0();
            stage_write<64, 512>(Bs, wreg);
            stage_write<32, 512>(As, areg);
            __syncthreads();
            acc[0] = zz; acc[1] = zz;
            mma_all<512>(As, Bs, acc);
#pragma unroll
            for (int j = 0; j < 2; j++) {
                int gn = n0 + wn + j * 16 + lrow;
                float bv = (s == 0) ? blk_b2[(size_t)i * HID + gn] : 0.f;
#pragma unroll
                for (int r = 0; r < 4; r++) {
                    int gm = m0 + wm + lq * 4 + r;
                    __hip_atomic_fetch_add(hbuf + (size_t)gm * HID + gn, acc[j][r] + bv,
                                           __ATOMIC_RELAXED, __HIP_MEMORY_SCOPE_AGENT);
                }
            }
        }
        gsync(gbar, ++ph * GBLK);
    }

    // ---- pout: projb[g-rows] = h @ poutT + pout_b  (24 active blocks/group, K=512)
    if (t < 24) {
        int n0 = t * 64;
        u32x4 wreg[16], areg[16];
        stage_issue<64, 512, false>(poutT + (size_t)n0 * HID, HID, wreg);
#pragma unroll
        for (int it = 0; it < 16; it++) {
            int unit = it * 256 + tid;
            int row = unit >> 7, ucol = unit & 127;   // 128 units of 4 f32 per row
            areg[it] = ld16_cg(hbuf + (size_t)(m0 + row) * HID + ucol * 4);
        }
        waitvm0();
        stage_write<64, 512>(Bs, wreg);
#pragma unroll
        for (int it = 0; it < 16; it++) {
            int unit = it * 256 + tid;
            int row = unit >> 7, ucol = unit & 127;
            float a = __uint_as_float(areg[it][0]), c = __uint_as_float(areg[it][1]);
            float d = __uint_as_float(areg[it][2]), e = __uint_as_float(areg[it][3]);
            uint2 w2v;
            w2v.x = pk2(a, c);
            w2v.y = pk2(d, e);
            *(uint2*)&As[row * LDPA + ucol * 4] = w2v;
        }
        __syncthreads();
        acc[0] = zz; acc[1] = zz;
        mma_all<512>(As, Bs, acc);
#pragma unroll
        for (int j = 0; j < 2; j++) {
            int gn = n0 + wn + j * 16 + lrow;
            float bv = pout_b[gn];
#pragma unroll
            for (int r = 0; r < 4; r++) {
                int gm = m0 + wm + lq * 4 + r;
                projb[(size_t)gm * (NCLS * RANK) + gn] = f2bf(acc[j][r] + bv);
            }
        }
    }
}

// ---------------- launch ----------------
extern "C" void kernel_launch(void* const* d_in, const int* in_sizes, int n_in,
                              void* d_out, int out_size, void* d_ws, size_t ws_size,
                              hipStream_t stream) {
    const int* node_indices = (const int*)d_in[0];
    const int* edge_src = (const int*)d_in[1];
    const int* edge_dst = edge_src + NEDGES;
    const float* edge_w = (const float*)d_in[2];
    const float* partial_emb = (const float*)d_in[3];
    const float* oov_emb = (const float*)d_in[4];
    const float* gnn_ln_s = (const float*)d_in[5];
    const float* gnn_ln_b = (const float*)d_in[6];
    const float* gnn_w = (const float*)d_in[7];
    const float* gnn_b = (const float*)d_in[8];
    const float* post_w = (const float*)d_in[9];
    const float* post_b = (const float*)d_in[10];
    const float* pin_w = (const float*)d_in[11];
    const float* pin_b = (const float*)d_in[12];
    const float* blk_ln_s = (const float*)d_in[13];
    const float* blk_ln_b = (const float*)d_in[14];
    const float* blk_w1 = (const float*)d_in[15];
    const float* blk_b1 = (const float*)d_in[16];
    const float* blk_w2 = (const float*)d_in[17];
    const float* blk_b2 = (const float*)d_in[18];
    const float* pout_w = (const float*)d_in[19];
    const float* pout_b = (const float*)d_in[20];
    const float* gene = (const float*)d_in[21];
    float* out = (float*)d_out;

    char* p = (char*)d_ws;
    auto alloc = [&](size_t bytes) {
        char* r = p;
        p += (bytes + 255) & ~(size_t)255;
        return r;
    };
    int* counts = (int*)alloc(NNODES * 4);
    int* incl = (int*)alloc(NNODES * 4);
    int* bsums = (int*)alloc(128 * 4);
    int* boffs = (int*)alloc(128 * 4);
    int* row_start = (int*)alloc(NNODES * 4);
    int* cursor = (int*)alloc(NNODES * 4);
    int2* epack = (int2*)alloc((size_t)NEDGES * 8);
    // 'part': GNN phase scratch = ln_bf + aggbf (bf16)
    float* part = (float*)alloc((size_t)NNODES * GDIM * 4);
    unsigned short* ln_bf = (unsigned short*)part;
    unsigned short* aggbf = (unsigned short*)((char*)part + (size_t)NNODES * GDIM * 2);
    float* xa = (float*)alloc((size_t)NNODES * GDIM * 4);
    float* xb = (float*)alloc((size_t)NNODES * GDIM * 4);
    float* hbuf = (float*)alloc((size_t)BSZ * HID * 4);
    unsigned short* aggselb = (unsigned short*)alloc((size_t)BSZ * GDIM * 2);
    unsigned short* pertinbf = (unsigned short*)alloc((size_t)BSZ * GDIM * 2);
    unsigned short* pertbf = (unsigned short*)alloc((size_t)BSZ * GDIM * 2);
    unsigned short* zlnbf = (unsigned short*)alloc((size_t)BSZ * HID * 2);
    unsigned short* z1bf = (unsigned short*)alloc((size_t)BSZ * INNER * 2);
    unsigned short* hbufbf = (unsigned short*)alloc((size_t)BSZ * HID * 2);
    unsigned short* projb = (unsigned short*)alloc((size_t)BSZ * NCLS * RANK * 2);
    unsigned short* gnnT = (unsigned short*)alloc((size_t)3 * GDIM * GDIM * 2);
    unsigned short* postT = (unsigned short*)alloc((size_t)GDIM * GDIM * 2);
    unsigned short* pinT = (unsigned short*)alloc((size_t)HID * GDIM * 2);
    unsigned short* w1T = (unsigned short*)alloc((size_t)6 * INNER * HID * 2);
    unsigned short* w2T = (unsigned short*)alloc((size_t)6 * HID * INNER * 2);
    unsigned short* poutT = (unsigned short*)alloc((size_t)NCLS * RANK * HID * 2);
    unsigned short* geneb = (unsigned short*)alloc((size_t)NGENES * RANK * 2);
    int* bar = (int*)alloc(1024);   // 8 group counters, 128 B apart

    const int EB = (NEDGES + 255) / 256;
    const int NB = (NNODES + 255) / 256;

    // all weight conversions in one dispatch
    convall_k<<<15100, 256, 0, stream>>>(gnn_w, post_w, pin_w, blk_w1, blk_w2, pout_w, gene,
                                         gnnT, postT, pinT, w1T, w2T, poutT, geneb);

    // CSR build
    (void)hipMemsetAsync(counts, 0, NNODES * 4, stream);
    (void)hipMemsetAsync(bar, 0, 1024, stream);
    hist_k<<<EB, 256, 0, stream>>>(edge_dst, counts, NEDGES);
    scan1_k<<<NB, 256, 0, stream>>>(counts, incl, bsums, NNODES);
    scan2_k<<<1, 128, 0, stream>>>(bsums, boffs, NB);
    scan3_k<<<NB, 256, 0, stream>>>(incl, counts, boffs, row_start, cursor, NNODES);
    scatter_k<<<EB, 256, 0, stream>>>(edge_src, edge_dst, edge_w, cursor, epack, NEDGES);

    // GNN layers 1 & 2 (full), layer 3 (selective)
    const float* x_in = partial_emb;
    float* bufs[2] = {xa, xb};
    for (int i = 0; i < 2; i++) {
        lnb_k<<<(NNODES + 3) / 4, 256, 0, stream>>>(x_in, gnn_ln_s + i * GDIM,
                                                    gnn_ln_b + i * GDIM, ln_bf, NNODES);
        aggb_k<<<(NNODES + 3) / 4, 256, 0, stream>>>(row_start, counts, epack, ln_bf, aggbf,
                                                     NNODES);
        float* x_out = bufs[i];
        mgemm_k<1, true, true><<<dim3(GDIM / 128, (NNODES + 127) / 128), 256, 0, stream>>>(
            aggbf, gnnT + (size_t)i * GDIM * GDIM, gnn_b + i * GDIM, x_in, x_out, NNODES, GDIM,
            GDIM);
        x_in = x_out;
    }
    lnb_k<<<(NNODES + 3) / 4, 256, 0, stream>>>(xb, gnn_ln_s + 2 * GDIM, gnn_ln_b + 2 * GDIM,
                                                ln_bf, NNODES);
    aggsel_k<<<BSZ / 4, 256, 0, stream>>>(node_indices, row_start, counts, epack, ln_bf, aggselb);
    mfull_k<1, 2><<<dim3(GDIM / 64, BSZ / 64), 256, 0, stream>>>(
        aggselb, gnnT + (size_t)2 * GDIM * GDIM, gnn_b + 2 * GDIM, node_indices, xb, pertinbf,
        BSZ, GDIM, GDIM);

    // post_mp + OOV replace (fused)
    mfull_k<0, 1><<<dim3(GDIM / 64, BSZ / 64), 256, 0, stream>>>(
        pertinbf, postT, post_b, node_indices, oov_emb, pertbf, BSZ, GDIM, GDIM);

    // fused head: pin + 6 blocks + pout, 8 independent 32-block groups (13 group syncs each)
    head_k<<<HGRID, 256, 0, stream>>>(pertbf, pinT, pin_b, blk_ln_s, blk_ln_b, w1T, blk_b1, w2T,
                                      blk_b2, poutT, pout_b, hbuf, z1bf, projb, bar);

    // logits
    mgemm_k<0, false, false><<<dim3((NGENES + 127) / 128, (BSZ * NCLS) / 128), 256, 0, stream>>>(
        projb, geneb, nullptr, nullptr, out, BSZ * NCLS, NGENES, RANK);
}

// Round 8
// 526.630 us; speedup vs baseline: 1.9007x; 1.0543x over previous
//
#include <hip/hip_runtime.h>
#include <hip/hip_bf16.h>
#include <math.h>

#define NNODES 20000
#define NEDGES 640000
#define BSZ 256
#define GDIM 256
#define HID 512
#define INNER 2048
#define RANK 512
#define NCLS 3
#define NGENES 6640

typedef __attribute__((ext_vector_type(8))) short bf16x8;
typedef __attribute__((ext_vector_type(4))) float f32x4;
typedef __attribute__((ext_vector_type(4))) unsigned u32x4;   // native vector: legal asm "v" operand

__device__ inline float bf2f(unsigned short u) {
    return __uint_as_float(((unsigned)u) << 16);
}
__device__ inline unsigned short f2bf(float f) {
    unsigned u = __float_as_uint(f);
    u = u + 0x7fff + ((u >> 16) & 1);   // RNE
    return (unsigned short)(u >> 16);
}
__device__ inline unsigned pk2(float a, float b) {
    return (unsigned)f2bf(a) | ((unsigned)f2bf(b) << 16);
}

// ---- device-coherent (cross-XCD) loads/stores: bypass L1/L2, complete at the
// memory-side coherence point. Used ONLY for the head's cross-phase activation
// buffers so the grid barrier needs NO cache maintenance (no buffer_wbl2 /
// buffer_inv -> weights stay L2-hot). Proven: 565 -> 365 -> 199 -> 178 -> 112 us.
__device__ inline u32x4 ld16_cg(const void* p) {
    u32x4 r;
    asm volatile("global_load_dwordx4 %0, %1, off sc0 sc1" : "=v"(r) : "v"(p) : "memory");
    return r;
}
__device__ inline void st4f_cg(void* p, float v) {
    asm volatile("global_store_dword %0, %1, off sc0 sc1" :: "v"(p), "v"(v) : "memory");
}
__device__ inline void st2_cg(void* p, unsigned short v) {
    unsigned w = v;
    asm volatile("global_store_short %0, %1, off sc0 sc1" :: "v"(p), "v"(w) : "memory");
}
__device__ inline void waitvm0(void) {
    asm volatile("s_waitcnt vmcnt(0)" ::: "memory");
    __builtin_amdgcn_sched_barrier(0);
}

// ---------------- CSR build ----------------
__global__ void hist_k(const int* __restrict__ dst, int* __restrict__ counts, int E) {
    int e = blockIdx.x * 256 + threadIdx.x;
    if (e < E) atomicAdd(&counts[dst[e]], 1);
}

__global__ void scan1_k(const int* __restrict__ counts, int* __restrict__ incl,
                        int* __restrict__ bsums, int n) {
    __shared__ int s[256];
    int i = blockIdx.x * 256 + threadIdx.x;
    int v = (i < n) ? counts[i] : 0;
    s[threadIdx.x] = v;
    __syncthreads();
    for (int off = 1; off < 256; off <<= 1) {
        int t = (threadIdx.x >= off) ? s[threadIdx.x - off] : 0;
        __syncthreads();
        s[threadIdx.x] += t;
        __syncthreads();
    }
    if (i < n) incl[i] = s[threadIdx.x];
    if (threadIdx.x == 255) bsums[blockIdx.x] = s[255];
}

__global__ void scan2_k(const int* __restrict__ bsums, int* __restrict__ boffs, int nb) {
    __shared__ int s[128];
    int tid = threadIdx.x;
    int v = (tid < nb) ? bsums[tid] : 0;
    s[tid] = v;
    __syncthreads();
    for (int off = 1; off < 128; off <<= 1) {
        int t = (tid >= off) ? s[tid - off] : 0;
        __syncthreads();
        s[tid] += t;
        __syncthreads();
    }
    if (tid < nb) boffs[tid] = s[tid] - v;
}

__global__ void scan3_k(const int* __restrict__ incl, const int* __restrict__ counts,
                        const int* __restrict__ boffs, int* __restrict__ row_start,
                        int* __restrict__ cursor, int n) {
    int i = blockIdx.x * 256 + threadIdx.x;
    if (i < n) {
        int st = incl[i] - counts[i] + boffs[blockIdx.x];
        row_start[i] = st;
        cursor[i] = st;
    }
}

__global__ void scatter_k(const int* __restrict__ src, const int* __restrict__ dst,
                          const float* __restrict__ w, int* __restrict__ cursor,
                          int2* __restrict__ ep, int E) {
    int e = blockIdx.x * 256 + threadIdx.x;
    if (e < E) {
        int d = dst[e];
        int p = atomicAdd(&cursor[d], 1);
        ep[p] = make_int2(src[e], __float_as_int(w[e]));
    }
}

// mark rows needed by GNN layers 2/3: sel nodes + their in-neighbors.
// (x2/LN(x2) are consumed ONLY at these rows; L1 must stay full since its
// outputs are gather-sources for ~all nodes.)
__global__ void flag_k(const int* __restrict__ idx, const int* __restrict__ row_start,
                       const int* __restrict__ counts, const int2* __restrict__ ep,
                       int* __restrict__ flag) {
    int r4 = blockIdx.x * 4 + (threadIdx.x >> 6);
    int lane = threadIdx.x & 63;
    int id = idx[r4];
    int row = id < 0 ? 0 : id;
    if (lane == 0) flag[row] = 1;
    int beg = row_start[row], cnt = counts[row];
    for (int t = lane; t < cnt; t += 64) flag[ep[beg + t].x] = 1;
}

// ---------------- combined weight conversion ----------------
__global__ void convall_k(const float* __restrict__ gnn_w, const float* __restrict__ post_w,
                          const float* __restrict__ pin_w, const float* __restrict__ blk_w1,
                          const float* __restrict__ blk_w2, const float* __restrict__ pout_w,
                          const float* __restrict__ gene, unsigned short* __restrict__ gnnT,
                          unsigned short* __restrict__ postT, unsigned short* __restrict__ pinT,
                          unsigned short* __restrict__ w1T, unsigned short* __restrict__ w2T,
                          unsigned short* __restrict__ poutT,
                          unsigned short* __restrict__ geneb) {
    int b = blockIdx.x;
    if (b >= 13440) {   // gene: plain fp32 -> bf16 convert, 2048 elems/block
        int t = b - 13440;
        const float4* xp = (const float4*)gene;
        int i = t * 512 + threadIdx.x * 2;    // float4 index
        float4 a = xp[i], c = xp[i + 1];
        *(ushort4*)(geneb + (size_t)i * 4) =
            make_ushort4(f2bf(a.x), f2bf(a.y), f2bf(a.z), f2bf(a.w));
        *(ushort4*)(geneb + (size_t)i * 4 + 4) =
            make_ushort4(f2bf(c.x), f2bf(c.y), f2bf(c.z), f2bf(c.w));
        return;
    }
    const float* W;
    unsigned short* WT;
    int K, N, tile;
    if (b < 192) {
        int l = b >> 6;
        tile = b & 63;
        W = gnn_w + (size_t)l * GDIM * GDIM;
        WT = gnnT + (size_t)l * GDIM * GDIM;
        K = GDIM; N = GDIM;
    } else if (b < 256) {
        tile = b - 192; W = post_w; WT = postT; K = GDIM; N = GDIM;
    } else if (b < 384) {
        tile = b - 256; W = pin_w; WT = pinT; K = GDIM; N = HID;
    } else if (b < 6528) {
        int t = b - 384;
        int l = t >> 10;
        tile = t & 1023;
        W = blk_w1 + (size_t)l * HID * INNER;
        WT = w1T + (size_t)l * INNER * HID;
        K = HID; N = INNER;
    } else if (b < 12672) {
        int t = b - 6528;
        int l = t >> 10;
        tile = t & 1023;
        W = blk_w2 + (size_t)l * INNER * HID;
        WT = w2T + (size_t)l * HID * INNER;
        K = INNER; N = HID;
    } else {
        tile = b - 12672; W = pout_w; WT = poutT; K = HID; N = NCLS * RANK;
    }
    __shared__ float s[32][33];
    int ntx = N >> 5;
    int k0 = (tile / ntx) << 5;
    int n0 = (tile % ntx) << 5;
    int tx = threadIdx.x & 31, ty = threadIdx.x >> 5;
#pragma unroll
    for (int i = 0; i < 4; i++)
        s[ty + 8 * i][tx] = W[(size_t)(k0 + ty + 8 * i) * N + n0 + tx];
    __syncthreads();
#pragma unroll
    for (int i = 0; i < 4; i++)
        WT[(size_t)(n0 + ty + 8 * i) * K + k0 + tx] = f2bf(s[tx][ty + 8 * i]);
}

// ---------------- GNN LayerNorm (D=256), bf16 out; optional row-flag skip ----------------
template <bool FLAGGED>
__global__ void lnb_k(const float* __restrict__ X, const float* __restrict__ sc,
                      const float* __restrict__ bi, unsigned short* __restrict__ Y, int M,
                      const int* __restrict__ flag) {
    int row = blockIdx.x * 4 + (threadIdx.x >> 6);
    int lane = threadIdx.x & 63;
    if (row >= M) return;
    if (FLAGGED && !flag[row]) return;   // wave-uniform skip: stale rows never consumed
    float4 v = ((const float4*)(X + (size_t)row * GDIM))[lane];
    float sum = v.x + v.y + v.z + v.w;
#pragma unroll
    for (int off = 32; off >= 1; off >>= 1) sum += __shfl_xor(sum, off);
    float mu = sum / GDIM;
    float a = v.x - mu, b = v.y - mu, c = v.z - mu, d = v.w - mu;
    float sq = a * a + b * b + c * c + d * d;
#pragma unroll
    for (int off = 32; off >= 1; off >>= 1) sq += __shfl_xor(sq, off);
    float rstd = rsqrtf(sq / GDIM + 1e-5f);
    float4 s4 = ((const float4*)sc)[lane];
    float4 b4 = ((const float4*)bi)[lane];
    *(ushort4*)(Y + (size_t)row * GDIM + lane * 4) =
        make_ushort4(f2bf(a * rstd * s4.x + b4.x), f2bf(b * rstd * s4.y + b4.y),
                     f2bf(c * rstd * s4.z + b4.z), f2bf(d * rstd * s4.w + b4.w));
}

// ---------------- CSR aggregation, 16-deep MLP unroll ----------------
__device__ inline void agg_row(int beg, int cnt, int lane, const int2* __restrict__ ep,
                               const unsigned short* __restrict__ H, float& a0, float& a1,
                               float& a2, float& a3) {
    int t = 0;
    for (; t + 16 <= cnt; t += 16) {
        int2 e[16];
#pragma unroll
        for (int u = 0; u < 16; u++) e[u] = ep[beg + t + u];
        ushort4 v[16];
#pragma unroll
        for (int u = 0; u < 16; u++)
            v[u] = *(const ushort4*)(H + (size_t)e[u].x * GDIM + lane * 4);
#pragma unroll
        for (int u = 0; u < 16; u++) {
            float w = __int_as_float(e[u].y);
            a0 = fmaf(bf2f(v[u].x), w, a0);
            a1 = fmaf(bf2f(v[u].y), w, a1);
            a2 = fmaf(bf2f(v[u].z), w, a2);
            a3 = fmaf(bf2f(v[u].w), w, a3);
        }
    }
    for (; t + 4 <= cnt; t += 4) {
        int2 e[4];
#pragma unroll
        for (int u = 0; u < 4; u++) e[u] = ep[beg + t + u];
        ushort4 v[4];
#pragma unroll
        for (int u = 0; u < 4; u++)
            v[u] = *(const ushort4*)(H + (size_t)e[u].x * GDIM + lane * 4);
#pragma unroll
        for (int u = 0; u < 4; u++) {
            float w = __int_as_float(e[u].y);
            a0 = fmaf(bf2f(v[u].x), w, a0);
            a1 = fmaf(bf2f(v[u].y), w, a1);
            a2 = fmaf(bf2f(v[u].z), w, a2);
            a3 = fmaf(bf2f(v[u].w), w, a3);
        }
    }
    for (; t < cnt; t++) {
        int2 e = ep[beg + t];
        float w = __int_as_float(e.y);
        ushort4 v = *(const ushort4*)(H + (size_t)e.x * GDIM + lane * 4);
        a0 = fmaf(bf2f(v.x), w, a0);
        a1 = fmaf(bf2f(v.y), w, a1);
        a2 = fmaf(bf2f(v.z), w, a2);
        a3 = fmaf(bf2f(v.w), w, a3);
    }
}

template <bool FLAGGED>
__global__ void aggb_k(const int* __restrict__ row_start, const int* __restrict__ counts,
                       const int2* __restrict__ ep, const unsigned short* __restrict__ H,
                       unsigned short* __restrict__ AGG, int n, const int* __restrict__ flag) {
    int row = blockIdx.x * 4 + (threadIdx.x >> 6);
    int lane = threadIdx.x & 63;
    if (row >= n) return;
    if (FLAGGED && !flag[row]) return;   // skip rows whose x2 is never consumed
    float a0 = 0.f, a1 = 0.f, a2 = 0.f, a3 = 0.f;
    agg_row(row_start[row], counts[row], lane, ep, H, a0, a1, a2, a3);
    *(ushort4*)(AGG + (size_t)row * GDIM + lane * 4) =
        make_ushort4(f2bf(a0), f2bf(a1), f2bf(a2), f2bf(a3));
}

__global__ void aggsel_k(const int* __restrict__ idx, const int* __restrict__ row_start,
                         const int* __restrict__ counts, const int2* __restrict__ ep,
                         const unsigned short* __restrict__ H, unsigned short* __restrict__ AGG) {
    int b = blockIdx.x * 4 + (threadIdx.x >> 6);
    int lane = threadIdx.x & 63;
    int id = idx[b];
    int row = id < 0 ? 0 : id;
    float a0 = 0.f, a1 = 0.f, a2 = 0.f, a3 = 0.f;
    agg_row(row_start[row], counts[row], lane, ep, H, a0, a1, a2, a3);
    *(ushort4*)(AGG + (size_t)b * GDIM + lane * 4) =
        make_ushort4(f2bf(a0), f2bf(a1), f2bf(a2), f2bf(a3));
}

// ---------------- bf16 MFMA GEMM (full-K, fp32 out, fused epilogue) — GNN L1/L2 & logits ----------------
template <int ACT, bool RES, bool BIAS>
__global__ __launch_bounds__(256) void mgemm_k(const unsigned short* __restrict__ A,
                                               const unsigned short* __restrict__ BT,
                                               const float* __restrict__ bias,
                                               const float* __restrict__ R,
                                               float* __restrict__ C, int M, int N, int K) {
    __shared__ unsigned short As[128 * 32];
    __shared__ unsigned short Bs[128 * 32];
    int m0 = blockIdx.y * 128, n0 = blockIdx.x * 128;
    int tid = threadIdx.x;
    int wave = tid >> 6, lane = tid & 63;
    int wm = (wave >> 1) * 64, wn = (wave & 1) * 64;
    int lrow = lane & 15, lq = lane >> 4;

    f32x4 acc[4][4];
    const f32x4 zz = {0.f, 0.f, 0.f, 0.f};
#pragma unroll
    for (int i = 0; i < 4; i++)
#pragma unroll
        for (int j = 0; j < 4; j++) acc[i][j] = zz;

    int r0 = tid >> 2;
    int q = tid & 3;

    for (int k0 = 0; k0 < K; k0 += 32) {
#pragma unroll
        for (int p = 0; p < 2; p++) {
            int row = r0 + p * 64;
            int gm = m0 + row;
            uint4 va = make_uint4(0, 0, 0, 0);
            if (gm < M) va = *(const uint4*)(A + (size_t)gm * K + k0 + q * 8);
            *(uint4*)&As[row * 32 + q * 8] = va;
            int gn = n0 + row;
            uint4 vb = make_uint4(0, 0, 0, 0);
            if (gn < N) vb = *(const uint4*)(BT + (size_t)gn * K + k0 + q * 8);
            *(uint4*)&Bs[row * 32 + q * 8] = vb;
        }
        __syncthreads();
        bf16x8 af[4], bf[4];
#pragma unroll
        for (int i = 0; i < 4; i++)
            af[i] = *(const bf16x8*)&As[(wm + i * 16 + lrow) * 32 + lq * 8];
#pragma unroll
        for (int j = 0; j < 4; j++)
            bf[j] = *(const bf16x8*)&Bs[(wn + j * 16 + lrow) * 32 + lq * 8];
#pragma unroll
        for (int i = 0; i < 4; i++)
#pragma unroll
            for (int j = 0; j < 4; j++)
                acc[i][j] =
                    __builtin_amdgcn_mfma_f32_16x16x32_bf16(af[i], bf[j], acc[i][j], 0, 0, 0);
        __syncthreads();
    }

#pragma unroll
    for (int i = 0; i < 4; i++) {
#pragma unroll
        for (int j = 0; j < 4; j++) {
            int gn = n0 + wn + j * 16 + lrow;
            if (gn >= N) continue;
            float bv = BIAS ? bias[gn] : 0.f;
#pragma unroll
            for (int r = 0; r < 4; r++) {
                int gm = m0 + wm + i * 16 + lq * 4 + r;
                if (gm >= M) continue;
                float v = acc[i][j][r] + bv;
                if (ACT == 1) v = fmaxf(v, 0.f);
                if (RES) v += R[(size_t)gm * N + gn];
                C[(size_t)gm * N + gn] = v;
            }
        }
    }
}

// ---------------- bf16 MFMA full-K, bf16 out, fused epilogue (GNN L3 / post) ----------------
template <int ACT, int EPI>
__global__ __launch_bounds__(256) void mfull_k(const unsigned short* __restrict__ A,
                                               const unsigned short* __restrict__ BT,
                                               const float* __restrict__ bias,
                                               const int* __restrict__ idx,
                                               const float* __restrict__ aux,
                                               unsigned short* __restrict__ O, int M, int N,
                                               int K) {
    __shared__ unsigned short As[64 * 32];
    __shared__ unsigned short Bs[64 * 32];
    int m0 = blockIdx.y * 64, n0 = blockIdx.x * 64;
    int tid = threadIdx.x;
    int wave = tid >> 6, lane = tid & 63;
    int wm = wave * 16;
    int lrow = lane & 15, lq = lane >> 4;
    f32x4 acc[4];
    const f32x4 zz = {0.f, 0.f, 0.f, 0.f};
#pragma unroll
    for (int j = 0; j < 4; j++) acc[j] = zz;
    int r0 = tid >> 2;
    int q = tid & 3;
    for (int k0 = 0; k0 < K; k0 += 32) {
        *(uint4*)&As[r0 * 32 + q * 8] = *(const uint4*)(A + (size_t)(m0 + r0) * K + k0 + q * 8);
        *(uint4*)&Bs[r0 * 32 + q * 8] = *(const uint4*)(BT + (size_t)(n0 + r0) * K + k0 + q * 8);
        __syncthreads();
        bf16x8 af = *(const bf16x8*)&As[(wm + lrow) * 32 + lq * 8];
#pragma unroll
        for (int j = 0; j < 4; j++) {
            bf16x8 bfr = *(const bf16x8*)&Bs[(j * 16 + lrow) * 32 + lq * 8];
            acc[j] = __builtin_amdgcn_mfma_f32_16x16x32_bf16(af, bfr, acc[j], 0, 0, 0);
        }
        __syncthreads();
    }
#pragma unroll
    for (int j = 0; j < 4; j++) {
        int gn = n0 + j * 16 + lrow;
        float bv = bias[gn];
#pragma unroll
        for (int r = 0; r < 4; r++) {
            int gm = m0 + wm + lq * 4 + r;
            float v = acc[j][r] + bv;
            if (ACT == 1) v = fmaxf(v, 0.f);
            if (ACT == 2) v = 0.5f * v * (1.f + erff(v * 0.70710678118654752f));
            if (EPI == 2) {
                int id = idx[gm];
                int safe = id < 0 ? 0 : id;
                v += aux[(size_t)safe * N + gn];
            }
            if (EPI == 1) {
                if (idx[gm] < 0) v = aux[gn];
            }
            O[(size_t)gm * N + gn] = f2bf(v);
        }
    }
}

// ================= fused persistent head (v5: row-groups + cross-barrier weight prefetch) ======
// Group g (blocks g*32..g*32+31) owns rows [32g,32g+32); per-group barriers (proven
// 178 -> 112 us). NEW: each phase's weight slice is statically known, so the NEXT
// phase's weights are issued into registers BEFORE gsync — their latency completes
// during barrier skew; post-barrier path has only the small activation load.

#define HGRID 256
#define LDPA 520   // ushort row stride for K<=512 tiles: 1040B -> bank-optimal b128 reads
#define GBLK 32    // blocks per group

__device__ inline void gsync(int* bar, int target) {
    waitvm0();   // drain cg-stores/atomics AND in-flight weight prefetch (regs then valid)
    __syncthreads();
    if (threadIdx.x == 0) {
        __hip_atomic_fetch_add(bar, 1, __ATOMIC_RELAXED, __HIP_MEMORY_SCOPE_AGENT);
        while (__hip_atomic_load(bar, __ATOMIC_RELAXED, __HIP_MEMORY_SCOPE_AGENT) < target)
            __builtin_amdgcn_s_sleep(2);
    }
    __syncthreads();
}

// issue ROWSxKC bf16 tile loads (all outstanding), NL = ROWS*KC/2048 regs/thread
template <int ROWS, int KC, bool CG>
__device__ inline void stage_issue(const unsigned short* src, int ld, u32x4* regs) {
    constexpr int NL = ROWS * KC / 8 / 256;
    int tid = threadIdx.x;
#pragma unroll
    for (int it = 0; it < NL; it++) {
        int unit = it * 256 + tid;
        int row = unit / (KC / 8);
        int ucol = unit % (KC / 8);
        const unsigned short* p = src + (size_t)row * ld + ucol * 8;
        if (CG) regs[it] = ld16_cg(p);
        else regs[it] = *(const u32x4*)p;
    }
}
template <int ROWS, int KC>
__device__ inline void stage_write(unsigned short* dst, const u32x4* regs) {
    constexpr int NL = ROWS * KC / 8 / 256;
    int tid = threadIdx.x;
#pragma unroll
    for (int it = 0; it < NL; it++) {
        int unit = it * 256 + tid;
        int row = unit / (KC / 8);
        int ucol = unit % (KC / 8);
        *(u32x4*)&dst[row * LDPA + ucol * 8] = regs[it];
    }
}

// uninterrupted MFMA stream over the fully-staged tile (no inner barriers)
template <int KC>
__device__ inline void mma_all(const unsigned short* As, const unsigned short* Bs, f32x4 acc[2]) {
    int tid = threadIdx.x, wave = tid >> 6, lane = tid & 63;
    int wm = (wave >> 1) * 16, wn = (wave & 1) * 32;
    int lrow = lane & 15, lq = lane >> 4;
#pragma unroll
    for (int kk = 0; kk < KC / 32; kk++) {
        bf16x8 af = *(const bf16x8*)&As[(wm + lrow) * LDPA + kk * 32 + lq * 8];
#pragma unroll
        for (int j = 0; j < 2; j++) {
            bf16x8 bfr = *(const bf16x8*)&Bs[(wn + j * 16 + lrow) * LDPA + kk * 32 + lq * 8];
            acc[j] = __builtin_amdgcn_mfma_f32_16x16x32_bf16(af, bfr, acc[j], 0, 0, 0);
        }
    }
}

__global__ __launch_bounds__(256) void head_k(
    const unsigned short* __restrict__ pertbf, const unsigned short* __restrict__ pinT,
    const float* __restrict__ pin_b, const float* __restrict__ blk_ln_s,
    const float* __restrict__ blk_ln_b, const unsigned short* __restrict__ w1T,
    const float* __restrict__ blk_b1, const unsigned short* __restrict__ w2T,
    const float* __restrict__ blk_b2, const unsigned short* __restrict__ poutT,
    const float* __restrict__ pout_b, float* __restrict__ hbuf,
    unsigned short* __restrict__ z1bf, unsigned short* __restrict__ projb,
    int* __restrict__ bar) {
    __shared__ unsigned short As[32 * LDPA];   // 33.3 KB
    __shared__ unsigned short Bs[64 * LDPA];   // 66.6 KB
    int b = blockIdx.x;
    int g = b >> 5;          // row-group 0..7: rows [g*32, g*32+32)
    int t = b & 31;          // rank within group; b%8 == t%8 -> XCD locality by n-slice
    int* gbar = bar + g * 32;   // per-group counter, 128 B apart
    int m0 = g * 32;
    int tid = threadIdx.x;
    int wave = tid >> 6, lane = tid & 63;
    int wm = (wave >> 1) * 16, wn = (wave & 1) * 32;
    int lrow = lane & 15, lq = lane >> 4;
    int ph = 0;
    f32x4 acc[2];
    const f32x4 zz = {0.f, 0.f, 0.f, 0.f};
    u32x4 pf[16];   // weight prefetch registers, live across gsync (1 block/CU: VGPR free)

    // ---- P0: h[g-rows] = pertbf @ pinT + pin_b  (8 active blocks/group, full K=256)
    if (t < 8) {
        int n0 = t * 64;
        u32x4 wreg[8], areg[4];
        stage_issue<64, 256, false>(pinT + (size_t)n0 * GDIM, GDIM, wreg);
        stage_issue<32, 256, false>(pertbf + (size_t)m0 * GDIM, GDIM, areg);
        waitvm0();
        stage_write<64, 256>(Bs, wreg);
        stage_write<32, 256>(As, areg);
        __syncthreads();
        acc[0] = zz; acc[1] = zz;
        mma_all<256>(As, Bs, acc);
#pragma unroll
        for (int j = 0; j < 2; j++) {
            int gn = n0 + wn + j * 16 + lrow;
            float bv = pin_b[gn];
#pragma unroll
            for (int r = 0; r < 4; r++) {
                int gm = m0 + wm + lq * 4 + r;
                st4f_cg(hbuf + (size_t)gm * HID + gn, acc[j][r] + bv);
            }
        }
    }
    // prefetch layer-0 w1 slice (ALL blocks) — completes during barrier skew
    stage_issue<64, 512, false>(w1T + (size_t)t * 64 * HID, HID, pf);
    gsync(gbar, ++ph * GBLK);

    for (int i = 0; i < 6; i++) {
        {   // A: z1[g-rows] = gelu(LN_i(h) @ w1 + b1); 32 blocks x 64-col slices, K=512
            int n0 = t * 64;
            u32x4 hreg[16];
            // issue h loads first, then drain prefetched weights into LDS under their latency
#pragma unroll
            for (int rr = 0; rr < 8; rr++) {
                const float* p = hbuf + (size_t)(m0 + wave * 8 + rr) * HID + lane * 8;
                hreg[2 * rr] = ld16_cg(p);
                hreg[2 * rr + 1] = ld16_cg(p + 4);
            }
            stage_write<64, 512>(Bs, pf);   // pf valid: drained by gsync's waitvm0
            waitvm0();
            // inline LayerNorm (redundant across the 32 n-slices, cheap) -> bf16 As
            const float* ls = blk_ln_s + (size_t)i * HID;
            const float* lb = blk_ln_b + (size_t)i * HID;
            float4 s0 = ((const float4*)ls)[lane * 2], s1 = ((const float4*)ls)[lane * 2 + 1];
            float4 t0 = ((const float4*)lb)[lane * 2], t1 = ((const float4*)lb)[lane * 2 + 1];
#pragma unroll
            for (int rr = 0; rr < 8; rr++) {
                float f0 = __uint_as_float(hreg[2 * rr][0]);
                float f1 = __uint_as_float(hreg[2 * rr][1]);
                float f2 = __uint_as_float(hreg[2 * rr][2]);
                float f3 = __uint_as_float(hreg[2 * rr][3]);
                float f4 = __uint_as_float(hreg[2 * rr + 1][0]);
                float f5 = __uint_as_float(hreg[2 * rr + 1][1]);
                float f6 = __uint_as_float(hreg[2 * rr + 1][2]);
                float f7 = __uint_as_float(hreg[2 * rr + 1][3]);
                float sum = f0 + f1 + f2 + f3 + f4 + f5 + f6 + f7;
#pragma unroll
                for (int off = 32; off >= 1; off >>= 1) sum += __shfl_xor(sum, off);
                float mu = sum * (1.f / HID);
                float d0 = f0 - mu, d1 = f1 - mu, d2 = f2 - mu, d3 = f3 - mu;
                float d4 = f4 - mu, d5 = f5 - mu, d6 = f6 - mu, d7 = f7 - mu;
                float sq = d0 * d0 + d1 * d1 + d2 * d2 + d3 * d3 + d4 * d4 + d5 * d5 +
                           d6 * d6 + d7 * d7;
#pragma unroll
                for (int off = 32; off >= 1; off >>= 1) sq += __shfl_xor(sq, off);
                float rstd = rsqrtf(sq * (1.f / HID) + 1e-5f);
                u32x4 pk;
                pk[0] = pk2(d0 * rstd * s0.x + t0.x, d1 * rstd * s0.y + t0.y);
                pk[1] = pk2(d2 * rstd * s0.z + t0.z, d3 * rstd * s0.w + t0.w);
                pk[2] = pk2(d4 * rstd * s1.x + t1.x, d5 * rstd * s1.y + t1.y);
                pk[3] = pk2(d6 * rstd * s1.z + t1.z, d7 * rstd * s1.w + t1.w);
                *(u32x4*)&As[(wave * 8 + rr) * LDPA + lane * 8] = pk;
            }
            __syncthreads();
            acc[0] = zz; acc[1] = zz;
            mma_all<512>(As, Bs, acc);
#pragma unroll
            for (int j = 0; j < 2; j++) {
                int gn = n0 + wn + j * 16 + lrow;
                float bv = blk_b1[(size_t)i * INNER + gn];
#pragma unroll
                for (int r = 0; r < 4; r++) {
                    int gm = m0 + wm + lq * 4 + r;
                    float v = acc[j][r] + bv;
                    v = 0.5f * v * (1.f + erff(v * 0.70710678118654752f));
                    st2_cg(z1bf + (size_t)gm * INNER + gn, f2bf(v));
                }
            }
            // prefetch my B-phase w2 slice
            stage_issue<64, 512, false>(
                w2T + (size_t)i * HID * INNER + (size_t)(t & 7) * 64 * INNER + (t >> 3) * 512,
                INNER, pf);
        }
        gsync(gbar, ++ph * GBLK);
        {   // B: h[g-rows] += z1 @ w2 K-chunk (+b2 once via s==0); 8n x 4s per group
            int s = t >> 3, n0 = (t & 7) * 64, kbeg = s * 512;
            u32x4 areg[8];
            stage_issue<32, 512, true>(z1bf + (size_t)m0 * INNER + kbeg, INNER, areg);
            stage_write<64, 512>(Bs, pf);
            waitvm0();
            stage_write<32, 512>(As, areg);
            __syncthreads();
            acc[0] = zz; acc[1] = zz;
            mma_all<512>(As, Bs, acc);
#pragma unroll
            for (int j = 0; j < 2; j++) {
                int gn = n0 + wn + j * 16 + lrow;
                float bv = (s == 0) ? blk_b2[(size_t)i * HID + gn] : 0.f;
#pragma unroll
                for (int r = 0; r < 4; r++) {
                    int gm = m0 + wm + lq * 4 + r;
                    __hip_atomic_fetch_add(hbuf + (size_t)gm * HID + gn, acc[j][r] + bv,
                                           __ATOMIC_RELAXED, __HIP_MEMORY_SCOPE_AGENT);
                }
            }
            // prefetch next A-phase w1 (or pout slice after the last layer)
            if (i < 5)
                stage_issue<64, 512, false>(
                    w1T + (size_t)(i + 1) * INNER * HID + (size_t)t * 64 * HID, HID, pf);
            else if (t < 24)
                stage_issue<64, 512, false>(poutT + (size_t)t * 64 * HID, HID, pf);
        }
        gsync(gbar, ++ph * GBLK);
    }

    // ---- pout: projb[g-rows] = h @ poutT + pout_b  (24 active blocks/group, K=512)
    if (t < 24) {
        int n0 = t * 64;
        u32x4 areg[16];
#pragma unroll
        for (int it = 0; it < 16; it++) {
            int unit = it * 256 + tid;
            int row = unit >> 7, ucol = unit & 127;   // 128 units of 4 f32 per row
            areg[it] = ld16_cg(hbuf + (size_t)(m0 + row) * HID + ucol * 4);
        }
        stage_write<64, 512>(Bs, pf);
        waitvm0();
#pragma unroll
        for (int it = 0; it < 16; it++) {
            int unit = it * 256 + tid;
            int row = unit >> 7, ucol = unit & 127;
            float a = __uint_as_float(areg[it][0]), c = __uint_as_float(areg[it][1]);
            float d = __uint_as_float(areg[it][2]), e = __uint_as_float(areg[it][3]);
            uint2 w2v;
            w2v.x = pk2(a, c);
            w2v.y = pk2(d, e);
            *(uint2*)&As[row * LDPA + ucol * 4] = w2v;
        }
        __syncthreads();
        acc[0] = zz; acc[1] = zz;
        mma_all<512>(As, Bs, acc);
#pragma unroll
        for (int j = 0; j < 2; j++) {
            int gn = n0 + wn + j * 16 + lrow;
            float bv = pout_b[gn];
#pragma unroll
            for (int r = 0; r < 4; r++) {
                int gm = m0 + wm + lq * 4 + r;
                projb[(size_t)gm * (NCLS * RANK) + gn] = f2bf(acc[j][r] + bv);
            }
        }
    }
}

// ---------------- launch ----------------
extern "C" void kernel_launch(void* const* d_in, const int* in_sizes, int n_in,
                              void* d_out, int out_size, void* d_ws, size_t ws_size,
                              hipStream_t stream) {
    const int* node_indices = (const int*)d_in[0];
    const int* edge_src = (const int*)d_in[1];
    const int* edge_dst = edge_src + NEDGES;
    const float* edge_w = (const float*)d_in[2];
    const float* partial_emb = (const float*)d_in[3];
    const float* oov_emb = (const float*)d_in[4];
    const float* gnn_ln_s = (const float*)d_in[5];
    const float* gnn_ln_b = (const float*)d_in[6];
    const float* gnn_w = (const float*)d_in[7];
    const float* gnn_b = (const float*)d_in[8];
    const float* post_w = (const float*)d_in[9];
    const float* post_b = (const float*)d_in[10];
    const float* pin_w = (const float*)d_in[11];
    const float* pin_b = (const float*)d_in[12];
    const float* blk_ln_s = (const float*)d_in[13];
    const float* blk_ln_b = (const float*)d_in[14];
    const float* blk_w1 = (const float*)d_in[15];
    const float* blk_b1 = (const float*)d_in[16];
    const float* blk_w2 = (const float*)d_in[17];
    const float* blk_b2 = (const float*)d_in[18];
    const float* pout_w = (const float*)d_in[19];
    const float* pout_b = (const float*)d_in[20];
    const float* gene = (const float*)d_in[21];
    float* out = (float*)d_out;

    char* p = (char*)d_ws;
    auto alloc = [&](size_t bytes) {
        char* r = p;
        p += (bytes + 255) & ~(size_t)255;
        return r;
    };
    int* counts = (int*)alloc(NNODES * 4);
    int* incl = (int*)alloc(NNODES * 4);
    int* bsums = (int*)alloc(128 * 4);
    int* boffs = (int*)alloc(128 * 4);
    int* row_start = (int*)alloc(NNODES * 4);
    int* cursor = (int*)alloc(NNODES * 4);
    int* flag = (int*)alloc(NNODES * 4);
    int2* epack = (int2*)alloc((size_t)NEDGES * 8);
    // 'part': GNN phase scratch = ln_bf + aggbf (bf16)
    float* part = (float*)alloc((size_t)NNODES * GDIM * 4);
    unsigned short* ln_bf = (unsigned short*)part;
    unsigned short* aggbf = (unsigned short*)((char*)part + (size_t)NNODES * GDIM * 2);
    float* xa = (float*)alloc((size_t)NNODES * GDIM * 4);
    float* xb = (float*)alloc((size_t)NNODES * GDIM * 4);
    float* hbuf = (float*)alloc((size_t)BSZ * HID * 4);
    unsigned short* aggselb = (unsigned short*)alloc((size_t)BSZ * GDIM * 2);
    unsigned short* pertinbf = (unsigned short*)alloc((size_t)BSZ * GDIM * 2);
    unsigned short* pertbf = (unsigned short*)alloc((size_t)BSZ * GDIM * 2);
    unsigned short* z1bf = (unsigned short*)alloc((size_t)BSZ * INNER * 2);
    unsigned short* projb = (unsigned short*)alloc((size_t)BSZ * NCLS * RANK * 2);
    unsigned short* gnnT = (unsigned short*)alloc((size_t)3 * GDIM * GDIM * 2);
    unsigned short* postT = (unsigned short*)alloc((size_t)GDIM * GDIM * 2);
    unsigned short* pinT = (unsigned short*)alloc((size_t)HID * GDIM * 2);
    unsigned short* w1T = (unsigned short*)alloc((size_t)6 * INNER * HID * 2);
    unsigned short* w2T = (unsigned short*)alloc((size_t)6 * HID * INNER * 2);
    unsigned short* poutT = (unsigned short*)alloc((size_t)NCLS * RANK * HID * 2);
    unsigned short* geneb = (unsigned short*)alloc((size_t)NGENES * RANK * 2);
    int* bar = (int*)alloc(1024);   // 8 group counters, 128 B apart

    const int EB = (NEDGES + 255) / 256;
    const int NB = (NNODES + 255) / 256;

    // all weight conversions in one dispatch
    convall_k<<<15100, 256, 0, stream>>>(gnn_w, post_w, pin_w, blk_w1, blk_w2, pout_w, gene,
                                         gnnT, postT, pinT, w1T, w2T, poutT, geneb);

    // CSR build
    (void)hipMemsetAsync(counts, 0, NNODES * 4, stream);
    (void)hipMemsetAsync(flag, 0, NNODES * 4, stream);
    (void)hipMemsetAsync(bar, 0, 1024, stream);
    hist_k<<<EB, 256, 0, stream>>>(edge_dst, counts, NEDGES);
    scan1_k<<<NB, 256, 0, stream>>>(counts, incl, bsums, NNODES);
    scan2_k<<<1, 128, 0, stream>>>(bsums, boffs, NB);
    scan3_k<<<NB, 256, 0, stream>>>(incl, counts, boffs, row_start, cursor, NNODES);
    scatter_k<<<EB, 256, 0, stream>>>(edge_src, edge_dst, edge_w, cursor, epack, NEDGES);
    // rows needed by layers 2/3: selected nodes + their in-neighbors (~41% of rows)
    flag_k<<<BSZ / 4, 256, 0, stream>>>(node_indices, row_start, counts, epack, flag);

    // GNN layer 1 (full) and layer 2 (flagged rows only)
    const float* x_in = partial_emb;
    float* bufs[2] = {xa, xb};
    for (int i = 0; i < 2; i++) {
        lnb_k<false><<<(NNODES + 3) / 4, 256, 0, stream>>>(
            x_in, gnn_ln_s + i * GDIM, gnn_ln_b + i * GDIM, ln_bf, NNODES, nullptr);
        if (i == 0)
            aggb_k<false><<<(NNODES + 3) / 4, 256, 0, stream>>>(row_start, counts, epack, ln_bf,
                                                                aggbf, NNODES, nullptr);
        else
            aggb_k<true><<<(NNODES + 3) / 4, 256, 0, stream>>>(row_start, counts, epack, ln_bf,
                                                               aggbf, NNODES, flag);
        float* x_out = bufs[i];
        mgemm_k<1, true, true><<<dim3(GDIM / 128, (NNODES + 127) / 128), 256, 0, stream>>>(
            aggbf, gnnT + (size_t)i * GDIM * GDIM, gnn_b + i * GDIM, x_in, x_out, NNODES, GDIM,
            GDIM);
        x_in = x_out;
    }
    // layer 3: LN only at flagged rows (sources of selected rows' edges)
    lnb_k<true><<<(NNODES + 3) / 4, 256, 0, stream>>>(xb, gnn_ln_s + 2 * GDIM,
                                                      gnn_ln_b + 2 * GDIM, ln_bf, NNODES, flag);
    aggsel_k<<<BSZ / 4, 256, 0, stream>>>(node_indices, row_start, counts, epack, ln_bf, aggselb);
    mfull_k<1, 2><<<dim3(GDIM / 64, BSZ / 64), 256, 0, stream>>>(
        aggselb, gnnT + (size_t)2 * GDIM * GDIM, gnn_b + 2 * GDIM, node_indices, xb, pertinbf,
        BSZ, GDIM, GDIM);

    // post_mp + OOV replace (fused)
    mfull_k<0, 1><<<dim3(GDIM / 64, BSZ / 64), 256, 0, stream>>>(
        pertinbf, postT, post_b, node_indices, oov_emb, pertbf, BSZ, GDIM, GDIM);

    // fused head: pin + 6 blocks + pout, 8 independent 32-block groups + weight prefetch
    head_k<<<HGRID, 256, 0, stream>>>(pertbf, pinT, pin_b, blk_ln_s, blk_ln_b, w1T, blk_b1, w2T,
                                      blk_b2, poutT, pout_b, hbuf, z1bf, projb, bar);

    // logits
    mgemm_k<0, false, false><<<dim3((NGENES + 127) / 128, (BSZ * NCLS) / 128), 256, 0, stream>>>(
        projb, geneb, nullptr, nullptr, out, BSZ * NCLS, NGENES, RANK);
}

// Round 9
// 514.828 us; speedup vs baseline: 1.9443x; 1.0229x over previous
//
#include <hip/hip_runtime.h>
#include <hip/hip_bf16.h>
#include <math.h>

#define NNODES 20000
#define NEDGES 640000
#define BSZ 256
#define GDIM 256
#define HID 512
#define INNER 2048
#define RANK 512
#define NCLS 3
#define NGENES 6640

typedef __attribute__((ext_vector_type(8))) short bf16x8;
typedef __attribute__((ext_vector_type(4))) float f32x4;
typedef __attribute__((ext_vector_type(4))) unsigned u32x4;   // native vector: legal asm "v" operand

__device__ inline float bf2f(unsigned short u) {
    return __uint_as_float(((unsigned)u) << 16);
}
__device__ inline unsigned short f2bf(float f) {
    unsigned u = __float_as_uint(f);
    u = u + 0x7fff + ((u >> 16) & 1);   // RNE
    return (unsigned short)(u >> 16);
}
__device__ inline unsigned pk2(float a, float b) {
    return (unsigned)f2bf(a) | ((unsigned)f2bf(b) << 16);
}

// ---- device-coherent (cross-XCD) loads/stores: bypass L1/L2, complete at the
// memory-side coherence point. Used ONLY for the head's cross-phase activation
// buffers so the grid barrier needs NO cache maintenance (no buffer_wbl2 /
// buffer_inv -> weights stay L2-hot). Proven: 565 -> 365 -> 199 -> 178 -> 112 us.
__device__ inline u32x4 ld16_cg(const void* p) {
    u32x4 r;
    asm volatile("global_load_dwordx4 %0, %1, off sc0 sc1" : "=v"(r) : "v"(p) : "memory");
    return r;
}
__device__ inline void st4f_cg(void* p, float v) {
    asm volatile("global_store_dword %0, %1, off sc0 sc1" :: "v"(p), "v"(v) : "memory");
}
__device__ inline void st2_cg(void* p, unsigned short v) {
    unsigned w = v;
    asm volatile("global_store_short %0, %1, off sc0 sc1" :: "v"(p), "v"(w) : "memory");
}
__device__ inline void waitvm0(void) {
    asm volatile("s_waitcnt vmcnt(0)" ::: "memory");
    __builtin_amdgcn_sched_barrier(0);
}

// ---------------- CSR build ----------------
__global__ void hist_k(const int* __restrict__ dst, int* __restrict__ counts, int E) {
    int e = blockIdx.x * 256 + threadIdx.x;
    if (e < E) atomicAdd(&counts[dst[e]], 1);
}

__global__ void scan1_k(const int* __restrict__ counts, int* __restrict__ incl,
                        int* __restrict__ bsums, int n) {
    __shared__ int s[256];
    int i = blockIdx.x * 256 + threadIdx.x;
    int v = (i < n) ? counts[i] : 0;
    s[threadIdx.x] = v;
    __syncthreads();
    for (int off = 1; off < 256; off <<= 1) {
        int t = (threadIdx.x >= off) ? s[threadIdx.x - off] : 0;
        __syncthreads();
        s[threadIdx.x] += t;
        __syncthreads();
    }
    if (i < n) incl[i] = s[threadIdx.x];
    if (threadIdx.x == 255) bsums[blockIdx.x] = s[255];
}

__global__ void scan2_k(const int* __restrict__ bsums, int* __restrict__ boffs, int nb) {
    __shared__ int s[128];
    int tid = threadIdx.x;
    int v = (tid < nb) ? bsums[tid] : 0;
    s[tid] = v;
    __syncthreads();
    for (int off = 1; off < 128; off <<= 1) {
        int t = (tid >= off) ? s[tid - off] : 0;
        __syncthreads();
        s[tid] += t;
        __syncthreads();
    }
    if (tid < nb) boffs[tid] = s[tid] - v;
}

__global__ void scan3_k(const int* __restrict__ incl, const int* __restrict__ counts,
                        const int* __restrict__ boffs, int* __restrict__ row_start,
                        int* __restrict__ cursor, int n) {
    int i = blockIdx.x * 256 + threadIdx.x;
    if (i < n) {
        int st = incl[i] - counts[i] + boffs[blockIdx.x];
        row_start[i] = st;
        cursor[i] = st;
    }
}

__global__ void scatter_k(const int* __restrict__ src, const int* __restrict__ dst,
                          const float* __restrict__ w, int* __restrict__ cursor,
                          int2* __restrict__ ep, int E) {
    int e = blockIdx.x * 256 + threadIdx.x;
    if (e < E) {
        int d = dst[e];
        int p = atomicAdd(&cursor[d], 1);
        ep[p] = make_int2(src[e], __float_as_int(w[e]));
    }
}

// mark rows needed by GNN layers 2/3: sel nodes + their in-neighbors.
__global__ void flag_k(const int* __restrict__ idx, const int* __restrict__ row_start,
                       const int* __restrict__ counts, const int2* __restrict__ ep,
                       int* __restrict__ flag) {
    int r4 = blockIdx.x * 4 + (threadIdx.x >> 6);
    int lane = threadIdx.x & 63;
    int id = idx[r4];
    int row = id < 0 ? 0 : id;
    if (lane == 0) flag[row] = 1;
    int beg = row_start[row], cnt = counts[row];
    for (int t = lane; t < cnt; t += 64) flag[ep[beg + t].x] = 1;
}

// ---------------- combined weight conversion ----------------
__global__ void convall_k(const float* __restrict__ gnn_w, const float* __restrict__ post_w,
                          const float* __restrict__ pin_w, const float* __restrict__ blk_w1,
                          const float* __restrict__ blk_w2, const float* __restrict__ pout_w,
                          const float* __restrict__ gene, unsigned short* __restrict__ gnnT,
                          unsigned short* __restrict__ postT, unsigned short* __restrict__ pinT,
                          unsigned short* __restrict__ w1T, unsigned short* __restrict__ w2T,
                          unsigned short* __restrict__ poutT,
                          unsigned short* __restrict__ geneb) {
    int b = blockIdx.x;
    if (b >= 13440) {   // gene: plain fp32 -> bf16 convert, 2048 elems/block
        int t = b - 13440;
        const float4* xp = (const float4*)gene;
        int i = t * 512 + threadIdx.x * 2;    // float4 index
        float4 a = xp[i], c = xp[i + 1];
        *(ushort4*)(geneb + (size_t)i * 4) =
            make_ushort4(f2bf(a.x), f2bf(a.y), f2bf(a.z), f2bf(a.w));
        *(ushort4*)(geneb + (size_t)i * 4 + 4) =
            make_ushort4(f2bf(c.x), f2bf(c.y), f2bf(c.z), f2bf(c.w));
        return;
    }
    const float* W;
    unsigned short* WT;
    int K, N, tile;
    if (b < 192) {
        int l = b >> 6;
        tile = b & 63;
        W = gnn_w + (size_t)l * GDIM * GDIM;
        WT = gnnT + (size_t)l * GDIM * GDIM;
        K = GDIM; N = GDIM;
    } else if (b < 256) {
        tile = b - 192; W = post_w; WT = postT; K = GDIM; N = GDIM;
    } else if (b < 384) {
        tile = b - 256; W = pin_w; WT = pinT; K = GDIM; N = HID;
    } else if (b < 6528) {
        int t = b - 384;
        int l = t >> 10;
        tile = t & 1023;
        W = blk_w1 + (size_t)l * HID * INNER;
        WT = w1T + (size_t)l * INNER * HID;
        K = HID; N = INNER;
    } else if (b < 12672) {
        int t = b - 6528;
        int l = t >> 10;
        tile = t & 1023;
        W = blk_w2 + (size_t)l * INNER * HID;
        WT = w2T + (size_t)l * HID * INNER;
        K = INNER; N = HID;
    } else {
        tile = b - 12672; W = pout_w; WT = poutT; K = HID; N = NCLS * RANK;
    }
    __shared__ float s[32][33];
    int ntx = N >> 5;
    int k0 = (tile / ntx) << 5;
    int n0 = (tile % ntx) << 5;
    int tx = threadIdx.x & 31, ty = threadIdx.x >> 5;
#pragma unroll
    for (int i = 0; i < 4; i++)
        s[ty + 8 * i][tx] = W[(size_t)(k0 + ty + 8 * i) * N + n0 + tx];
    __syncthreads();
#pragma unroll
    for (int i = 0; i < 4; i++)
        WT[(size_t)(n0 + ty + 8 * i) * K + k0 + tx] = f2bf(s[tx][ty + 8 * i]);
}

// ---------------- GNN LayerNorm (D=256), bf16 out; optional row-flag skip ----------------
template <bool FLAGGED>
__global__ void lnb_k(const float* __restrict__ X, const float* __restrict__ sc,
                      const float* __restrict__ bi, unsigned short* __restrict__ Y, int M,
                      const int* __restrict__ flag) {
    int row = blockIdx.x * 4 + (threadIdx.x >> 6);
    int lane = threadIdx.x & 63;
    if (row >= M) return;
    if (FLAGGED && !flag[row]) return;   // wave-uniform skip: stale rows never consumed
    float4 v = ((const float4*)(X + (size_t)row * GDIM))[lane];
    float sum = v.x + v.y + v.z + v.w;
#pragma unroll
    for (int off = 32; off >= 1; off >>= 1) sum += __shfl_xor(sum, off);
    float mu = sum / GDIM;
    float a = v.x - mu, b = v.y - mu, c = v.z - mu, d = v.w - mu;
    float sq = a * a + b * b + c * c + d * d;
#pragma unroll
    for (int off = 32; off >= 1; off >>= 1) sq += __shfl_xor(sq, off);
    float rstd = rsqrtf(sq / GDIM + 1e-5f);
    float4 s4 = ((const float4*)sc)[lane];
    float4 b4 = ((const float4*)bi)[lane];
    *(ushort4*)(Y + (size_t)row * GDIM + lane * 4) =
        make_ushort4(f2bf(a * rstd * s4.x + b4.x), f2bf(b * rstd * s4.y + b4.y),
                     f2bf(c * rstd * s4.z + b4.z), f2bf(d * rstd * s4.w + b4.w));
}

// ---------------- CSR aggregation, 16-deep MLP unroll ----------------
__device__ inline void agg_row(int beg, int cnt, int lane, const int2* __restrict__ ep,
                               const unsigned short* __restrict__ H, float& a0, float& a1,
                               float& a2, float& a3) {
    int t = 0;
    for (; t + 16 <= cnt; t += 16) {
        int2 e[16];
#pragma unroll
        for (int u = 0; u < 16; u++) e[u] = ep[beg + t + u];
        ushort4 v[16];
#pragma unroll
        for (int u = 0; u < 16; u++)
            v[u] = *(const ushort4*)(H + (size_t)e[u].x * GDIM + lane * 4);
#pragma unroll
        for (int u = 0; u < 16; u++) {
            float w = __int_as_float(e[u].y);
            a0 = fmaf(bf2f(v[u].x), w, a0);
            a1 = fmaf(bf2f(v[u].y), w, a1);
            a2 = fmaf(bf2f(v[u].z), w, a2);
            a3 = fmaf(bf2f(v[u].w), w, a3);
        }
    }
    for (; t + 4 <= cnt; t += 4) {
        int2 e[4];
#pragma unroll
        for (int u = 0; u < 4; u++) e[u] = ep[beg + t + u];
        ushort4 v[4];
#pragma unroll
        for (int u = 0; u < 4; u++)
            v[u] = *(const ushort4*)(H + (size_t)e[u].x * GDIM + lane * 4);
#pragma unroll
        for (int u = 0; u < 4; u++) {
            float w = __int_as_float(e[u].y);
            a0 = fmaf(bf2f(v[u].x), w, a0);
            a1 = fmaf(bf2f(v[u].y), w, a1);
            a2 = fmaf(bf2f(v[u].z), w, a2);
            a3 = fmaf(bf2f(v[u].w), w, a3);
        }
    }
    for (; t < cnt; t++) {
        int2 e = ep[beg + t];
        float w = __int_as_float(e.y);
        ushort4 v = *(const ushort4*)(H + (size_t)e.x * GDIM + lane * 4);
        a0 = fmaf(bf2f(v.x), w, a0);
        a1 = fmaf(bf2f(v.y), w, a1);
        a2 = fmaf(bf2f(v.z), w, a2);
        a3 = fmaf(bf2f(v.w), w, a3);
    }
}

template <bool FLAGGED>
__global__ void aggb_k(const int* __restrict__ row_start, const int* __restrict__ counts,
                       const int2* __restrict__ ep, const unsigned short* __restrict__ H,
                       unsigned short* __restrict__ AGG, int n, const int* __restrict__ flag) {
    int row = blockIdx.x * 4 + (threadIdx.x >> 6);
    int lane = threadIdx.x & 63;
    if (row >= n) return;
    if (FLAGGED && !flag[row]) return;   // skip rows whose x2 is never consumed
    float a0 = 0.f, a1 = 0.f, a2 = 0.f, a3 = 0.f;
    agg_row(row_start[row], counts[row], lane, ep, H, a0, a1, a2, a3);
    *(ushort4*)(AGG + (size_t)row * GDIM + lane * 4) =
        make_ushort4(f2bf(a0), f2bf(a1), f2bf(a2), f2bf(a3));
}

__global__ void aggsel_k(const int* __restrict__ idx, const int* __restrict__ row_start,
                         const int* __restrict__ counts, const int2* __restrict__ ep,
                         const unsigned short* __restrict__ H, unsigned short* __restrict__ AGG) {
    int b = blockIdx.x * 4 + (threadIdx.x >> 6);
    int lane = threadIdx.x & 63;
    int id = idx[b];
    int row = id < 0 ? 0 : id;
    float a0 = 0.f, a1 = 0.f, a2 = 0.f, a3 = 0.f;
    agg_row(row_start[row], counts[row], lane, ep, H, a0, a1, a2, a3);
    *(ushort4*)(AGG + (size_t)b * GDIM + lane * 4) =
        make_ushort4(f2bf(a0), f2bf(a1), f2bf(a2), f2bf(a3));
}

// ---------------- bf16 MFMA GEMM (full-K, fp32 out, fused epilogue) — GNN L1/L2 & logits ----------------
template <int ACT, bool RES, bool BIAS>
__global__ __launch_bounds__(256) void mgemm_k(const unsigned short* __restrict__ A,
                                               const unsigned short* __restrict__ BT,
                                               const float* __restrict__ bias,
                                               const float* __restrict__ R,
                                               float* __restrict__ C, int M, int N, int K) {
    __shared__ unsigned short As[128 * 32];
    __shared__ unsigned short Bs[128 * 32];
    int m0 = blockIdx.y * 128, n0 = blockIdx.x * 128;
    int tid = threadIdx.x;
    int wave = tid >> 6, lane = tid & 63;
    int wm = (wave >> 1) * 64, wn = (wave & 1) * 64;
    int lrow = lane & 15, lq = lane >> 4;

    f32x4 acc[4][4];
    const f32x4 zz = {0.f, 0.f, 0.f, 0.f};
#pragma unroll
    for (int i = 0; i < 4; i++)
#pragma unroll
        for (int j = 0; j < 4; j++) acc[i][j] = zz;

    int r0 = tid >> 2;
    int q = tid & 3;

    for (int k0 = 0; k0 < K; k0 += 32) {
#pragma unroll
        for (int p = 0; p < 2; p++) {
            int row = r0 + p * 64;
            int gm = m0 + row;
            uint4 va = make_uint4(0, 0, 0, 0);
            if (gm < M) va = *(const uint4*)(A + (size_t)gm * K + k0 + q * 8);
            *(uint4*)&As[row * 32 + q * 8] = va;
            int gn = n0 + row;
            uint4 vb = make_uint4(0, 0, 0, 0);
            if (gn < N) vb = *(const uint4*)(BT + (size_t)gn * K + k0 + q * 8);
            *(uint4*)&Bs[row * 32 + q * 8] = vb;
        }
        __syncthreads();
        bf16x8 af[4], bf[4];
#pragma unroll
        for (int i = 0; i < 4; i++)
            af[i] = *(const bf16x8*)&As[(wm + i * 16 + lrow) * 32 + lq * 8];
#pragma unroll
        for (int j = 0; j < 4; j++)
            bf[j] = *(const bf16x8*)&Bs[(wn + j * 16 + lrow) * 32 + lq * 8];
#pragma unroll
        for (int i = 0; i < 4; i++)
#pragma unroll
            for (int j = 0; j < 4; j++)
                acc[i][j] =
                    __builtin_amdgcn_mfma_f32_16x16x32_bf16(af[i], bf[j], acc[i][j], 0, 0, 0);
        __syncthreads();
    }

#pragma unroll
    for (int i = 0; i < 4; i++) {
#pragma unroll
        for (int j = 0; j < 4; j++) {
            int gn = n0 + wn + j * 16 + lrow;
            if (gn >= N) continue;
            float bv = BIAS ? bias[gn] : 0.f;
#pragma unroll
            for (int r = 0; r < 4; r++) {
                int gm = m0 + wm + i * 16 + lq * 4 + r;
                if (gm >= M) continue;
                float v = acc[i][j][r] + bv;
                if (ACT == 1) v = fmaxf(v, 0.f);
                if (RES) v += R[(size_t)gm * N + gn];
                C[(size_t)gm * N + gn] = v;
            }
        }
    }
}

// ---------------- bf16 MFMA full-K, bf16 out, fused epilogue (GNN L3 / post) ----------------
template <int ACT, int EPI>
__global__ __launch_bounds__(256) void mfull_k(const unsigned short* __restrict__ A,
                                               const unsigned short* __restrict__ BT,
                                               const float* __restrict__ bias,
                                               const int* __restrict__ idx,
                                               const float* __restrict__ aux,
                                               unsigned short* __restrict__ O, int M, int N,
                                               int K) {
    __shared__ unsigned short As[64 * 32];
    __shared__ unsigned short Bs[64 * 32];
    int m0 = blockIdx.y * 64, n0 = blockIdx.x * 64;
    int tid = threadIdx.x;
    int wave = tid >> 6, lane = tid & 63;
    int wm = wave * 16;
    int lrow = lane & 15, lq = lane >> 4;
    f32x4 acc[4];
    const f32x4 zz = {0.f, 0.f, 0.f, 0.f};
#pragma unroll
    for (int j = 0; j < 4; j++) acc[j] = zz;
    int r0 = tid >> 2;
    int q = tid & 3;
    for (int k0 = 0; k0 < K; k0 += 32) {
        *(uint4*)&As[r0 * 32 + q * 8] = *(const uint4*)(A + (size_t)(m0 + r0) * K + k0 + q * 8);
        *(uint4*)&Bs[r0 * 32 + q * 8] = *(const uint4*)(BT + (size_t)(n0 + r0) * K + k0 + q * 8);
        __syncthreads();
        bf16x8 af = *(const bf16x8*)&As[(wm + lrow) * 32 + lq * 8];
#pragma unroll
        for (int j = 0; j < 4; j++) {
            bf16x8 bfr = *(const bf16x8*)&Bs[(j * 16 + lrow) * 32 + lq * 8];
            acc[j] = __builtin_amdgcn_mfma_f32_16x16x32_bf16(af, bfr, acc[j], 0, 0, 0);
        }
        __syncthreads();
    }
#pragma unroll
    for (int j = 0; j < 4; j++) {
        int gn = n0 + j * 16 + lrow;
        float bv = bias[gn];
#pragma unroll
        for (int r = 0; r < 4; r++) {
            int gm = m0 + wm + lq * 4 + r;
            float v = acc[j][r] + bv;
            if (ACT == 1) v = fmaxf(v, 0.f);
            if (ACT == 2) v = 0.5f * v * (1.f + erff(v * 0.70710678118654752f));
            if (EPI == 2) {
                int id = idx[gm];
                int safe = id < 0 ? 0 : id;
                v += aux[(size_t)safe * N + gn];
            }
            if (EPI == 1) {
                if (idx[gm] < 0) v = aux[gn];
            }
            O[(size_t)gm * N + gn] = f2bf(v);
        }
    }
}

// ================= fused persistent head (v6: split arrive/wait barrier around prefetch) ======
// Group g (blocks g*32..g*32+31) owns rows [32g,32g+32); per-group barriers (proven
// 178 -> 112 us). Round-8 lesson: issuing prefetch BEFORE gsync serialized the
// weight-load latency into barrier arrival (gsync's waitvm0 drained it; 112->122).
// v6: arrive (store-drain + counter add) FIRST, then issue prefetch, then poll +
// RAW s_barrier (no compiler vmcnt(0) drain) — load latency overlaps the poll.
// Prefetch loads are compiler-tracked; first pf use gets an automatic counted wait.

#define HGRID 256
#define LDPA 520   // ushort row stride for K<=512 tiles: 1040B -> bank-optimal b128 reads
#define GBLK 32    // blocks per group

__device__ inline void gsync_arrive(int* bar) {
    waitvm0();        // drain this thread's cg-stores/atomics (globally visible at retire)
    __syncthreads();  // all threads of the block drained
    if (threadIdx.x == 0)
        __hip_atomic_fetch_add(bar, 1, __ATOMIC_RELAXED, __HIP_MEMORY_SCOPE_AGENT);
}
__device__ inline void gsync_wait(int* bar, int target) {
    if (threadIdx.x == 0) {
        while (__hip_atomic_load(bar, __ATOMIC_RELAXED, __HIP_MEMORY_SCOPE_AGENT) < target)
            __builtin_amdgcn_s_sleep(2);
    }
    // raw s_barrier: no vmcnt(0) drain -> prefetch loads stay in flight across it.
    // No LDS hazard: all prior ds ops are consumed before the preceding arrive.
    __builtin_amdgcn_s_barrier();
}

// issue ROWSxKC bf16 tile loads (all outstanding), NL = ROWS*KC/2048 regs/thread
template <int ROWS, int KC, bool CG>
__device__ inline void stage_issue(const unsigned short* src, int ld, u32x4* regs) {
    constexpr int NL = ROWS * KC / 8 / 256;
    int tid = threadIdx.x;
#pragma unroll
    for (int it = 0; it < NL; it++) {
        int unit = it * 256 + tid;
        int row = unit / (KC / 8);
        int ucol = unit % (KC / 8);
        const unsigned short* p = src + (size_t)row * ld + ucol * 8;
        if (CG) regs[it] = ld16_cg(p);
        else regs[it] = *(const u32x4*)p;
    }
}
template <int ROWS, int KC>
__device__ inline void stage_write(unsigned short* dst, const u32x4* regs) {
    constexpr int NL = ROWS * KC / 8 / 256;
    int tid = threadIdx.x;
#pragma unroll
    for (int it = 0; it < NL; it++) {
        int unit = it * 256 + tid;
        int row = unit / (KC / 8);
        int ucol = unit % (KC / 8);
        *(u32x4*)&dst[row * LDPA + ucol * 8] = regs[it];
    }
}

// uninterrupted MFMA stream over the fully-staged tile (no inner barriers)
template <int KC>
__device__ inline void mma_all(const unsigned short* As, const unsigned short* Bs, f32x4 acc[2]) {
    int tid = threadIdx.x, wave = tid >> 6, lane = tid & 63;
    int wm = (wave >> 1) * 16, wn = (wave & 1) * 32;
    int lrow = lane & 15, lq = lane >> 4;
#pragma unroll
    for (int kk = 0; kk < KC / 32; kk++) {
        bf16x8 af = *(const bf16x8*)&As[(wm + lrow) * LDPA + kk * 32 + lq * 8];
#pragma unroll
        for (int j = 0; j < 2; j++) {
            bf16x8 bfr = *(const bf16x8*)&Bs[(wn + j * 16 + lrow) * LDPA + kk * 32 + lq * 8];
            acc[j] = __builtin_amdgcn_mfma_f32_16x16x32_bf16(af, bfr, acc[j], 0, 0, 0);
        }
    }
}

__global__ __launch_bounds__(256) void head_k(
    const unsigned short* __restrict__ pertbf, const unsigned short* __restrict__ pinT,
    const float* __restrict__ pin_b, const float* __restrict__ blk_ln_s,
    const float* __restrict__ blk_ln_b, const unsigned short* __restrict__ w1T,
    const float* __restrict__ blk_b1, const unsigned short* __restrict__ w2T,
    const float* __restrict__ blk_b2, const unsigned short* __restrict__ poutT,
    const float* __restrict__ pout_b, float* __restrict__ hbuf,
    unsigned short* __restrict__ z1bf, unsigned short* __restrict__ projb,
    int* __restrict__ bar) {
    __shared__ unsigned short As[32 * LDPA];   // 33.3 KB
    __shared__ unsigned short Bs[64 * LDPA];   // 66.6 KB
    int b = blockIdx.x;
    int g = b >> 5;          // row-group 0..7: rows [g*32, g*32+32)
    int t = b & 31;          // rank within group; b%8 == t%8 -> XCD locality by n-slice
    int* gbar = bar + g * 32;   // per-group counter, 128 B apart
    int m0 = g * 32;
    int tid = threadIdx.x;
    int wave = tid >> 6, lane = tid & 63;
    int wm = (wave >> 1) * 16, wn = (wave & 1) * 32;
    int lrow = lane & 15, lq = lane >> 4;
    int ph = 0;
    f32x4 acc[2];
    const f32x4 zz = {0.f, 0.f, 0.f, 0.f};
    u32x4 pf[16];   // weight prefetch registers, live across the barrier (1 block/CU)

    // ---- P0: h[g-rows] = pertbf @ pinT + pin_b  (8 active blocks/group, full K=256)
    if (t < 8) {
        int n0 = t * 64;
        u32x4 wreg[8], areg[4];
        stage_issue<64, 256, false>(pinT + (size_t)n0 * GDIM, GDIM, wreg);
        stage_issue<32, 256, false>(pertbf + (size_t)m0 * GDIM, GDIM, areg);
        waitvm0();
        stage_write<64, 256>(Bs, wreg);
        stage_write<32, 256>(As, areg);
        __syncthreads();
        acc[0] = zz; acc[1] = zz;
        mma_all<256>(As, Bs, acc);
#pragma unroll
        for (int j = 0; j < 2; j++) {
            int gn = n0 + wn + j * 16 + lrow;
            float bv = pin_b[gn];
#pragma unroll
            for (int r = 0; r < 4; r++) {
                int gm = m0 + wm + lq * 4 + r;
                st4f_cg(hbuf + (size_t)gm * HID + gn, acc[j][r] + bv);
            }
        }
    }
    // arrive -> issue layer-0 w1 prefetch -> poll: load latency hides under the poll
    gsync_arrive(gbar);
    stage_issue<64, 512, false>(w1T + (size_t)t * 64 * HID, HID, pf);
    gsync_wait(gbar, ++ph * GBLK);

    for (int i = 0; i < 6; i++) {
        {   // A: z1[g-rows] = gelu(LN_i(h) @ w1 + b1); 32 blocks x 64-col slices, K=512
            int n0 = t * 64;
            u32x4 hreg[16];
            // issue h loads first, then drain prefetched weights into LDS under their latency
#pragma unroll
            for (int rr = 0; rr < 8; rr++) {
                const float* p = hbuf + (size_t)(m0 + wave * 8 + rr) * HID + lane * 8;
                hreg[2 * rr] = ld16_cg(p);
                hreg[2 * rr + 1] = ld16_cg(p + 4);
            }
            stage_write<64, 512>(Bs, pf);   // compiler inserts counted wait for pf here
            waitvm0();
            // inline LayerNorm (redundant across the 32 n-slices, cheap) -> bf16 As
            const float* ls = blk_ln_s + (size_t)i * HID;
            const float* lb = blk_ln_b + (size_t)i * HID;
            float4 s0 = ((const float4*)ls)[lane * 2], s1 = ((const float4*)ls)[lane * 2 + 1];
            float4 t0 = ((const float4*)lb)[lane * 2], t1 = ((const float4*)lb)[lane * 2 + 1];
#pragma unroll
            for (int rr = 0; rr < 8; rr++) {
                float f0 = __uint_as_float(hreg[2 * rr][0]);
                float f1 = __uint_as_float(hreg[2 * rr][1]);
                float f2 = __uint_as_float(hreg[2 * rr][2]);
                float f3 = __uint_as_float(hreg[2 * rr][3]);
                float f4 = __uint_as_float(hreg[2 * rr + 1][0]);
                float f5 = __uint_as_float(hreg[2 * rr + 1][1]);
                float f6 = __uint_as_float(hreg[2 * rr + 1][2]);
                float f7 = __uint_as_float(hreg[2 * rr + 1][3]);
                float sum = f0 + f1 + f2 + f3 + f4 + f5 + f6 + f7;
#pragma unroll
                for (int off = 32; off >= 1; off >>= 1) sum += __shfl_xor(sum, off);
                float mu = sum * (1.f / HID);
                float d0 = f0 - mu, d1 = f1 - mu, d2 = f2 - mu, d3 = f3 - mu;
                float d4 = f4 - mu, d5 = f5 - mu, d6 = f6 - mu, d7 = f7 - mu;
                float sq = d0 * d0 + d1 * d1 + d2 * d2 + d3 * d3 + d4 * d4 + d5 * d5 +
                           d6 * d6 + d7 * d7;
#pragma unroll
                for (int off = 32; off >= 1; off >>= 1) sq += __shfl_xor(sq, off);
                float rstd = rsqrtf(sq * (1.f / HID) + 1e-5f);
                u32x4 pk;
                pk[0] = pk2(d0 * rstd * s0.x + t0.x, d1 * rstd * s0.y + t0.y);
                pk[1] = pk2(d2 * rstd * s0.z + t0.z, d3 * rstd * s0.w + t0.w);
                pk[2] = pk2(d4 * rstd * s1.x + t1.x, d5 * rstd * s1.y + t1.y);
                pk[3] = pk2(d6 * rstd * s1.z + t1.z, d7 * rstd * s1.w + t1.w);
                *(u32x4*)&As[(wave * 8 + rr) * LDPA + lane * 8] = pk;
            }
            __syncthreads();
            acc[0] = zz; acc[1] = zz;
            mma_all<512>(As, Bs, acc);
#pragma unroll
            for (int j = 0; j < 2; j++) {
                int gn = n0 + wn + j * 16 + lrow;
                float bv = blk_b1[(size_t)i * INNER + gn];
#pragma unroll
                for (int r = 0; r < 4; r++) {
                    int gm = m0 + wm + lq * 4 + r;
                    float v = acc[j][r] + bv;
                    v = 0.5f * v * (1.f + erff(v * 0.70710678118654752f));
                    st2_cg(z1bf + (size_t)gm * INNER + gn, f2bf(v));
                }
            }
        }
        // arrive -> prefetch my B-phase w2 slice -> poll
        gsync_arrive(gbar);
        stage_issue<64, 512, false>(
            w2T + (size_t)i * HID * INNER + (size_t)(t & 7) * 64 * INNER + (t >> 3) * 512,
            INNER, pf);
        gsync_wait(gbar, ++ph * GBLK);
        {   // B: h[g-rows] += z1 @ w2 K-chunk (+b2 once via s==0); 8n x 4s per group
            int s = t >> 3, n0 = (t & 7) * 64, kbeg = s * 512;
            u32x4 areg[8];
            stage_issue<32, 512, true>(z1bf + (size_t)m0 * INNER + kbeg, INNER, areg);
            stage_write<64, 512>(Bs, pf);
            waitvm0();
            stage_write<32, 512>(As, areg);
            __syncthreads();
            acc[0] = zz; acc[1] = zz;
            mma_all<512>(As, Bs, acc);
#pragma unroll
            for (int j = 0; j < 2; j++) {
                int gn = n0 + wn + j * 16 + lrow;
                float bv = (s == 0) ? blk_b2[(size_t)i * HID + gn] : 0.f;
#pragma unroll
                for (int r = 0; r < 4; r++) {
                    int gm = m0 + wm + lq * 4 + r;
                    __hip_atomic_fetch_add(hbuf + (size_t)gm * HID + gn, acc[j][r] + bv,
                                           __ATOMIC_RELAXED, __HIP_MEMORY_SCOPE_AGENT);
                }
            }
        }
        // arrive -> prefetch next A-phase w1 (or pout slice after last layer) -> poll
        gsync_arrive(gbar);
        if (i < 5)
            stage_issue<64, 512, false>(
                w1T + (size_t)(i + 1) * INNER * HID + (size_t)t * 64 * HID, HID, pf);
        else if (t < 24)
            stage_issue<64, 512, false>(poutT + (size_t)t * 64 * HID, HID, pf);
        gsync_wait(gbar, ++ph * GBLK);
    }

    // ---- pout: projb[g-rows] = h @ poutT + pout_b  (24 active blocks/group, K=512)
    if (t < 24) {
        int n0 = t * 64;
        u32x4 areg[16];
#pragma unroll
        for (int it = 0; it < 16; it++) {
            int unit = it * 256 + tid;
            int row = unit >> 7, ucol = unit & 127;   // 128 units of 4 f32 per row
            areg[it] = ld16_cg(hbuf + (size_t)(m0 + row) * HID + ucol * 4);
        }
        stage_write<64, 512>(Bs, pf);
        waitvm0();
#pragma unroll
        for (int it = 0; it < 16; it++) {
            int unit = it * 256 + tid;
            int row = unit >> 7, ucol = unit & 127;
            float a = __uint_as_float(areg[it][0]), c = __uint_as_float(areg[it][1]);
            float d = __uint_as_float(areg[it][2]), e = __uint_as_float(areg[it][3]);
            uint2 w2v;
            w2v.x = pk2(a, c);
            w2v.y = pk2(d, e);
            *(uint2*)&As[row * LDPA + ucol * 4] = w2v;
        }
        __syncthreads();
        acc[0] = zz; acc[1] = zz;
        mma_all<512>(As, Bs, acc);
#pragma unroll
        for (int j = 0; j < 2; j++) {
            int gn = n0 + wn + j * 16 + lrow;
            float bv = pout_b[gn];
#pragma unroll
            for (int r = 0; r < 4; r++) {
                int gm = m0 + wm + lq * 4 + r;
                projb[(size_t)gm * (NCLS * RANK) + gn] = f2bf(acc[j][r] + bv);
            }
        }
    }
}

// ---------------- launch ----------------
extern "C" void kernel_launch(void* const* d_in, const int* in_sizes, int n_in,
                              void* d_out, int out_size, void* d_ws, size_t ws_size,
                              hipStream_t stream) {
    const int* node_indices = (const int*)d_in[0];
    const int* edge_src = (const int*)d_in[1];
    const int* edge_dst = edge_src + NEDGES;
    const float* edge_w = (const float*)d_in[2];
    const float* partial_emb = (const float*)d_in[3];
    const float* oov_emb = (const float*)d_in[4];
    const float* gnn_ln_s = (const float*)d_in[5];
    const float* gnn_ln_b = (const float*)d_in[6];
    const float* gnn_w = (const float*)d_in[7];
    const float* gnn_b = (const float*)d_in[8];
    const float* post_w = (const float*)d_in[9];
    const float* post_b = (const float*)d_in[10];
    const float* pin_w = (const float*)d_in[11];
    const float* pin_b = (const float*)d_in[12];
    const float* blk_ln_s = (const float*)d_in[13];
    const float* blk_ln_b = (const float*)d_in[14];
    const float* blk_w1 = (const float*)d_in[15];
    const float* blk_b1 = (const float*)d_in[16];
    const float* blk_w2 = (const float*)d_in[17];
    const float* blk_b2 = (const float*)d_in[18];
    const float* pout_w = (const float*)d_in[19];
    const float* pout_b = (const float*)d_in[20];
    const float* gene = (const float*)d_in[21];
    float* out = (float*)d_out;

    char* p = (char*)d_ws;
    auto alloc = [&](size_t bytes) {
        char* r = p;
        p += (bytes + 255) & ~(size_t)255;
        return r;
    };
    int* counts = (int*)alloc(NNODES * 4);
    int* incl = (int*)alloc(NNODES * 4);
    int* bsums = (int*)alloc(128 * 4);
    int* boffs = (int*)alloc(128 * 4);
    int* row_start = (int*)alloc(NNODES * 4);
    int* cursor = (int*)alloc(NNODES * 4);
    int* flag = (int*)alloc(NNODES * 4);
    int2* epack = (int2*)alloc((size_t)NEDGES * 8);
    // 'part': GNN phase scratch = ln_bf + aggbf (bf16)
    float* part = (float*)alloc((size_t)NNODES * GDIM * 4);
    unsigned short* ln_bf = (unsigned short*)part;
    unsigned short* aggbf = (unsigned short*)((char*)part + (size_t)NNODES * GDIM * 2);
    float* xa = (float*)alloc((size_t)NNODES * GDIM * 4);
    float* xb = (float*)alloc((size_t)NNODES * GDIM * 4);
    float* hbuf = (float*)alloc((size_t)BSZ * HID * 4);
    unsigned short* aggselb = (unsigned short*)alloc((size_t)BSZ * GDIM * 2);
    unsigned short* pertinbf = (unsigned short*)alloc((size_t)BSZ * GDIM * 2);
    unsigned short* pertbf = (unsigned short*)alloc((size_t)BSZ * GDIM * 2);
    unsigned short* z1bf = (unsigned short*)alloc((size_t)BSZ * INNER * 2);
    unsigned short* projb = (unsigned short*)alloc((size_t)BSZ * NCLS * RANK * 2);
    unsigned short* gnnT = (unsigned short*)alloc((size_t)3 * GDIM * GDIM * 2);
    unsigned short* postT = (unsigned short*)alloc((size_t)GDIM * GDIM * 2);
    unsigned short* pinT = (unsigned short*)alloc((size_t)HID * GDIM * 2);
    unsigned short* w1T = (unsigned short*)alloc((size_t)6 * INNER * HID * 2);
    unsigned short* w2T = (unsigned short*)alloc((size_t)6 * HID * INNER * 2);
    unsigned short* poutT = (unsigned short*)alloc((size_t)NCLS * RANK * HID * 2);
    unsigned short* geneb = (unsigned short*)alloc((size_t)NGENES * RANK * 2);
    int* bar = (int*)alloc(1024);   // 8 group counters, 128 B apart

    const int EB = (NEDGES + 255) / 256;
    const int NB = (NNODES + 255) / 256;

    // all weight conversions in one dispatch
    convall_k<<<15100, 256, 0, stream>>>(gnn_w, post_w, pin_w, blk_w1, blk_w2, pout_w, gene,
                                         gnnT, postT, pinT, w1T, w2T, poutT, geneb);

    // CSR build
    (void)hipMemsetAsync(counts, 0, NNODES * 4, stream);
    (void)hipMemsetAsync(flag, 0, NNODES * 4, stream);
    (void)hipMemsetAsync(bar, 0, 1024, stream);
    hist_k<<<EB, 256, 0, stream>>>(edge_dst, counts, NEDGES);
    scan1_k<<<NB, 256, 0, stream>>>(counts, incl, bsums, NNODES);
    scan2_k<<<1, 128, 0, stream>>>(bsums, boffs, NB);
    scan3_k<<<NB, 256, 0, stream>>>(incl, counts, boffs, row_start, cursor, NNODES);
    scatter_k<<<EB, 256, 0, stream>>>(edge_src, edge_dst, edge_w, cursor, epack, NEDGES);
    // rows needed by layers 2/3: selected nodes + their in-neighbors (~41% of rows)
    flag_k<<<BSZ / 4, 256, 0, stream>>>(node_indices, row_start, counts, epack, flag);

    // GNN layer 1 (full) and layer 2 (flagged rows only)
    const float* x_in = partial_emb;
    float* bufs[2] = {xa, xb};
    for (int i = 0; i < 2; i++) {
        lnb_k<false><<<(NNODES + 3) / 4, 256, 0, stream>>>(
            x_in, gnn_ln_s + i * GDIM, gnn_ln_b + i * GDIM, ln_bf, NNODES, nullptr);
        if (i == 0)
            aggb_k<false><<<(NNODES + 3) / 4, 256, 0, stream>>>(row_start, counts, epack, ln_bf,
                                                                aggbf, NNODES, nullptr);
        else
            aggb_k<true><<<(NNODES + 3) / 4, 256, 0, stream>>>(row_start, counts, epack, ln_bf,
                                                               aggbf, NNODES, flag);
        float* x_out = bufs[i];
        mgemm_k<1, true, true><<<dim3(GDIM / 128, (NNODES + 127) / 128), 256, 0, stream>>>(
            aggbf, gnnT + (size_t)i * GDIM * GDIM, gnn_b + i * GDIM, x_in, x_out, NNODES, GDIM,
            GDIM);
        x_in = x_out;
    }
    // layer 3: LN only at flagged rows (sources of selected rows' edges)
    lnb_k<true><<<(NNODES + 3) / 4, 256, 0, stream>>>(xb, gnn_ln_s + 2 * GDIM,
                                                      gnn_ln_b + 2 * GDIM, ln_bf, NNODES, flag);
    aggsel_k<<<BSZ / 4, 256, 0, stream>>>(node_indices, row_start, counts, epack, ln_bf, aggselb);
    mfull_k<1, 2><<<dim3(GDIM / 64, BSZ / 64), 256, 0, stream>>>(
        aggselb, gnnT + (size_t)2 * GDIM * GDIM, gnn_b + 2 * GDIM, node_indices, xb, pertinbf,
        BSZ, GDIM, GDIM);

    // post_mp + OOV replace (fused)
    mfull_k<0, 1><<<dim3(GDIM / 64, BSZ / 64), 256, 0, stream>>>(
        pertinbf, postT, post_b, node_indices, oov_emb, pertbf, BSZ, GDIM, GDIM);

    // fused head: 8 independent 32-block groups, arrive->prefetch->wait barriers
    head_k<<<HGRID, 256, 0, stream>>>(pertbf, pinT, pin_b, blk_ln_s, blk_ln_b, w1T, blk_b1, w2T,
                                      blk_b2, poutT, pout_b, hbuf, z1bf, projb, bar);

    // logits
    mgemm_k<0, false, false><<<dim3((NGENES + 127) / 128, (BSZ * NCLS) / 128), 256, 0, stream>>>(
        projb, geneb, nullptr, nullptr, out, BSZ * NCLS, NGENES, RANK);
}